// Round 2
// baseline (4804.169 us; speedup 1.0000x reference)
//
#include <hip/hip_runtime.h>
#include <hip/hip_bf16.h>

constexpr int B_  = 32;
constexpr int N_  = 500;
constexpr int T0_ = 13;
constexpr int E_  = 2000;
constexpr int EH_ = 300;
constexpr int C_  = 40;
constexpr float EPS_ = 1e-5f;

__device__ __forceinline__ float sigm(float x){ return 1.f/(1.f+__expf(-x)); }
__device__ __forceinline__ float lrelu(float x){ return x > 0.f ? x : 0.01f*x; }

// ---------------- init: zero/flag all small state (replaces hipMemsetAsync) ----------------
__global__ __launch_bounds__(256) void kern_init(float* __restrict__ insum, int* __restrict__ map,
                                                 int* __restrict__ cnts, int* __restrict__ selfe)
{
    int i = blockIdx.x*256 + threadIdx.x;
    if (i < 2) insum[i] = 0.f;
    if (i < N_*N_) map[i] = -1;
    if (i < 1024) cnts[i] = 0;      // cnt0[512] + cnt1[512] contiguous
    if (i < 512) selfe[i] = -1;
}

__global__ __launch_bounds__(256) void kern_zeroacc(float* __restrict__ p, int n)
{
    int i = blockIdx.x*256 + threadIdx.x;
    if (i < n) p[i] = 0.f;
}

// ---------------- input BN stats (single channel) ----------------
__global__ __launch_bounds__(256) void kern_instats(const float* __restrict__ in, float* __restrict__ acc)
{
    float s = 0.f, ss = 0.f;
    int total = B_*N_*T0_;
    for (int i = blockIdx.x*256 + threadIdx.x; i < total; i += gridDim.x*256) {
        float v = in[i]; s += v; ss += v*v;
    }
    __shared__ float l1[256], l2[256];
    l1[threadIdx.x] = s; l2[threadIdx.x] = ss; __syncthreads();
    for (int o = 128; o > 0; o >>= 1) {
        if (threadIdx.x < o) { l1[threadIdx.x] += l1[threadIdx.x+o]; l2[threadIdx.x] += l2[threadIdx.x+o]; }
        __syncthreads();
    }
    if (threadIdx.x == 0) { atomicAdd(&acc[0], l1[0]); atomicAdd(&acc[1], l2[0]); }
}

// ---------------- normalize + start conv -> x (B,N,T,C) ----------------
__global__ __launch_bounds__(256) void kern_x0(const float* __restrict__ in, const float* __restrict__ insum,
    const float* __restrict__ sw, const float* __restrict__ sb, float* __restrict__ x)
{
    int idx = blockIdx.x*256 + threadIdx.x;
    int total = B_*N_*T0_*C_;
    if (idx >= total) return;
    float cnt = (float)(B_*N_*T0_);
    float mean = insum[0]/cnt;
    float var  = insum[1]/cnt - mean*mean;
    float inv  = rsqrtf(var + EPS_);
    int c = idx % C_;
    int pos = idx / C_;                 // == (b*N+n)*T0 + t  (input layout B,1,N,T)
    float xn = (in[pos] - mean)*inv;
    x[idx] = sw[c]*xn + sb[c];
}

// ---------------- adp = softmax(relu(nv1@nv2), axis=1), stored transposed ----------------
__global__ __launch_bounds__(512) void kern_adp(const float* __restrict__ nv1, const float* __restrict__ nv2,
                                                float* __restrict__ adpT)
{
    int n = blockIdx.x;
    int m = threadIdx.x;
    float r = 0.f;
    if (m < N_) {
        #pragma unroll
        for (int k = 0; k < 10; ++k) r += nv1[n*10+k]*nv2[k*N_+m];
        r = r > 0.f ? r : 0.f;
    }
    __shared__ float red[512];
    red[threadIdx.x] = (m < N_) ? r : -1e30f; __syncthreads();
    for (int o = 256; o > 0; o >>= 1) {
        if (threadIdx.x < o) red[threadIdx.x] = fmaxf(red[threadIdx.x], red[threadIdx.x+o]);
        __syncthreads();
    }
    float mx = red[0]; __syncthreads();
    float ev = (m < N_) ? __expf(r - mx) : 0.f;
    red[threadIdx.x] = ev; __syncthreads();
    for (int o = 256; o > 0; o >>= 1) {
        if (threadIdx.x < o) red[threadIdx.x] += red[threadIdx.x+o];
        __syncthreads();
    }
    float sum = red[0];
    if (m < N_) adpT[(size_t)m*N_ + n] = ev/sum;
}

// ---------------- edge preprocessing ----------------
__global__ void kern_emax(const int* __restrict__ idx, int* __restrict__ map)
{
    int e = blockIdx.x*256 + threadIdx.x;
    if (e < E_) atomicMax(&map[idx[e]*N_ + idx[E_+e]], e);
}
__global__ void kern_ecnt(const int* __restrict__ idx, const int* __restrict__ map,
                          int* __restrict__ cnt0, int* __restrict__ cnt1, int* __restrict__ selfe)
{
    int e = blockIdx.x*256 + threadIdx.x;
    if (e >= E_) return;
    int i0 = idx[e], i1 = idx[E_+e];
    if (map[i0*N_+i1] != e) return;     // only last duplicate is active (numpy .set semantics)
    atomicAdd(&cnt1[i1], 1);
    atomicAdd(&cnt0[i0], 1);
    if (i0 == i1) selfe[i0] = e;        // unique per node after dedup
}
__global__ __launch_bounds__(512) void kern_scan(const int* __restrict__ cnt0, const int* __restrict__ cnt1,
    int* __restrict__ ptr0, int* __restrict__ ptr1, int* __restrict__ cur0, int* __restrict__ cur1)
{
    __shared__ int s0[512], s1[512];
    int tid = threadIdx.x;
    s0[tid] = (tid < N_) ? cnt0[tid] : 0;
    s1[tid] = (tid < N_) ? cnt1[tid] : 0;
    __syncthreads();
    for (int o = 1; o < 512; o <<= 1) {
        int v0 = (tid >= o) ? s0[tid-o] : 0;
        int v1 = (tid >= o) ? s1[tid-o] : 0;
        __syncthreads();
        s0[tid] += v0; s1[tid] += v1;
        __syncthreads();
    }
    if (tid == 0) { ptr0[0] = 0; ptr1[0] = 0; }
    if (tid < N_) {
        ptr0[tid+1] = s0[tid]; ptr1[tid+1] = s1[tid];
        cur0[tid] = (tid == 0) ? 0 : s0[tid-1];
        cur1[tid] = (tid == 0) ? 0 : s1[tid-1];
    }
}
__global__ void kern_efill(const int* __restrict__ idx, const int* __restrict__ map,
    const float* __restrict__ Af, const float* __restrict__ Ab,
    int* __restrict__ cur0, int* __restrict__ cur1,
    int* __restrict__ e0id, int* __restrict__ e0nb, float* __restrict__ a0v,
    int* __restrict__ e1id, int* __restrict__ e1nb, float* __restrict__ a1v)
{
    int e = blockIdx.x*256 + threadIdx.x;
    if (e >= E_) return;
    int i0 = idx[e], i1 = idx[E_+e];
    if (map[i0*N_+i1] != e) return;
    int s1 = atomicAdd(&cur1[i1], 1);   // s0 operator: grouped by destination m=i1
    e0id[s1] = e; e0nb[s1] = i0; a0v[s1] = Af[i0*N_+i1];
    int s0 = atomicAdd(&cur0[i0], 1);   // s1 operator: grouped by m=i0
    e1id[s0] = e; e1nb[s0] = i1; a1v[s0] = Ab[i1*N_+i0];
}

// ---------------- per-(b,n) mean over t, dotted with 4 C-vectors ----------------
__global__ __launch_bounds__(64) void kern_umean(const float* __restrict__ x, int Tin,
    const float* __restrict__ vsf, const float* __restrict__ vdf,
    const float* __restrict__ vsb, const float* __restrict__ vdb,
    float* __restrict__ usf, float* __restrict__ udf, float* __restrict__ usb, float* __restrict__ udb)
{
    int bn = blockIdx.x;
    const float* xp = x + (size_t)bn*Tin*C_;
    int tid = threadIdx.x;
    float a0=0.f,a1=0.f,a2=0.f,a3=0.f;
    for (int i = tid; i < Tin*C_; i += 64) {
        float v = xp[i]; int c = i % C_;
        a0 += v*vsf[c]; a1 += v*vdf[c]; a2 += v*vsb[c]; a3 += v*vdb[c];
    }
    for (int o = 32; o > 0; o >>= 1) {
        a0 += __shfl_down(a0,o); a1 += __shfl_down(a1,o);
        a2 += __shfl_down(a2,o); a3 += __shfl_down(a3,o);
    }
    if (tid == 0) {
        float inv = 1.f/(float)Tin;
        usf[bn]=a0*inv; udf[bn]=a1*inv; usb[bn]=a2*inv; udb[bn]=a3*inv;
    }
}

__global__ void kern_sc(const int* __restrict__ idx,
    const float* __restrict__ usf, const float* __restrict__ udf,
    const float* __restrict__ usb, const float* __restrict__ udb,
    float* __restrict__ scf, float* __restrict__ scb)
{
    int i = blockIdx.x*256 + threadIdx.x;
    if (i >= B_*E_) return;
    int b = i / E_, e = i % E_;
    int i0 = idx[e], i1 = idx[E_+e];
    scf[i] = usf[b*N_+i0] + udf[b*N_+i1];
    scb[i] = usb[b*N_+i0] + udb[b*N_+i1];
}

// tf[b,h] += sum_e sc[b,e]*G0[e,h]  (chunked over e, atomic accumulate)
__global__ __launch_bounds__(320) void kern_t(const float* __restrict__ scf, const float* __restrict__ scb,
    const float* __restrict__ G0, float* __restrict__ tf, float* __restrict__ tb)
{
    int b = blockIdx.x, chunk = blockIdx.y;
    int e0 = chunk*250;
    __shared__ float sf[250], sb2[250];
    int tid = threadIdx.x;
    for (int i = tid; i < 250; i += 320) { sf[i] = scf[b*E_+e0+i]; sb2[i] = scb[b*E_+e0+i]; }
    __syncthreads();
    if (tid < EH_) {
        float af = 0.f, ab = 0.f;
        for (int i = 0; i < 250; ++i) {
            float g = G0[(size_t)(e0+i)*EH_ + tid];
            af += sf[i]*g; ab += sb2[i]*g;
        }
        atomicAdd(&tf[b*EH_+tid], af);
        atomicAdd(&tb[b*EH_+tid], ab);
    }
}

// ef[b,e] = sigmoid(sum_h tf[b,h]*w[h]*G1[h,e])
__global__ __launch_bounds__(256) void kern_ef(const float* __restrict__ tf, const float* __restrict__ tb,
    const float* __restrict__ wf, const float* __restrict__ wb, const float* __restrict__ G1,
    float* __restrict__ ef, float* __restrict__ eb)
{
    int b = blockIdx.y;
    int e = blockIdx.x*256 + threadIdx.x;
    __shared__ float f[EH_], g[EH_];
    for (int i = threadIdx.x; i < EH_; i += 256) {
        f[i] = tf[b*EH_+i]*wf[i];
        g[i] = tb[b*EH_+i]*wb[i];
    }
    __syncthreads();
    if (e < E_) {
        float af = 0.f, ab = 0.f;
        for (int h = 0; h < EH_; ++h) {
            float v = G1[(size_t)h*E_ + e];
            af += f[h]*v; ab += g[h]*v;
        }
        ef[b*E_+e] = sigm(af);
        eb[b*E_+e] = sigm(ab);
    }
}

// ---------------- dilated causal conv (dil=2) + tanh*sigmoid gate ----------------
__global__ __launch_bounds__(256) void kern_dconv(const float* __restrict__ x, int Tin,
    const float* __restrict__ fw, const float* __restrict__ fb,
    const float* __restrict__ gw, const float* __restrict__ gb, float* __restrict__ xg)
{
    int bn = blockIdx.x;
    int Tout = Tin - 2;
    __shared__ float xs[T0_*C_];          // <= 520
    __shared__ float wf[2*C_*C_];         // [k][c][o]
    __shared__ float wg[2*C_*C_];
    int tid = threadIdx.x;
    const float* xp = x + (size_t)bn*Tin*C_;
    for (int i = tid; i < Tin*C_; i += 256) xs[i] = xp[i];
    for (int i = tid; i < 2*C_*C_; i += 256) {
        int k = i / (C_*C_); int r = i % (C_*C_); int c = r / C_; int o = r % C_;
        wf[i] = fw[(o*C_+c)*2 + k];
        wg[i] = gw[(o*C_+c)*2 + k];
    }
    __syncthreads();
    for (int oi = tid; oi < Tout*C_; oi += 256) {
        int t = oi / C_, o = oi % C_;
        float af = fb[o], ag = gb[o];
        for (int c = 0; c < C_; ++c) {
            float x0v = xs[t*C_+c], x2v = xs[(t+2)*C_+c];
            af += wf[c*C_+o]*x0v + wf[C_*C_ + c*C_+o]*x2v;
            ag += wg[c*C_+o]*x0v + wg[C_*C_ + c*C_+o]*x2v;
        }
        xg[(size_t)bn*Tout*C_ + oi] = tanhf(af) * sigm(ag);
    }
}

// ---- fused sparse graph op + gconv accumulate ----
// tile = dval*in[b,m] + sum_edges w*in[b,nbr]; optionally write tile to outTile;
// gc[b,m] += tile @ Wslice   (each block owns its (b,m) tile -> no races)
__global__ __launch_bounds__(256) void kern_sparse_acc(const float* __restrict__ in,
    float* __restrict__ outTile, int Tout,
    const int* __restrict__ ptr, const int* __restrict__ nbr, const int* __restrict__ eid,
    const float* __restrict__ aval, const float* __restrict__ coef,
    const float* __restrict__ Amat, const int* __restrict__ selfe,
    const float* __restrict__ gwp, float* __restrict__ gc)
{
    int bn = blockIdx.x; int b = bn / N_, m = bn % N_;
    __shared__ float wv[64];
    __shared__ int nb[64];
    __shared__ float ps[11*C_];     // 440
    __shared__ float wl[C_*C_];     // 1600, [c][o]
    int tid = threadIdx.x;
    int p0 = ptr[m], p1 = ptr[m+1];
    int deg = p1 - p0; if (deg > 64) deg = 64;
    if (tid < deg) {
        wv[tid] = coef[b*E_ + eid[p0+tid]] * aval[p0+tid];
        nb[tid] = nbr[p0+tid];
    }
    for (int i = tid; i < C_*C_; i += 256) wl[i] = gwp[i];
    __syncthreads();
    float dval = (selfe[m] >= 0) ? 0.f : Amat[(size_t)m*N_ + m];
    const float* inb = in + (size_t)b*N_*Tout*C_;
    for (int oi = tid; oi < Tout*C_; oi += 256) {
        float acc = dval * inb[(size_t)m*Tout*C_ + oi];
        for (int j = 0; j < deg; ++j) acc += wv[j]*inb[(size_t)nb[j]*Tout*C_ + oi];
        ps[oi] = acc;
        if (outTile) outTile[(size_t)bn*Tout*C_ + oi] = acc;
    }
    __syncthreads();
    for (int oi = tid; oi < Tout*C_; oi += 256) {
        int t = oi / C_, o = oi % C_;
        float acc = gc[(size_t)bn*Tout*C_ + oi];
        for (int c = 0; c < C_; ++c) acc += ps[t*C_+c]*wl[c*C_+o];
        gc[(size_t)bn*Tout*C_ + oi] = acc;
    }
}

// ---------------- dense adp operator (batched GEMM): out[b][m,j] = sum_n adpT[m,n]*in[b][n,j] ----------------
__global__ __launch_bounds__(256) void kern_gemm_adp(const float* __restrict__ adpT,
    const float* __restrict__ xin, float* __restrict__ xout, int LD)
{
    __shared__ float As[16][68];
    __shared__ float Bs[16][68];
    int b  = blockIdx.z;
    int m0 = blockIdx.x*64;
    int j0 = blockIdx.y*64;
    const float* in_b = xin + (size_t)b*N_*LD;
    float* out_b = xout + (size_t)b*N_*LD;
    int tid = threadIdx.x;
    int tx = tid & 15, ty = tid >> 4;
    int lk = tid & 15, lm = tid >> 4;
    int lj = tid & 63, lkb = tid >> 6;
    float acc[4][4] = {};
    for (int k0 = 0; k0 < N_; k0 += 16) {
        #pragma unroll
        for (int p = 0; p < 4; ++p) {
            int mm = lm + p*16;
            int gm = m0 + mm, gk = k0 + lk;
            As[lk][mm] = (gm < N_ && gk < N_) ? adpT[(size_t)gm*N_ + gk] : 0.f;
            int kk = lkb + p*4;
            int gk2 = k0 + kk, gj = j0 + lj;
            Bs[kk][lj] = (gk2 < N_ && gj < LD) ? in_b[(size_t)gk2*LD + gj] : 0.f;
        }
        __syncthreads();
        #pragma unroll
        for (int kk = 0; kk < 16; ++kk) {
            float4 av = *(const float4*)&As[kk][ty*4];
            float4 bv = *(const float4*)&Bs[kk][tx*4];
            float a[4] = {av.x, av.y, av.z, av.w};
            float bb[4] = {bv.x, bv.y, bv.z, bv.w};
            #pragma unroll
            for (int i = 0; i < 4; ++i)
                #pragma unroll
                for (int j = 0; j < 4; ++j)
                    acc[i][j] += a[i]*bb[j];
        }
        __syncthreads();
    }
    #pragma unroll
    for (int i = 0; i < 4; ++i) {
        int gm = m0 + ty*4 + i;
        if (gm >= N_) continue;
        #pragma unroll
        for (int j = 0; j < 4; ++j) {
            int gj = j0 + tx*4 + j;
            if (gj < LD) out_b[(size_t)gm*LD + gj] = acc[i][j];
        }
    }
}

// ---------------- gconv accumulate one 40-chunk: gc (+)= part @ Wslice (+bias) ----------------
__global__ __launch_bounds__(256) void kern_gacc(const float* __restrict__ part, const float* __restrict__ gwp,
    const float* __restrict__ gbias, float* __restrict__ gc, int Tout, int first)
{
    int bn = blockIdx.x;
    __shared__ float ps[11*C_];     // 440
    __shared__ float wl[C_*C_];     // 1600, [c][o]
    int tid = threadIdx.x;
    for (int i = tid; i < Tout*C_; i += 256) ps[i] = part[(size_t)bn*Tout*C_ + i];
    for (int i = tid; i < C_*C_; i += 256) wl[i] = gwp[i];
    __syncthreads();
    for (int oi = tid; oi < Tout*C_; oi += 256) {
        int t = oi / C_, o = oi % C_;
        float acc = first ? gbias[o] : gc[(size_t)bn*Tout*C_ + oi];
        for (int c = 0; c < C_; ++c) acc += ps[t*C_+c]*wl[c*C_+o];
        gc[(size_t)bn*Tout*C_ + oi] = acc;
    }
}

// ---------------- BN stats over (b,n,t) per channel (C=40) ----------------
__global__ __launch_bounds__(320) void kern_bnstats(const float* __restrict__ src, size_t total, float* __restrict__ acc)
{
    int tid = threadIdx.x;
    float s = 0.f, ss = 0.f;
    for (size_t i = (size_t)blockIdx.x*320 + tid; i < total; i += (size_t)gridDim.x*320) {
        float v = src[i]; s += v; ss += v*v;
    }
    __shared__ float ls[320], lss[320];
    ls[tid] = s; lss[tid] = ss; __syncthreads();
    if (tid < C_) {
        float t1 = 0.f, t2 = 0.f;
        for (int r = 0; r < 8; ++r) { t1 += ls[r*C_+tid]; t2 += lss[r*C_+tid]; }
        atomicAdd(&acc[tid], t1); atomicAdd(&acc[C_+tid], t2);
    }
}

// BN1 apply + residual add (in place into gc) + BN2 stats
__global__ __launch_bounds__(320) void kern_bn1(float* __restrict__ gc, const float* __restrict__ resid,
    int Tin, int Tout, const float* __restrict__ acc1,
    const float* __restrict__ g1, const float* __restrict__ b1, float* __restrict__ acc2)
{
    int tid = threadIdx.x; int c = tid % C_;
    float cnt = (float)(B_*N_*Tout);
    float mean = acc1[c]/cnt;
    float var  = acc1[C_+c]/cnt - mean*mean;
    float inv  = rsqrtf(var + EPS_);
    float gg = g1[c], bb = b1[c];
    int dlt = Tin - Tout;
    float s = 0.f, ss = 0.f;
    size_t total = (size_t)B_*N_*Tout*C_;
    for (size_t i = (size_t)blockIdx.x*320 + tid; i < total; i += (size_t)gridDim.x*320) {
        size_t pos = i / C_; int t = (int)(pos % Tout); size_t bn = pos / Tout;
        float y = gg*(gc[i]-mean)*inv + bb;
        y += resid[(bn*Tin + (t+dlt))*C_ + c];
        gc[i] = y;
        s += y; ss += y*y;
    }
    __shared__ float ls[320], lss[320];
    ls[tid] = s; lss[tid] = ss; __syncthreads();
    if (tid < C_) {
        float t1 = 0.f, t2 = 0.f;
        for (int r = 0; r < 8; ++r) { t1 += ls[r*C_+tid]; t2 += lss[r*C_+tid]; }
        atomicAdd(&acc2[tid], t1); atomicAdd(&acc2[C_+tid], t2);
    }
}

__global__ __launch_bounds__(256) void kern_bn2(const float* __restrict__ gc, float* __restrict__ xout, int Tout,
    const float* __restrict__ acc2, const float* __restrict__ g2, const float* __restrict__ b2)
{
    size_t total = (size_t)B_*N_*Tout*C_;
    size_t i = (size_t)blockIdx.x*256 + threadIdx.x;
    if (i >= total) return;
    int c = (int)(i % C_);
    float cnt = (float)(B_*N_*Tout);
    float mean = acc2[c]/cnt;
    float var  = acc2[C_+c]/cnt - mean*mean;
    float inv  = rsqrtf(var + EPS_);
    xout[i] = g2[c]*(gc[i]-mean)*inv + b2[c];
}

// ---------------- skip conv on last 7 steps -> bf16 skip(B,N,7,320) ----------------
__global__ __launch_bounds__(256) void kern_skip(const float* __restrict__ x, int Tout,
    const float* __restrict__ sw, const float* __restrict__ sbias, __hip_bfloat16* __restrict__ skp, int first)
{
    int bn = blockIdx.x; int half = blockIdx.y;    // o in [half*160, half*160+160)
    int off = Tout - 7;
    __shared__ float xs[7*C_];       // 280
    __shared__ float wl[160*41];     // padded stride 41
    int tid = threadIdx.x;
    for (int i = tid; i < 7*C_; i += 256) xs[i] = x[((size_t)bn*Tout + off)*C_ + i];
    for (int i = tid; i < 160*C_; i += 256) {
        int oo = i / C_, c = i % C_;
        wl[oo*41 + c] = sw[(size_t)(half*160 + oo)*C_ + c];
    }
    __syncthreads();
    for (int oi = tid; oi < 7*160; oi += 256) {
        int t = oi / 160, oo = oi % 160;
        float acc = 0.f;
        for (int c = 0; c < C_; ++c) acc += xs[t*C_+c]*wl[oo*41+c];
        int o = half*160 + oo;
        size_t di = ((size_t)bn*7 + t)*320 + o;
        float v = acc + sbias[o];
        float old = first ? 0.f : __bfloat162float(skp[di]);
        skp[di] = __float2bfloat16(old + v);
    }
}

// ---------------- output init with end2 bias ----------------
__global__ void kern_oinit(float* __restrict__ out, const float* __restrict__ e2b)
{
    int i = blockIdx.x*256 + threadIdx.x;
    if (i >= B_*12*N_*7) return;
    int o = (i / (N_*7)) % 12;
    out[i] = e2b[o];
}

// ---------------- fused end1(+lrelu both sides)+end2 with atomic finish ----------------
__global__ __launch_bounds__(256) void kern_end(const __hip_bfloat16* __restrict__ skp,
    const float* __restrict__ e1w, const float* __restrict__ e1b,
    const float* __restrict__ e2w, float* __restrict__ out)
{
    __shared__ float As[16][68];
    __shared__ float Bs[16][68];
    __shared__ float w2[12][64];
    __shared__ float yl[64][65];
    int tid = threadIdx.x;
    int m0 = blockIdx.x*64;     // M = B*N*7 = 112000 = 1750*64 exactly
    int c0 = blockIdx.y*64;     // 640 = 10*64 exactly
    for (int i = tid; i < 12*64; i += 256) {
        int o = i >> 6, cc = i & 63;
        w2[o][cc] = e2w[o*640 + c0 + cc];
    }
    int tx = tid & 15, ty = tid >> 4;
    int lk = tid & 15, lm = tid >> 4;
    float acc[4][4] = {};
    for (int k0 = 0; k0 < 320; k0 += 16) {
        #pragma unroll
        for (int p = 0; p < 4; ++p) {
            int mm = lm + p*16;
            float v = __bfloat162float(skp[(size_t)(m0+mm)*320 + k0 + lk]);
            As[lk][mm] = lrelu(v);
            Bs[lk][mm] = e1w[(size_t)(c0+mm)*320 + k0 + lk];
        }
        __syncthreads();
        #pragma unroll
        for (int kk = 0; kk < 16; ++kk) {
            float4 av = *(const float4*)&As[kk][ty*4];
            float4 bv = *(const float4*)&Bs[kk][tx*4];
            float a[4] = {av.x, av.y, av.z, av.w};
            float bb[4] = {bv.x, bv.y, bv.z, bv.w};
            #pragma unroll
            for (int i = 0; i < 4; ++i)
                #pragma unroll
                for (int j = 0; j < 4; ++j)
                    acc[i][j] += a[i]*bb[j];
        }
        __syncthreads();
    }
    #pragma unroll
    for (int j = 0; j < 4; ++j) {
        float bias = e1b[c0 + tx*4 + j];
        #pragma unroll
        for (int i = 0; i < 4; ++i) {
            float y = acc[i][j] + bias;
            yl[ty*4+i][tx*4+j] = lrelu(y);
        }
    }
    __syncthreads();
    for (int i = tid; i < 64*12; i += 256) {
        int m = i & 63, o = i >> 6;
        float a = 0.f;
        #pragma unroll 8
        for (int cc = 0; cc < 64; ++cc) a += yl[m][cc]*w2[o][cc];
        int gm = m0 + m;
        int t = gm % 7; int bn = gm / 7; int n = bn % N_; int b = bn / N_;
        atomicAdd(&out[(((size_t)b*12 + o)*N_ + n)*7 + t], a);
    }
}

extern "C" void kernel_launch(void* const* d_in, const int* in_sizes, int n_in,
                              void* d_out, int out_size, void* d_ws, size_t ws_size,
                              hipStream_t stream)
{
    (void)in_sizes; (void)n_in; (void)out_size;
    const float* input   = (const float*)d_in[0];
    const float* A_fwd   = (const float*)d_in[1];
    const float* A_bwd   = (const float*)d_in[2];
    const int*   indices = (const int*)  d_in[3];
    const float* G0      = (const float*)d_in[4];
    const float* G1      = (const float*)d_in[5];
    const float* nv1     = (const float*)d_in[6];
    const float* nv2     = (const float*)d_in[7];
    const float* wef     = (const float*)d_in[8];
    const float* web     = (const float*)d_in[9];
    const float* vsf     = (const float*)d_in[10];
    const float* vdf     = (const float*)d_in[11];
    const float* vsb     = (const float*)d_in[12];
    const float* vdb     = (const float*)d_in[13];
    const float* start_w = (const float*)d_in[14];
    const float* start_b = (const float*)d_in[15];
    const float* filt_w  = (const float*)d_in[16];
    const float* filt_b  = (const float*)d_in[17];
    const float* gate_w  = (const float*)d_in[18];
    const float* gate_b  = (const float*)d_in[19];
    const float* gcw     = (const float*)d_in[20];
    const float* gcb     = (const float*)d_in[21];
    const float* bng_g   = (const float*)d_in[22];
    const float* bng_b   = (const float*)d_in[23];
    const float* bn_g    = (const float*)d_in[24];
    const float* bn_b    = (const float*)d_in[25];
    const float* skw     = (const float*)d_in[26];
    const float* skb     = (const float*)d_in[27];
    const float* e1w     = (const float*)d_in[28];
    const float* e1b     = (const float*)d_in[29];
    const float* e2w     = (const float*)d_in[30];
    const float* e2b     = (const float*)d_in[31];
    float* out = (float*)d_out;

    // ---- workspace layout (counted in 4B units) ----
    float* W = (float*)d_ws;
    size_t off = 0;
    auto FA = [&](size_t n){ float* p = W + off; off += n; return p; };
    float* insum  = FA(2);
    float* tf     = FA((size_t)B_*EH_);
    float* tb     = FA((size_t)B_*EH_);
    float* bnacc1 = FA(80);
    float* bnacc2 = FA(80);
    float* usf = FA((size_t)B_*N_); float* udf = FA((size_t)B_*N_);
    float* usb = FA((size_t)B_*N_); float* udb = FA((size_t)B_*N_);
    float* scf = FA((size_t)B_*E_); float* scb = FA((size_t)B_*E_);
    float* efv = FA((size_t)B_*E_); float* ebv = FA((size_t)B_*E_);
    float* adpT = FA((size_t)N_*N_);
    float* a0v = FA(E_); float* a1v = FA(E_);
    int* ibase = (int*)(W + off); size_t ioff = 0;
    auto IA = [&](size_t n){ int* p = ibase + ioff; ioff += n; return p; };
    int* map  = IA((size_t)N_*N_);
    int* cnt0 = IA(512); int* cnt1 = IA(512);     // contiguous: zeroed together
    int* ptr0 = IA(512); int* ptr1 = IA(512);
    int* cur0 = IA(512); int* cur1 = IA(512);
    int* selfe = IA(512);
    int* e0id = IA(E_); int* e0nb = IA(E_);
    int* e1id = IA(E_); int* e1nb = IA(E_);
    off += ioff;
    float* xA  = FA((size_t)B_*N_*T0_*C_);                   // current x, (B,N,T,C)
    float* xg  = FA((size_t)B_*N_*11*C_);                    // gated dconv out / adp hop2 reuse
    float* pa  = FA((size_t)B_*N_*11*C_);                    // first-hop buffer
    float* gc  = FA((size_t)B_*N_*11*C_);                    // gconv accumulator
    __hip_bfloat16* skp = (__hip_bfloat16*)FA((size_t)B_*N_*7*320/2);  // bf16 skip

    // ws guard: fail cleanly (wrong answer) instead of faulting if scratch too small
    if (ws_size < off*sizeof(float)) return;

    // ---- setup ----
    kern_init<<<(N_*N_+255)/256, 256, 0, stream>>>(insum, map, cnt0, selfe);
    kern_instats<<<256, 256, 0, stream>>>(input, insum);
    kern_x0<<<(B_*N_*T0_*C_+255)/256, 256, 0, stream>>>(input, insum, start_w, start_b, xA);
    kern_adp<<<N_, 512, 0, stream>>>(nv1, nv2, adpT);
    kern_emax<<<(E_+255)/256, 256, 0, stream>>>(indices, map);
    kern_ecnt<<<(E_+255)/256, 256, 0, stream>>>(indices, map, cnt0, cnt1, selfe);
    kern_scan<<<1, 512, 0, stream>>>(cnt0, cnt1, ptr0, ptr1, cur0, cur1);
    kern_efill<<<(E_+255)/256, 256, 0, stream>>>(indices, map, A_fwd, A_bwd, cur0, cur1,
                                                 e0id, e0nb, a0v, e1id, e1nb, a1v);

    // ---- 3 blocks ----
    for (int blk = 0; blk < 3; ++blk) {
        int Tin = T0_ - 2*blk;
        int Tout = Tin - 2;
        size_t total = (size_t)B_*N_*Tout*C_;
        // zero tf,tb,bnacc1,bnacc2 (contiguous run starting at tf)
        kern_zeroacc<<<(2*B_*EH_+160+255)/256, 256, 0, stream>>>(tf, 2*B_*EH_+160);

        kern_umean<<<B_*N_, 64, 0, stream>>>(xA, Tin, vsf+blk*C_, vdf+blk*C_, vsb+blk*C_, vdb+blk*C_,
                                             usf, udf, usb, udb);
        kern_sc<<<(B_*E_+255)/256, 256, 0, stream>>>(indices, usf, udf, usb, udb, scf, scb);
        kern_t<<<dim3(B_, 8), 320, 0, stream>>>(scf, scb, G0, tf, tb);
        kern_ef<<<dim3(8, B_), 256, 0, stream>>>(tf, tb, wef, web, G1, efv, ebv);

        kern_dconv<<<B_*N_, 256, 0, stream>>>(xA, Tin, filt_w + (size_t)blk*2*C_*C_, filt_b + blk*C_,
                                              gate_w + (size_t)blk*2*C_*C_, gate_b + blk*C_, xg);

        const float* gwb = gcw + (size_t)blk*7*C_*C_;
        // chunk 0: identity term (with bias)
        kern_gacc<<<B_*N_, 256, 0, stream>>>(xg, gwb + 0*C_*C_, gcb + blk*C_, gc, Tout, 1);
        // s0: two hops (hop2 fused, never materialized)
        kern_sparse_acc<<<B_*N_, 256, 0, stream>>>(xg, pa, Tout, ptr1, e0nb, e0id, a0v, efv,
                                                   A_fwd, selfe, gwb + 1*C_*C_, gc);
        kern_sparse_acc<<<B_*N_, 256, 0, stream>>>(pa, nullptr, Tout, ptr1, e0nb, e0id, a0v, efv,
                                                   A_fwd, selfe, gwb + 2*C_*C_, gc);
        // s1: two hops
        kern_sparse_acc<<<B_*N_, 256, 0, stream>>>(xg, pa, Tout, ptr0, e1nb, e1id, a1v, ebv,
                                                   A_bwd, selfe, gwb + 3*C_*C_, gc);
        kern_sparse_acc<<<B_*N_, 256, 0, stream>>>(pa, nullptr, Tout, ptr0, e1nb, e1id, a1v, ebv,
                                                   A_bwd, selfe, gwb + 4*C_*C_, gc);
        // adp: two dense hops; hop2 writes into xg (dead after hop1)
        int LD = Tout*C_;
        dim3 gg(8, (LD+63)/64, B_);
        kern_gemm_adp<<<gg, 256, 0, stream>>>(adpT, xg, pa, LD);
        kern_gacc<<<B_*N_, 256, 0, stream>>>(pa, gwb + 5*C_*C_, nullptr, gc, Tout, 0);
        kern_gemm_adp<<<gg, 256, 0, stream>>>(adpT, pa, xg, LD);
        kern_gacc<<<B_*N_, 256, 0, stream>>>(xg, gwb + 6*C_*C_, nullptr, gc, Tout, 0);

        kern_bnstats<<<512, 320, 0, stream>>>(gc, total, bnacc1);
        kern_bn1<<<512, 320, 0, stream>>>(gc, xA, Tin, Tout, bnacc1, bng_g + blk*C_, bng_b + blk*C_, bnacc2);
        kern_bn2<<<(int)((total+255)/256), 256, 0, stream>>>(gc, xA, Tout, bnacc2, bn_g + blk*C_, bn_b + blk*C_);

        kern_skip<<<dim3(B_*N_, 2), 256, 0, stream>>>(xA, Tout, skw + (size_t)blk*320*C_, skb + blk*320,
                                                      skp, blk == 0 ? 1 : 0);
    }

    // ---- end stage ----
    kern_oinit<<<(B_*12*N_*7+255)/256, 256, 0, stream>>>(out, e2b);
    kern_end<<<dim3(B_*N_*7/64, 640/64), 256, 0, stream>>>(skp, e1w, e1b, e2w, out);
}

// Round 3
// 3925.873 us; speedup vs baseline: 1.2237x; 1.2237x over previous
//
#include <hip/hip_runtime.h>
#include <hip/hip_bf16.h>

constexpr int B_  = 32;
constexpr int N_  = 500;
constexpr int T0_ = 13;
constexpr int E_  = 2000;
constexpr int EH_ = 300;
constexpr int C_  = 40;
constexpr float EPS_ = 1e-5f;

typedef short bf16x8 __attribute__((ext_vector_type(8)));
typedef float f32x4  __attribute__((ext_vector_type(4)));

__device__ __forceinline__ float sigm(float x){ return 1.f/(1.f+__expf(-x)); }
__device__ __forceinline__ float lrelu(float x){ return x > 0.f ? x : 0.01f*x; }

// ---------------- init: zero/flag all small state ----------------
__global__ __launch_bounds__(256) void kern_init(float* __restrict__ insum, int* __restrict__ map,
                                                 int* __restrict__ cnts, int* __restrict__ selfe)
{
    int i = blockIdx.x*256 + threadIdx.x;
    if (i < 2) insum[i] = 0.f;
    if (i < N_*N_) map[i] = -1;
    if (i < 1024) cnts[i] = 0;
    if (i < 512) selfe[i] = -1;
}

__global__ __launch_bounds__(256) void kern_zeroacc(float* __restrict__ p, int n)
{
    int i = blockIdx.x*256 + threadIdx.x;
    if (i < n) p[i] = 0.f;
}

// ---------------- input BN stats ----------------
__global__ __launch_bounds__(256) void kern_instats(const float* __restrict__ in, float* __restrict__ acc)
{
    float s = 0.f, ss = 0.f;
    int total = B_*N_*T0_;
    for (int i = blockIdx.x*256 + threadIdx.x; i < total; i += gridDim.x*256) {
        float v = in[i]; s += v; ss += v*v;
    }
    __shared__ float l1[256], l2[256];
    l1[threadIdx.x] = s; l2[threadIdx.x] = ss; __syncthreads();
    for (int o = 128; o > 0; o >>= 1) {
        if (threadIdx.x < o) { l1[threadIdx.x] += l1[threadIdx.x+o]; l2[threadIdx.x] += l2[threadIdx.x+o]; }
        __syncthreads();
    }
    if (threadIdx.x == 0) { atomicAdd(&acc[0], l1[0]); atomicAdd(&acc[1], l2[0]); }
}

// ---------------- normalize + start conv -> x (B,N,T,C) ----------------
__global__ __launch_bounds__(256) void kern_x0(const float* __restrict__ in, const float* __restrict__ insum,
    const float* __restrict__ sw, const float* __restrict__ sb, float* __restrict__ x)
{
    int idx = blockIdx.x*256 + threadIdx.x;
    int total = B_*N_*T0_*C_;
    if (idx >= total) return;
    float cnt = (float)(B_*N_*T0_);
    float mean = insum[0]/cnt;
    float var  = insum[1]/cnt - mean*mean;
    float inv  = rsqrtf(var + EPS_);
    int c = idx % C_;
    int pos = idx / C_;
    float xn = (in[pos] - mean)*inv;
    x[idx] = sw[c]*xn + sb[c];
}

// ---------------- adp = softmax(relu(nv1@nv2), axis=1), stored transposed ----------------
__global__ __launch_bounds__(512) void kern_adp(const float* __restrict__ nv1, const float* __restrict__ nv2,
                                                float* __restrict__ adpT)
{
    int n = blockIdx.x;
    int m = threadIdx.x;
    float r = 0.f;
    if (m < N_) {
        #pragma unroll
        for (int k = 0; k < 10; ++k) r += nv1[n*10+k]*nv2[k*N_+m];
        r = r > 0.f ? r : 0.f;
    }
    __shared__ float red[512];
    red[threadIdx.x] = (m < N_) ? r : -1e30f; __syncthreads();
    for (int o = 256; o > 0; o >>= 1) {
        if (threadIdx.x < o) red[threadIdx.x] = fmaxf(red[threadIdx.x], red[threadIdx.x+o]);
        __syncthreads();
    }
    float mx = red[0]; __syncthreads();
    float ev = (m < N_) ? __expf(r - mx) : 0.f;
    red[threadIdx.x] = ev; __syncthreads();
    for (int o = 256; o > 0; o >>= 1) {
        if (threadIdx.x < o) red[threadIdx.x] += red[threadIdx.x+o];
        __syncthreads();
    }
    float sum = red[0];
    if (m < N_) adpT[(size_t)m*N_ + n] = ev/sum;
}

// ---------------- edge preprocessing ----------------
__global__ void kern_emax(const int* __restrict__ idx, int* __restrict__ map)
{
    int e = blockIdx.x*256 + threadIdx.x;
    if (e < E_) atomicMax(&map[idx[e]*N_ + idx[E_+e]], e);
}
__global__ void kern_ecnt(const int* __restrict__ idx, const int* __restrict__ map,
                          int* __restrict__ cnt0, int* __restrict__ cnt1, int* __restrict__ selfe)
{
    int e = blockIdx.x*256 + threadIdx.x;
    if (e >= E_) return;
    int i0 = idx[e], i1 = idx[E_+e];
    if (map[i0*N_+i1] != e) return;
    atomicAdd(&cnt1[i1], 1);
    atomicAdd(&cnt0[i0], 1);
    if (i0 == i1) selfe[i0] = e;
}
__global__ __launch_bounds__(512) void kern_scan(const int* __restrict__ cnt0, const int* __restrict__ cnt1,
    int* __restrict__ ptr0, int* __restrict__ ptr1, int* __restrict__ cur0, int* __restrict__ cur1)
{
    __shared__ int s0[512], s1[512];
    int tid = threadIdx.x;
    s0[tid] = (tid < N_) ? cnt0[tid] : 0;
    s1[tid] = (tid < N_) ? cnt1[tid] : 0;
    __syncthreads();
    for (int o = 1; o < 512; o <<= 1) {
        int v0 = (tid >= o) ? s0[tid-o] : 0;
        int v1 = (tid >= o) ? s1[tid-o] : 0;
        __syncthreads();
        s0[tid] += v0; s1[tid] += v1;
        __syncthreads();
    }
    if (tid == 0) { ptr0[0] = 0; ptr1[0] = 0; }
    if (tid < N_) {
        ptr0[tid+1] = s0[tid]; ptr1[tid+1] = s1[tid];
        cur0[tid] = (tid == 0) ? 0 : s0[tid-1];
        cur1[tid] = (tid == 0) ? 0 : s1[tid-1];
    }
}
__global__ void kern_efill(const int* __restrict__ idx, const int* __restrict__ map,
    const float* __restrict__ Af, const float* __restrict__ Ab,
    int* __restrict__ cur0, int* __restrict__ cur1,
    int* __restrict__ e0id, int* __restrict__ e0nb, float* __restrict__ a0v,
    int* __restrict__ e1id, int* __restrict__ e1nb, float* __restrict__ a1v)
{
    int e = blockIdx.x*256 + threadIdx.x;
    if (e >= E_) return;
    int i0 = idx[e], i1 = idx[E_+e];
    if (map[i0*N_+i1] != e) return;
    int s1 = atomicAdd(&cur1[i1], 1);
    e0id[s1] = e; e0nb[s1] = i0; a0v[s1] = Af[i0*N_+i1];
    int s0 = atomicAdd(&cur0[i0], 1);
    e1id[s0] = e; e1nb[s0] = i1; a1v[s0] = Ab[i1*N_+i0];
}

// ---------------- per-(b,n) mean over t, dotted with 4 C-vectors ----------------
__global__ __launch_bounds__(64) void kern_umean(const float* __restrict__ x, int Tin,
    const float* __restrict__ vsf, const float* __restrict__ vdf,
    const float* __restrict__ vsb, const float* __restrict__ vdb,
    float* __restrict__ usf, float* __restrict__ udf, float* __restrict__ usb, float* __restrict__ udb)
{
    int bn = blockIdx.x;
    const float* xp = x + (size_t)bn*Tin*C_;
    int tid = threadIdx.x;
    float a0=0.f,a1=0.f,a2=0.f,a3=0.f;
    for (int i = tid; i < Tin*C_; i += 64) {
        float v = xp[i]; int c = i % C_;
        a0 += v*vsf[c]; a1 += v*vdf[c]; a2 += v*vsb[c]; a3 += v*vdb[c];
    }
    for (int o = 32; o > 0; o >>= 1) {
        a0 += __shfl_down(a0,o); a1 += __shfl_down(a1,o);
        a2 += __shfl_down(a2,o); a3 += __shfl_down(a3,o);
    }
    if (tid == 0) {
        float inv = 1.f/(float)Tin;
        usf[bn]=a0*inv; udf[bn]=a1*inv; usb[bn]=a2*inv; udb[bn]=a3*inv;
    }
}

__global__ void kern_sc(const int* __restrict__ idx,
    const float* __restrict__ usf, const float* __restrict__ udf,
    const float* __restrict__ usb, const float* __restrict__ udb,
    float* __restrict__ scf, float* __restrict__ scb)
{
    int i = blockIdx.x*256 + threadIdx.x;
    if (i >= B_*E_) return;
    int b = i / E_, e = i % E_;
    int i0 = idx[e], i1 = idx[E_+e];
    scf[i] = usf[b*N_+i0] + udf[b*N_+i1];
    scb[i] = usb[b*N_+i0] + udb[b*N_+i1];
}

__global__ __launch_bounds__(320) void kern_t(const float* __restrict__ scf, const float* __restrict__ scb,
    const float* __restrict__ G0, float* __restrict__ tf, float* __restrict__ tb)
{
    int b = blockIdx.x, chunk = blockIdx.y;
    int e0 = chunk*250;
    __shared__ float sf[250], sb2[250];
    int tid = threadIdx.x;
    for (int i = tid; i < 250; i += 320) { sf[i] = scf[b*E_+e0+i]; sb2[i] = scb[b*E_+e0+i]; }
    __syncthreads();
    if (tid < EH_) {
        float af = 0.f, ab = 0.f;
        for (int i = 0; i < 250; ++i) {
            float g = G0[(size_t)(e0+i)*EH_ + tid];
            af += sf[i]*g; ab += sb2[i]*g;
        }
        atomicAdd(&tf[b*EH_+tid], af);
        atomicAdd(&tb[b*EH_+tid], ab);
    }
}

__global__ __launch_bounds__(256) void kern_ef(const float* __restrict__ tf, const float* __restrict__ tb,
    const float* __restrict__ wf, const float* __restrict__ wb, const float* __restrict__ G1,
    float* __restrict__ ef, float* __restrict__ eb)
{
    int b = blockIdx.y;
    int e = blockIdx.x*256 + threadIdx.x;
    __shared__ float f[EH_], g[EH_];
    for (int i = threadIdx.x; i < EH_; i += 256) {
        f[i] = tf[b*EH_+i]*wf[i];
        g[i] = tb[b*EH_+i]*wb[i];
    }
    __syncthreads();
    if (e < E_) {
        float af = 0.f, ab = 0.f;
        for (int h = 0; h < EH_; ++h) {
            float v = G1[(size_t)h*E_ + e];
            af += f[h]*v; ab += g[h]*v;
        }
        ef[b*E_+e] = sigm(af);
        eb[b*E_+e] = sigm(ab);
    }
}

// ---------------- dilated conv + gate, fused with gconv chunk0 (2 bn tiles / block) ----------------
__global__ __launch_bounds__(256) void kern_dconv_acc(const float* __restrict__ x, int Tin,
    const float* __restrict__ fw, const float* __restrict__ fb4,
    const float* __restrict__ gw, const float* __restrict__ gb4,
    const float* __restrict__ wl0, const float* __restrict__ gbias,
    float* __restrict__ xg, float* __restrict__ gc)
{
    int Tout = Tin - 2;
    int nout = Tout*C_;
    int tile = threadIdx.x >> 7;
    int lane = threadIdx.x & 127;
    int bn = blockIdx.x*2 + tile;
    __shared__ alignas(16) float xs[2][T0_*C_];
    __shared__ alignas(16) float wf[2*C_*C_];   // [k][c][o]
    __shared__ alignas(16) float wg[2*C_*C_];
    __shared__ alignas(16) float wl[C_*C_];     // [c][o]
    __shared__ alignas(16) float ps[2][11*C_];
    int tid = threadIdx.x;
    {
        const float4* xp = (const float4*)(x + (size_t)bn*Tin*C_);
        float4* xd = (float4*)xs[tile];
        for (int i = lane; i < (Tin*C_)/4; i += 128) xd[i] = xp[i];
    }
    for (int i = tid; i < 2*C_*C_; i += 256) {
        int k = i / (C_*C_); int r = i % (C_*C_); int c = r / C_; int o = r % C_;
        wf[i] = fw[(o*C_+c)*2 + k];
        wg[i] = gw[(o*C_+c)*2 + k];
    }
    for (int i = tid; i < C_*C_; i += 256) wl[i] = wl0[i];
    __syncthreads();
    int nq = Tout*10;
    for (int u = lane; u < nq; u += 128) {
        int t = u/10, o = (u%10)*4;
        float4 f4 = *(const float4*)&fb4[o];
        float4 g4 = *(const float4*)&gb4[o];
        for (int c = 0; c < C_; ++c) {
            float x0v = xs[tile][t*C_+c], x2v = xs[tile][(t+2)*C_+c];
            float4 wf0 = *(const float4*)&wf[c*C_+o];
            float4 wf1 = *(const float4*)&wf[C_*C_ + c*C_+o];
            float4 wg0 = *(const float4*)&wg[c*C_+o];
            float4 wg1 = *(const float4*)&wg[C_*C_ + c*C_+o];
            f4.x += wf0.x*x0v + wf1.x*x2v;  f4.y += wf0.y*x0v + wf1.y*x2v;
            f4.z += wf0.z*x0v + wf1.z*x2v;  f4.w += wf0.w*x0v + wf1.w*x2v;
            g4.x += wg0.x*x0v + wg1.x*x2v;  g4.y += wg0.y*x0v + wg1.y*x2v;
            g4.z += wg0.z*x0v + wg1.z*x2v;  g4.w += wg0.w*x0v + wg1.w*x2v;
        }
        float4 r4;
        r4.x = tanhf(f4.x)*sigm(g4.x);
        r4.y = tanhf(f4.y)*sigm(g4.y);
        r4.z = tanhf(f4.z)*sigm(g4.z);
        r4.w = tanhf(f4.w)*sigm(g4.w);
        *(float4*)&ps[tile][t*C_+o] = r4;
        *(float4*)&xg[(size_t)bn*nout + t*C_+o] = r4;
    }
    __syncthreads();
    // gc = bias + ps @ wl
    for (int u = lane; u < nq; u += 128) {
        int t = u/10, o = (u%10)*4;
        float4 a4 = *(const float4*)&gbias[o];
        for (int c = 0; c < C_; ++c) {
            float s = ps[tile][t*C_+c];
            float4 w = *(const float4*)&wl[c*C_+o];
            a4.x += s*w.x; a4.y += s*w.y; a4.z += s*w.z; a4.w += s*w.w;
        }
        *(float4*)&gc[(size_t)bn*nout + t*C_+o] = a4;
    }
}

// ---- fused sparse graph op + gconv accumulate (2 bn tiles / block) ----
__global__ __launch_bounds__(256) void kern_sparse_acc(const float* __restrict__ in,
    float* __restrict__ outTile, int Tout,
    const int* __restrict__ ptr, const int* __restrict__ nbr, const int* __restrict__ eid,
    const float* __restrict__ aval, const float* __restrict__ coef,
    const float* __restrict__ Amat, const int* __restrict__ selfe,
    const float* __restrict__ gwp, float* __restrict__ gc)
{
    int tile = threadIdx.x >> 7;
    int lane = threadIdx.x & 127;
    int bn = blockIdx.x*2 + tile;
    int b = bn / N_, m = bn % N_;
    __shared__ float wv[2][64];
    __shared__ int   nb[2][64];
    __shared__ alignas(16) float ps[2][11*C_];
    __shared__ alignas(16) float wl[C_*C_];
    int tid = threadIdx.x;
    int p0 = ptr[m], p1 = ptr[m+1];
    int deg = p1 - p0; if (deg > 64) deg = 64;
    if (lane < deg) {
        wv[tile][lane] = coef[b*E_ + eid[p0+lane]] * aval[p0+lane];
        nb[tile][lane] = nbr[p0+lane];
    }
    for (int i = tid; i < C_*C_; i += 256) wl[i] = gwp[i];
    __syncthreads();
    float dval = (selfe[m] >= 0) ? 0.f : Amat[(size_t)m*N_ + m];
    const float* inb = in + (size_t)b*N_*Tout*C_;
    int nout = Tout*C_;
    for (int oi = lane; oi < nout; oi += 128) {
        float acc = dval * inb[(size_t)m*nout + oi];
        for (int j = 0; j < deg; ++j) acc += wv[tile][j]*inb[(size_t)nb[tile][j]*nout + oi];
        ps[tile][oi] = acc;
        if (outTile) outTile[(size_t)bn*nout + oi] = acc;
    }
    __syncthreads();
    int nq = Tout*10;
    for (int u = lane; u < nq; u += 128) {
        int t = u/10, o = (u%10)*4;
        float4 a4 = *(const float4*)&gc[(size_t)bn*nout + t*C_+o];
        for (int c = 0; c < C_; ++c) {
            float s = ps[tile][t*C_+c];
            float4 w = *(const float4*)&wl[c*C_+o];
            a4.x += s*w.x; a4.y += s*w.y; a4.z += s*w.z; a4.w += s*w.w;
        }
        *(float4*)&gc[(size_t)bn*nout + t*C_+o] = a4;
    }
}

// ---------------- dense adp operator: out[b][m,j] = sum_n adpT[m,n]*in[b][n,j], 64x128 tiles ----------------
__global__ __launch_bounds__(256) void kern_gemm_adp(const float* __restrict__ adpT,
    const float* __restrict__ xin, float* __restrict__ xout, int LD)
{
    __shared__ alignas(16) float As[16][68];
    __shared__ alignas(16) float Bs[16][132];
    int b  = blockIdx.z;
    int m0 = blockIdx.x*64;
    int j0 = blockIdx.y*128;
    const float* in_b = xin + (size_t)b*N_*LD;
    float* out_b = xout + (size_t)b*N_*LD;
    int tid = threadIdx.x;
    int tx = tid & 15, ty = tid >> 4;
    float acc[4][8] = {};
    for (int k0 = 0; k0 < N_; k0 += 16) {
        #pragma unroll
        for (int p = 0; p < 4; ++p) {
            int idx = tid + p*256;
            int kk = idx >> 6, mm = idx & 63;
            int gm = m0 + mm, gk = k0 + kk;
            As[kk][mm] = (gm < N_ && gk < N_) ? adpT[(size_t)gm*N_ + gk] : 0.f;
        }
        #pragma unroll
        for (int p = 0; p < 8; ++p) {
            int idx = tid + p*256;
            int kk = idx >> 7, jj = idx & 127;
            int gk = k0 + kk, gj = j0 + jj;
            Bs[kk][jj] = (gk < N_ && gj < LD) ? in_b[(size_t)gk*LD + gj] : 0.f;
        }
        __syncthreads();
        #pragma unroll
        for (int kk = 0; kk < 16; ++kk) {
            float4 av  = *(const float4*)&As[kk][ty*4];
            float4 bv0 = *(const float4*)&Bs[kk][tx*8];
            float4 bv1 = *(const float4*)&Bs[kk][tx*8+4];
            float a[4] = {av.x, av.y, av.z, av.w};
            float bb[8] = {bv0.x, bv0.y, bv0.z, bv0.w, bv1.x, bv1.y, bv1.z, bv1.w};
            #pragma unroll
            for (int i = 0; i < 4; ++i)
                #pragma unroll
                for (int j = 0; j < 8; ++j)
                    acc[i][j] += a[i]*bb[j];
        }
        __syncthreads();
    }
    int gjb = j0 + tx*8;
    #pragma unroll
    for (int i = 0; i < 4; ++i) {
        int gm = m0 + ty*4 + i;
        if (gm >= N_ || gjb >= LD) continue;   // LD multiple of 8 -> whole group in/out
        float4 v0 = {acc[i][0], acc[i][1], acc[i][2], acc[i][3]};
        float4 v1 = {acc[i][4], acc[i][5], acc[i][6], acc[i][7]};
        *(float4*)&out_b[(size_t)gm*LD + gjb]     = v0;
        *(float4*)&out_b[(size_t)gm*LD + gjb + 4] = v1;
    }
}

// ---------------- gconv accumulate one 40-chunk (2 bn tiles / block) ----------------
__global__ __launch_bounds__(256) void kern_gacc(const float* __restrict__ part, const float* __restrict__ gwp,
    float* __restrict__ gc, int Tout)
{
    int tile = threadIdx.x >> 7;
    int lane = threadIdx.x & 127;
    int bn = blockIdx.x*2 + tile;
    int nout = Tout*C_;
    __shared__ alignas(16) float ps[2][11*C_];
    __shared__ alignas(16) float wl[C_*C_];
    int tid = threadIdx.x;
    {
        const float4* pp = (const float4*)(part + (size_t)bn*nout);
        float4* pd = (float4*)ps[tile];
        for (int i = lane; i < nout/4; i += 128) pd[i] = pp[i];
    }
    for (int i = tid; i < C_*C_; i += 256) wl[i] = gwp[i];
    __syncthreads();
    int nq = Tout*10;
    for (int u = lane; u < nq; u += 128) {
        int t = u/10, o = (u%10)*4;
        float4 a4 = *(const float4*)&gc[(size_t)bn*nout + t*C_+o];
        for (int c = 0; c < C_; ++c) {
            float s = ps[tile][t*C_+c];
            float4 w = *(const float4*)&wl[c*C_+o];
            a4.x += s*w.x; a4.y += s*w.y; a4.z += s*w.z; a4.w += s*w.w;
        }
        *(float4*)&gc[(size_t)bn*nout + t*C_+o] = a4;
    }
}

// ---------------- BN stats per channel ----------------
__global__ __launch_bounds__(320) void kern_bnstats(const float* __restrict__ src, size_t total, float* __restrict__ acc)
{
    int tid = threadIdx.x;
    float s = 0.f, ss = 0.f;
    for (size_t i = (size_t)blockIdx.x*320 + tid; i < total; i += (size_t)gridDim.x*320) {
        float v = src[i]; s += v; ss += v*v;
    }
    __shared__ float ls[320], lss[320];
    ls[tid] = s; lss[tid] = ss; __syncthreads();
    if (tid < C_) {
        float t1 = 0.f, t2 = 0.f;
        for (int r = 0; r < 8; ++r) { t1 += ls[r*C_+tid]; t2 += lss[r*C_+tid]; }
        atomicAdd(&acc[tid], t1); atomicAdd(&acc[C_+tid], t2);
    }
}

__global__ __launch_bounds__(320) void kern_bn1(float* __restrict__ gc, const float* __restrict__ resid,
    int Tin, int Tout, const float* __restrict__ acc1,
    const float* __restrict__ g1, const float* __restrict__ b1, float* __restrict__ acc2)
{
    int tid = threadIdx.x; int c = tid % C_;
    float cnt = (float)(B_*N_*Tout);
    float mean = acc1[c]/cnt;
    float var  = acc1[C_+c]/cnt - mean*mean;
    float inv  = rsqrtf(var + EPS_);
    float gg = g1[c], bb = b1[c];
    int dlt = Tin - Tout;
    float s = 0.f, ss = 0.f;
    size_t total = (size_t)B_*N_*Tout*C_;
    for (size_t i = (size_t)blockIdx.x*320 + tid; i < total; i += (size_t)gridDim.x*320) {
        size_t pos = i / C_; int t = (int)(pos % Tout); size_t bn = pos / Tout;
        float y = gg*(gc[i]-mean)*inv + bb;
        y += resid[(bn*Tin + (t+dlt))*C_ + c];
        gc[i] = y;
        s += y; ss += y*y;
    }
    __shared__ float ls[320], lss[320];
    ls[tid] = s; lss[tid] = ss; __syncthreads();
    if (tid < C_) {
        float t1 = 0.f, t2 = 0.f;
        for (int r = 0; r < 8; ++r) { t1 += ls[r*C_+tid]; t2 += lss[r*C_+tid]; }
        atomicAdd(&acc2[tid], t1); atomicAdd(&acc2[C_+tid], t2);
    }
}

__global__ __launch_bounds__(256) void kern_bn2(const float* __restrict__ gc, float* __restrict__ xout, int Tout,
    const float* __restrict__ acc2, const float* __restrict__ g2, const float* __restrict__ b2)
{
    size_t total = (size_t)B_*N_*Tout*C_;
    size_t i = (size_t)blockIdx.x*256 + threadIdx.x;
    if (i >= total) return;
    int c = (int)(i % C_);
    float cnt = (float)(B_*N_*Tout);
    float mean = acc2[c]/cnt;
    float var  = acc2[C_+c]/cnt - mean*mean;
    float inv  = rsqrtf(var + EPS_);
    xout[i] = g2[c]*(gc[i]-mean)*inv + b2[c];
}

// ---------------- skip conv on last 7 steps -> bf16 skip(B,N,7,320) ----------------
__global__ __launch_bounds__(256) void kern_skip(const float* __restrict__ x, int Tout,
    const float* __restrict__ sw, const float* __restrict__ sbias, __hip_bfloat16* __restrict__ skp, int first)
{
    int bn = blockIdx.x; int half = blockIdx.y;
    int off = Tout - 7;
    __shared__ alignas(16) float xs[7*C_];
    __shared__ alignas(16) float wl[C_*164];    // [c][oo], stride 164 (16B aligned for o%4==0)
    int tid = threadIdx.x;
    {
        const float4* xp = (const float4*)(x + ((size_t)bn*Tout + off)*C_);
        float4* xd = (float4*)xs;
        for (int i = tid; i < (7*C_)/4; i += 256) xd[i] = xp[i];
    }
    for (int i = tid; i < 160*C_; i += 256) {
        int oo = i / C_, c = i % C_;
        wl[c*164 + oo] = sw[(size_t)(half*160 + oo)*C_ + c];
    }
    __syncthreads();
    for (int u = tid; u < 7*40; u += 256) {
        int t = u / 40, o = (u % 40)*4;
        float4 a4 = {0.f,0.f,0.f,0.f};
        for (int c = 0; c < C_; ++c) {
            float s = xs[t*C_+c];
            float4 w = *(const float4*)&wl[c*164 + o];
            a4.x += s*w.x; a4.y += s*w.y; a4.z += s*w.z; a4.w += s*w.w;
        }
        int og = half*160 + o;
        float4 b4 = *(const float4*)&sbias[og];
        a4.x += b4.x; a4.y += b4.y; a4.z += b4.z; a4.w += b4.w;
        size_t di = ((size_t)bn*7 + t)*320 + og;
        if (first) {
            skp[di+0] = __float2bfloat16(a4.x);
            skp[di+1] = __float2bfloat16(a4.y);
            skp[di+2] = __float2bfloat16(a4.z);
            skp[di+3] = __float2bfloat16(a4.w);
        } else {
            skp[di+0] = __float2bfloat16(__bfloat162float(skp[di+0]) + a4.x);
            skp[di+1] = __float2bfloat16(__bfloat162float(skp[di+1]) + a4.y);
            skp[di+2] = __float2bfloat16(__bfloat162float(skp[di+2]) + a4.z);
            skp[di+3] = __float2bfloat16(__bfloat162float(skp[di+3]) + a4.w);
        }
    }
}

// ---------------- end-stage prep: skl = lrelu(skp) (bf16), e1wb = bf16(e1w) ----------------
__global__ __launch_bounds__(256) void kern_skl(const __hip_bfloat16* __restrict__ skp, __hip_bfloat16* __restrict__ skl)
{
    size_t total = (size_t)B_*N_*7*320;
    size_t i = (size_t)blockIdx.x*256 + threadIdx.x;
    if (i >= total) return;
    float v = __bfloat162float(skp[i]);
    skl[i] = __float2bfloat16(v > 0.f ? v : 0.01f*v);
}
__global__ __launch_bounds__(256) void kern_cvtw(const float* __restrict__ w, __hip_bfloat16* __restrict__ wb, int n)
{
    int i = blockIdx.x*256 + threadIdx.x;
    if (i < n) wb[i] = __float2bfloat16(w[i]);
}

// ---------------- output init with end2 bias ----------------
__global__ void kern_oinit(float* __restrict__ out, const float* __restrict__ e2b)
{
    int i = blockIdx.x*256 + threadIdx.x;
    if (i >= B_*12*N_*7) return;
    int o = (i / (N_*7)) % 12;
    out[i] = e2b[o];
}

// ---------------- MFMA end1 (bf16) + fused end2 epilogue ----------------
// grid (10, 1750): x = c-tile (64 of 640), y = m-tile (64 of 112000). 4 waves/block, wave = 16 m rows.
__global__ __launch_bounds__(256) void kern_end_mfma(const __hip_bfloat16* __restrict__ skl,
    const __hip_bfloat16* __restrict__ e1wb, const float* __restrict__ e1b,
    const float* __restrict__ e2w, float* __restrict__ out)
{
    __shared__ alignas(16) float yl[64][68];
    __shared__ alignas(16) float w2[12][64];
    int tid = threadIdx.x;
    int wave = tid >> 6, lane = tid & 63;
    int c0 = blockIdx.x*64;
    int m0 = blockIdx.y*64;
    for (int i = tid; i < 12*64; i += 256) {
        int o = i >> 6, cc = i & 63;
        w2[o][cc] = e2w[o*640 + c0 + cc];
    }
    int rn = lane & 15;        // A: m row within 16; B: n col within 16
    int q  = lane >> 4;        // k-chunk quad
    const short* Ab = (const short*)skl  + (size_t)(m0 + wave*16 + rn)*320 + q*8;
    const short* Bb = (const short*)e1wb + (size_t)(c0 + rn)*320 + q*8;
    f32x4 acc[4] = {};
    for (int k = 0; k < 320; k += 32) {
        bf16x8 a = *(const bf16x8*)(Ab + k);
        #pragma unroll
        for (int s = 0; s < 4; ++s) {
            bf16x8 bfr = *(const bf16x8*)(Bb + (size_t)s*16*320 + k);
            acc[s] = __builtin_amdgcn_mfma_f32_16x16x32_bf16(a, bfr, acc[s], 0, 0, 0);
        }
    }
    // D layout: col = lane&15 (n), row = q*4 + r (m)
    #pragma unroll
    for (int s = 0; s < 4; ++s) {
        float bias = e1b[c0 + s*16 + rn];
        #pragma unroll
        for (int r = 0; r < 4; ++r) {
            float y = acc[s][r] + bias;
            yl[wave*16 + q*4 + r][s*16 + rn] = lrelu(y);
        }
    }
    __syncthreads();
    for (int i = tid; i < 64*12; i += 256) {
        int m = i & 63, o = i >> 6;
        float a = 0.f;
        #pragma unroll
        for (int qq = 0; qq < 16; ++qq) {
            float4 y = *(const float4*)&yl[m][qq*4];
            float4 w = *(const float4*)&w2[o][qq*4];
            a += y.x*w.x + y.y*w.y + y.z*w.z + y.w*w.w;
        }
        int gm = m0 + m;
        int t = gm % 7; int bn = gm / 7; int n = bn % N_; int b = bn / N_;
        atomicAdd(&out[(((size_t)b*12 + o)*N_ + n)*7 + t], a);
    }
}

extern "C" void kernel_launch(void* const* d_in, const int* in_sizes, int n_in,
                              void* d_out, int out_size, void* d_ws, size_t ws_size,
                              hipStream_t stream)
{
    (void)in_sizes; (void)n_in; (void)out_size;
    const float* input   = (const float*)d_in[0];
    const float* A_fwd   = (const float*)d_in[1];
    const float* A_bwd   = (const float*)d_in[2];
    const int*   indices = (const int*)  d_in[3];
    const float* G0      = (const float*)d_in[4];
    const float* G1      = (const float*)d_in[5];
    const float* nv1     = (const float*)d_in[6];
    const float* nv2     = (const float*)d_in[7];
    const float* wef     = (const float*)d_in[8];
    const float* web     = (const float*)d_in[9];
    const float* vsf     = (const float*)d_in[10];
    const float* vdf     = (const float*)d_in[11];
    const float* vsb     = (const float*)d_in[12];
    const float* vdb     = (const float*)d_in[13];
    const float* start_w = (const float*)d_in[14];
    const float* start_b = (const float*)d_in[15];
    const float* filt_w  = (const float*)d_in[16];
    const float* filt_b  = (const float*)d_in[17];
    const float* gate_w  = (const float*)d_in[18];
    const float* gate_b  = (const float*)d_in[19];
    const float* gcw     = (const float*)d_in[20];
    const float* gcb     = (const float*)d_in[21];
    const float* bng_g   = (const float*)d_in[22];
    const float* bng_b   = (const float*)d_in[23];
    const float* bn_g    = (const float*)d_in[24];
    const float* bn_b    = (const float*)d_in[25];
    const float* skw     = (const float*)d_in[26];
    const float* skb     = (const float*)d_in[27];
    const float* e1w     = (const float*)d_in[28];
    const float* e1b     = (const float*)d_in[29];
    const float* e2w     = (const float*)d_in[30];
    const float* e2b     = (const float*)d_in[31];
    float* out = (float*)d_out;

    // ---- workspace layout (4B units, 16B-aligned allocations) ----
    float* W = (float*)d_ws;
    size_t off = 0;
    auto FA = [&](size_t n){ off = (off + 3) & ~(size_t)3; float* p = W + off; off += n; return p; };
    float* insum  = FA(2);
    float* tf     = FA((size_t)B_*EH_);
    float* tb     = FA((size_t)B_*EH_);
    float* bnacc1 = FA(80);
    float* bnacc2 = FA(80);
    float* usf = FA((size_t)B_*N_); float* udf = FA((size_t)B_*N_);
    float* usb = FA((size_t)B_*N_); float* udb = FA((size_t)B_*N_);
    float* scf = FA((size_t)B_*E_); float* scb = FA((size_t)B_*E_);
    float* efv = FA((size_t)B_*E_); float* ebv = FA((size_t)B_*E_);
    float* adpT = FA((size_t)N_*N_);
    float* a0v = FA(E_); float* a1v = FA(E_);
    int* map  = (int*)FA((size_t)N_*N_);
    int* cnt0 = (int*)FA(512); int* cnt1 = (int*)FA(512);
    int* ptr0 = (int*)FA(512); int* ptr1 = (int*)FA(512);
    int* cur0 = (int*)FA(512); int* cur1 = (int*)FA(512);
    int* selfe = (int*)FA(512);
    int* e0id = (int*)FA(E_); int* e0nb = (int*)FA(E_);
    int* e1id = (int*)FA(E_); int* e1nb = (int*)FA(E_);
    float* xA  = FA((size_t)B_*N_*T0_*C_);
    float* xg  = FA((size_t)B_*N_*11*C_);      // also start of end-stage scratch overlay
    float* pa  = FA((size_t)B_*N_*11*C_);
    float* gc  = FA((size_t)B_*N_*11*C_);
    __hip_bfloat16* skp = (__hip_bfloat16*)FA((size_t)B_*N_*7*320/2);
    // end-stage overlay: xg/pa/gc region = 3*7,040,000 = 21.12M floats, dead after block loop
    __hip_bfloat16* skl  = (__hip_bfloat16*)xg;                 // 35.84M bf16 = 17.92M floats
    __hip_bfloat16* e1wb = (__hip_bfloat16*)(xg + 18000000);    // 204800 bf16

    if (ws_size < off*sizeof(float)) return;   // fail cleanly, not a fault

    // ---- setup ----
    kern_init<<<(N_*N_+255)/256, 256, 0, stream>>>(insum, map, cnt0, selfe);
    kern_instats<<<256, 256, 0, stream>>>(input, insum);
    kern_x0<<<(B_*N_*T0_*C_+255)/256, 256, 0, stream>>>(input, insum, start_w, start_b, xA);
    kern_adp<<<N_, 512, 0, stream>>>(nv1, nv2, adpT);
    kern_emax<<<(E_+255)/256, 256, 0, stream>>>(indices, map);
    kern_ecnt<<<(E_+255)/256, 256, 0, stream>>>(indices, map, cnt0, cnt1, selfe);
    kern_scan<<<1, 512, 0, stream>>>(cnt0, cnt1, ptr0, ptr1, cur0, cur1);
    kern_efill<<<(E_+255)/256, 256, 0, stream>>>(indices, map, A_fwd, A_bwd, cur0, cur1,
                                                 e0id, e0nb, a0v, e1id, e1nb, a1v);

    // ---- 3 blocks ----
    for (int blk = 0; blk < 3; ++blk) {
        int Tin = T0_ - 2*blk;
        int Tout = Tin - 2;
        size_t total = (size_t)B_*N_*Tout*C_;
        kern_zeroacc<<<(2*B_*EH_+160+255)/256, 256, 0, stream>>>(tf, 2*B_*EH_+160);

        kern_umean<<<B_*N_, 64, 0, stream>>>(xA, Tin, vsf+blk*C_, vdf+blk*C_, vsb+blk*C_, vdb+blk*C_,
                                             usf, udf, usb, udb);
        kern_sc<<<(B_*E_+255)/256, 256, 0, stream>>>(indices, usf, udf, usb, udb, scf, scb);
        kern_t<<<dim3(B_, 8), 320, 0, stream>>>(scf, scb, G0, tf, tb);
        kern_ef<<<dim3(8, B_), 256, 0, stream>>>(tf, tb, wef, web, G1, efv, ebv);

        const float* gwb = gcw + (size_t)blk*7*C_*C_;
        // dconv + gate + gconv chunk0 (bias) fused
        kern_dconv_acc<<<B_*N_/2, 256, 0, stream>>>(xA, Tin,
            filt_w + (size_t)blk*2*C_*C_, filt_b + blk*C_,
            gate_w + (size_t)blk*2*C_*C_, gate_b + blk*C_,
            gwb + 0*C_*C_, gcb + blk*C_, xg, gc);
        // s0 two hops
        kern_sparse_acc<<<B_*N_/2, 256, 0, stream>>>(xg, pa, Tout, ptr1, e0nb, e0id, a0v, efv,
                                                     A_fwd, selfe, gwb + 1*C_*C_, gc);
        kern_sparse_acc<<<B_*N_/2, 256, 0, stream>>>(pa, nullptr, Tout, ptr1, e0nb, e0id, a0v, efv,
                                                     A_fwd, selfe, gwb + 2*C_*C_, gc);
        // s1 two hops
        kern_sparse_acc<<<B_*N_/2, 256, 0, stream>>>(xg, pa, Tout, ptr0, e1nb, e1id, a1v, ebv,
                                                     A_bwd, selfe, gwb + 3*C_*C_, gc);
        kern_sparse_acc<<<B_*N_/2, 256, 0, stream>>>(pa, nullptr, Tout, ptr0, e1nb, e1id, a1v, ebv,
                                                     A_bwd, selfe, gwb + 4*C_*C_, gc);
        // adp two dense hops; hop2 writes into xg (dead after hop1)
        int LD = Tout*C_;
        dim3 gg(8, (LD+127)/128, B_);
        kern_gemm_adp<<<gg, 256, 0, stream>>>(adpT, xg, pa, LD);
        kern_gacc<<<B_*N_/2, 256, 0, stream>>>(pa, gwb + 5*C_*C_, gc, Tout);
        kern_gemm_adp<<<gg, 256, 0, stream>>>(adpT, pa, xg, LD);
        kern_gacc<<<B_*N_/2, 256, 0, stream>>>(xg, gwb + 6*C_*C_, gc, Tout);

        kern_bnstats<<<512, 320, 0, stream>>>(gc, total, bnacc1);
        kern_bn1<<<512, 320, 0, stream>>>(gc, xA, Tin, Tout, bnacc1, bng_g + blk*C_, bng_b + blk*C_, bnacc2);
        kern_bn2<<<(int)((total+255)/256), 256, 0, stream>>>(gc, xA, Tout, bnacc2, bn_g + blk*C_, bn_b + blk*C_);

        kern_skip<<<dim3(B_*N_, 2), 256, 0, stream>>>(xA, Tout, skw + (size_t)blk*320*C_, skb + blk*320,
                                                      skp, blk == 0 ? 1 : 0);
    }

    // ---- end stage: prep + MFMA ----
    kern_skl<<<(int)(((size_t)B_*N_*7*320 + 255)/256), 256, 0, stream>>>(skp, skl);
    kern_cvtw<<<(640*320+255)/256, 256, 0, stream>>>(e1w, e1wb, 640*320);
    kern_oinit<<<(B_*12*N_*7+255)/256, 256, 0, stream>>>(out, e2b);
    kern_end_mfma<<<dim3(10, B_*N_*7/64), 256, 0, stream>>>(skl, e1wb, e1b, e2w, out);
}

// Round 4
// 2709.965 us; speedup vs baseline: 1.7728x; 1.4487x over previous
//
#include <hip/hip_runtime.h>
#include <hip/hip_bf16.h>

constexpr int B_  = 32;
constexpr int N_  = 500;
constexpr int T0_ = 13;
constexpr int E_  = 2000;
constexpr int EH_ = 300;
constexpr int C_  = 40;
constexpr float EPS_ = 1e-5f;
constexpr int KP_ = 512;     // padded node dim for MFMA adp gemm

typedef short bf16x8 __attribute__((ext_vector_type(8)));
typedef _Float16 f16x8 __attribute__((ext_vector_type(8)));
typedef float f32x4  __attribute__((ext_vector_type(4)));

__device__ __forceinline__ float sigm(float x){ return 1.f/(1.f+__expf(-x)); }
__device__ __forceinline__ float lrelu(float x){ return x > 0.f ? x : 0.01f*x; }
__device__ __forceinline__ unsigned short f2bf(float f){
    __hip_bfloat16 h = __float2bfloat16(f);
    return *(unsigned short*)&h;
}

// ---------------- init: zero/flag all small state ----------------
__global__ __launch_bounds__(256) void kern_init(float* __restrict__ insum, int* __restrict__ map,
                                                 int* __restrict__ cnts, int* __restrict__ selfe,
                                                 int* __restrict__ adpTbz)
{
    int i = blockIdx.x*256 + threadIdx.x;
    if (i < 2) insum[i] = 0.f;
    if (i < N_*N_) map[i] = -1;
    if (i < 1024) cnts[i] = 0;
    if (i < 512) selfe[i] = -1;
    if (i < KP_*KP_/2) adpTbz[i] = 0;
}

__global__ __launch_bounds__(256) void kern_zeroacc(float* __restrict__ p, int n)
{
    int i = blockIdx.x*256 + threadIdx.x;
    if (i < n) p[i] = 0.f;
}

// ---------------- input BN stats ----------------
__global__ __launch_bounds__(256) void kern_instats(const float* __restrict__ in, float* __restrict__ acc)
{
    float s = 0.f, ss = 0.f;
    int total = B_*N_*T0_;
    for (int i = blockIdx.x*256 + threadIdx.x; i < total; i += gridDim.x*256) {
        float v = in[i]; s += v; ss += v*v;
    }
    __shared__ float l1[256], l2[256];
    l1[threadIdx.x] = s; l2[threadIdx.x] = ss; __syncthreads();
    for (int o = 128; o > 0; o >>= 1) {
        if (threadIdx.x < o) { l1[threadIdx.x] += l1[threadIdx.x+o]; l2[threadIdx.x] += l2[threadIdx.x+o]; }
        __syncthreads();
    }
    if (threadIdx.x == 0) { atomicAdd(&acc[0], l1[0]); atomicAdd(&acc[1], l2[0]); }
}

// ---------------- normalize + start conv -> x (B,N,T,C) ----------------
__global__ __launch_bounds__(256) void kern_x0(const float* __restrict__ in, const float* __restrict__ insum,
    const float* __restrict__ sw, const float* __restrict__ sb, float* __restrict__ x)
{
    int idx = blockIdx.x*256 + threadIdx.x;
    int total = B_*N_*T0_*C_;
    if (idx >= total) return;
    float cnt = (float)(B_*N_*T0_);
    float mean = insum[0]/cnt;
    float var  = insum[1]/cnt - mean*mean;
    float inv  = rsqrtf(var + EPS_);
    int c = idx % C_;
    int pos = idx / C_;
    float xn = (in[pos] - mean)*inv;
    x[idx] = sw[c]*xn + sb[c];
}

// ---------------- adp = softmax(relu(nv1@nv2), axis=1), stored transposed bf16 padded ----------------
__global__ __launch_bounds__(512) void kern_adp(const float* __restrict__ nv1, const float* __restrict__ nv2,
                                                __hip_bfloat16* __restrict__ adpTb)
{
    int n = blockIdx.x;
    int m = threadIdx.x;
    float r = 0.f;
    if (m < N_) {
        #pragma unroll
        for (int k = 0; k < 10; ++k) r += nv1[n*10+k]*nv2[k*N_+m];
        r = r > 0.f ? r : 0.f;
    }
    __shared__ float red[512];
    red[threadIdx.x] = (m < N_) ? r : -1e30f; __syncthreads();
    for (int o = 256; o > 0; o >>= 1) {
        if (threadIdx.x < o) red[threadIdx.x] = fmaxf(red[threadIdx.x], red[threadIdx.x+o]);
        __syncthreads();
    }
    float mx = red[0]; __syncthreads();
    float ev = (m < N_) ? __expf(r - mx) : 0.f;
    red[threadIdx.x] = ev; __syncthreads();
    for (int o = 256; o > 0; o >>= 1) {
        if (threadIdx.x < o) red[threadIdx.x] += red[threadIdx.x+o];
        __syncthreads();
    }
    float sum = red[0];
    if (m < N_) adpTb[(size_t)m*KP_ + n] = __float2bfloat16(ev/sum);
}

// ---------------- edge preprocessing ----------------
__global__ void kern_emax(const int* __restrict__ idx, int* __restrict__ map)
{
    int e = blockIdx.x*256 + threadIdx.x;
    if (e < E_) atomicMax(&map[idx[e]*N_ + idx[E_+e]], e);
}
__global__ void kern_ecnt(const int* __restrict__ idx, const int* __restrict__ map,
                          int* __restrict__ cnt0, int* __restrict__ cnt1, int* __restrict__ selfe)
{
    int e = blockIdx.x*256 + threadIdx.x;
    if (e >= E_) return;
    int i0 = idx[e], i1 = idx[E_+e];
    if (map[i0*N_+i1] != e) return;
    atomicAdd(&cnt1[i1], 1);
    atomicAdd(&cnt0[i0], 1);
    if (i0 == i1) selfe[i0] = e;
}
__global__ __launch_bounds__(512) void kern_scan(const int* __restrict__ cnt0, const int* __restrict__ cnt1,
    int* __restrict__ ptr0, int* __restrict__ ptr1, int* __restrict__ cur0, int* __restrict__ cur1)
{
    __shared__ int s0[512], s1[512];
    int tid = threadIdx.x;
    s0[tid] = (tid < N_) ? cnt0[tid] : 0;
    s1[tid] = (tid < N_) ? cnt1[tid] : 0;
    __syncthreads();
    for (int o = 1; o < 512; o <<= 1) {
        int v0 = (tid >= o) ? s0[tid-o] : 0;
        int v1 = (tid >= o) ? s1[tid-o] : 0;
        __syncthreads();
        s0[tid] += v0; s1[tid] += v1;
        __syncthreads();
    }
    if (tid == 0) { ptr0[0] = 0; ptr1[0] = 0; }
    if (tid < N_) {
        ptr0[tid+1] = s0[tid]; ptr1[tid+1] = s1[tid];
        cur0[tid] = (tid == 0) ? 0 : s0[tid-1];
        cur1[tid] = (tid == 0) ? 0 : s1[tid-1];
    }
}
__global__ void kern_efill(const int* __restrict__ idx, const int* __restrict__ map,
    const float* __restrict__ Af, const float* __restrict__ Ab,
    int* __restrict__ cur0, int* __restrict__ cur1,
    int* __restrict__ e0id, int* __restrict__ e0nb, float* __restrict__ a0v,
    int* __restrict__ e1id, int* __restrict__ e1nb, float* __restrict__ a1v)
{
    int e = blockIdx.x*256 + threadIdx.x;
    if (e >= E_) return;
    int i0 = idx[e], i1 = idx[E_+e];
    if (map[i0*N_+i1] != e) return;
    int s1 = atomicAdd(&cur1[i1], 1);
    e0id[s1] = e; e0nb[s1] = i0; a0v[s1] = Af[i0*N_+i1];
    int s0 = atomicAdd(&cur0[i0], 1);
    e1id[s0] = e; e1nb[s0] = i1; a1v[s0] = Ab[i1*N_+i0];
}

// ---------------- per-(b,n) mean over t, dotted with 4 C-vectors ----------------
__global__ __launch_bounds__(64) void kern_umean(const float* __restrict__ x, int Tin,
    const float* __restrict__ vsf, const float* __restrict__ vdf,
    const float* __restrict__ vsb, const float* __restrict__ vdb,
    float* __restrict__ usf, float* __restrict__ udf, float* __restrict__ usb, float* __restrict__ udb)
{
    int bn = blockIdx.x;
    const float* xp = x + (size_t)bn*Tin*C_;
    int tid = threadIdx.x;
    float a0=0.f,a1=0.f,a2=0.f,a3=0.f;
    for (int i = tid; i < Tin*C_; i += 64) {
        float v = xp[i]; int c = i % C_;
        a0 += v*vsf[c]; a1 += v*vdf[c]; a2 += v*vsb[c]; a3 += v*vdb[c];
    }
    for (int o = 32; o > 0; o >>= 1) {
        a0 += __shfl_down(a0,o); a1 += __shfl_down(a1,o);
        a2 += __shfl_down(a2,o); a3 += __shfl_down(a3,o);
    }
    if (tid == 0) {
        float inv = 1.f/(float)Tin;
        usf[bn]=a0*inv; udf[bn]=a1*inv; usb[bn]=a2*inv; udb[bn]=a3*inv;
    }
}

__global__ void kern_sc(const int* __restrict__ idx,
    const float* __restrict__ usf, const float* __restrict__ udf,
    const float* __restrict__ usb, const float* __restrict__ udb,
    float* __restrict__ scf, float* __restrict__ scb)
{
    int i = blockIdx.x*256 + threadIdx.x;
    if (i >= B_*E_) return;
    int b = i / E_, e = i % E_;
    int i0 = idx[e], i1 = idx[E_+e];
    scf[i] = usf[b*N_+i0] + udf[b*N_+i1];
    scb[i] = usb[b*N_+i0] + udb[b*N_+i1];
}

__global__ __launch_bounds__(320) void kern_t(const float* __restrict__ scf, const float* __restrict__ scb,
    const float* __restrict__ G0, float* __restrict__ tf, float* __restrict__ tb)
{
    int b = blockIdx.x, chunk = blockIdx.y;
    int e0 = chunk*250;
    __shared__ float sf[250], sb2[250];
    int tid = threadIdx.x;
    for (int i = tid; i < 250; i += 320) { sf[i] = scf[b*E_+e0+i]; sb2[i] = scb[b*E_+e0+i]; }
    __syncthreads();
    if (tid < EH_) {
        float af = 0.f, ab = 0.f;
        for (int i = 0; i < 250; ++i) {
            float g = G0[(size_t)(e0+i)*EH_ + tid];
            af += sf[i]*g; ab += sb2[i]*g;
        }
        atomicAdd(&tf[b*EH_+tid], af);
        atomicAdd(&tb[b*EH_+tid], ab);
    }
}

__global__ __launch_bounds__(256) void kern_ef(const float* __restrict__ tf, const float* __restrict__ tb,
    const float* __restrict__ wf, const float* __restrict__ wb, const float* __restrict__ G1,
    float* __restrict__ ef, float* __restrict__ eb)
{
    int b = blockIdx.y;
    int e = blockIdx.x*256 + threadIdx.x;
    __shared__ float f[EH_], g[EH_];
    for (int i = threadIdx.x; i < EH_; i += 256) {
        f[i] = tf[b*EH_+i]*wf[i];
        g[i] = tb[b*EH_+i]*wb[i];
    }
    __syncthreads();
    if (e < E_) {
        float af = 0.f, ab = 0.f;
        for (int h = 0; h < EH_; ++h) {
            float v = G1[(size_t)h*E_ + e];
            af += f[h]*v; ab += g[h]*v;
        }
        ef[b*E_+e] = sigm(af);
        eb[b*E_+e] = sigm(ab);
    }
}

// ---------------- dilated conv + gate, fused with gconv chunk0; also writes transposed bf16 xgT ----------------
__global__ __launch_bounds__(256) void kern_dconv_acc(const float* __restrict__ x, int Tin,
    const float* __restrict__ fw, const float* __restrict__ fb4,
    const float* __restrict__ gw, const float* __restrict__ gb4,
    const float* __restrict__ wl0, const float* __restrict__ gbias,
    float* __restrict__ xg, float* __restrict__ gc,
    __hip_bfloat16* __restrict__ xgT, int JP)
{
    int Tout = Tin - 2;
    int nout = Tout*C_;
    int tile = threadIdx.x >> 7;
    int lane = threadIdx.x & 127;
    int bn = blockIdx.x*2 + tile;
    int b = bn / N_, n = bn % N_;
    __shared__ alignas(16) float xs[2][T0_*C_];
    __shared__ alignas(16) float wf[2*C_*C_];
    __shared__ alignas(16) float wg[2*C_*C_];
    __shared__ alignas(16) float wl[C_*C_];
    __shared__ alignas(16) float ps[2][11*C_];
    int tid = threadIdx.x;
    {
        const float4* xp = (const float4*)(x + (size_t)bn*Tin*C_);
        float4* xd = (float4*)xs[tile];
        for (int i = lane; i < (Tin*C_)/4; i += 128) xd[i] = xp[i];
    }
    for (int i = tid; i < 2*C_*C_; i += 256) {
        int k = i / (C_*C_); int r = i % (C_*C_); int c = r / C_; int o = r % C_;
        wf[i] = fw[(o*C_+c)*2 + k];
        wg[i] = gw[(o*C_+c)*2 + k];
    }
    for (int i = tid; i < C_*C_; i += 256) wl[i] = wl0[i];
    __syncthreads();
    int nq = Tout*10;
    for (int u = lane; u < nq; u += 128) {
        int t = u/10, o = (u%10)*4;
        float4 f4 = *(const float4*)&fb4[o];
        float4 g4 = *(const float4*)&gb4[o];
        for (int c = 0; c < C_; ++c) {
            float x0v = xs[tile][t*C_+c], x2v = xs[tile][(t+2)*C_+c];
            float4 wf0 = *(const float4*)&wf[c*C_+o];
            float4 wf1 = *(const float4*)&wf[C_*C_ + c*C_+o];
            float4 wg0 = *(const float4*)&wg[c*C_+o];
            float4 wg1 = *(const float4*)&wg[C_*C_ + c*C_+o];
            f4.x += wf0.x*x0v + wf1.x*x2v;  f4.y += wf0.y*x0v + wf1.y*x2v;
            f4.z += wf0.z*x0v + wf1.z*x2v;  f4.w += wf0.w*x0v + wf1.w*x2v;
            g4.x += wg0.x*x0v + wg1.x*x2v;  g4.y += wg0.y*x0v + wg1.y*x2v;
            g4.z += wg0.z*x0v + wg1.z*x2v;  g4.w += wg0.w*x0v + wg1.w*x2v;
        }
        float4 r4;
        r4.x = tanhf(f4.x)*sigm(g4.x);
        r4.y = tanhf(f4.y)*sigm(g4.y);
        r4.z = tanhf(f4.z)*sigm(g4.z);
        r4.w = tanhf(f4.w)*sigm(g4.w);
        *(float4*)&ps[tile][t*C_+o] = r4;
        *(float4*)&xg[(size_t)bn*nout + t*C_+o] = r4;
        int j = t*C_+o;
        size_t tb = ((size_t)b*JP + j)*KP_ + n;
        xgT[tb]          = __float2bfloat16(r4.x);
        xgT[tb + KP_]    = __float2bfloat16(r4.y);
        xgT[tb + 2*KP_]  = __float2bfloat16(r4.z);
        xgT[tb + 3*KP_]  = __float2bfloat16(r4.w);
    }
    __syncthreads();
    for (int u = lane; u < nq; u += 128) {
        int t = u/10, o = (u%10)*4;
        float4 a4 = *(const float4*)&gbias[o];
        for (int c = 0; c < C_; ++c) {
            float s = ps[tile][t*C_+c];
            float4 w = *(const float4*)&wl[c*C_+o];
            a4.x += s*w.x; a4.y += s*w.y; a4.z += s*w.z; a4.w += s*w.w;
        }
        *(float4*)&gc[(size_t)bn*nout + t*C_+o] = a4;
    }
}

// ---- fused sparse graph op + gconv accumulate (2 bn tiles / block) ----
__global__ __launch_bounds__(256) void kern_sparse_acc(const float* __restrict__ in,
    float* __restrict__ outTile, int Tout,
    const int* __restrict__ ptr, const int* __restrict__ nbr, const int* __restrict__ eid,
    const float* __restrict__ aval, const float* __restrict__ coef,
    const float* __restrict__ Amat, const int* __restrict__ selfe,
    const float* __restrict__ gwp, float* __restrict__ gc)
{
    int tile = threadIdx.x >> 7;
    int lane = threadIdx.x & 127;
    int bn = blockIdx.x*2 + tile;
    int b = bn / N_, m = bn % N_;
    __shared__ float wv[2][64];
    __shared__ int   nb[2][64];
    __shared__ alignas(16) float ps[2][11*C_];
    __shared__ alignas(16) float wl[C_*C_];
    int tid = threadIdx.x;
    int p0 = ptr[m], p1 = ptr[m+1];
    int deg = p1 - p0; if (deg > 64) deg = 64;
    if (lane < deg) {
        wv[tile][lane] = coef[b*E_ + eid[p0+lane]] * aval[p0+lane];
        nb[tile][lane] = nbr[p0+lane];
    }
    for (int i = tid; i < C_*C_; i += 256) wl[i] = gwp[i];
    __syncthreads();
    float dval = (selfe[m] >= 0) ? 0.f : Amat[(size_t)m*N_ + m];
    const float* inb = in + (size_t)b*N_*Tout*C_;
    int nout = Tout*C_;
    for (int oi = lane; oi < nout; oi += 128) {
        float acc = dval * inb[(size_t)m*nout + oi];
        for (int j = 0; j < deg; ++j) acc += wv[tile][j]*inb[(size_t)nb[tile][j]*nout + oi];
        ps[tile][oi] = acc;
        if (outTile) outTile[(size_t)bn*nout + oi] = acc;
    }
    __syncthreads();
    int nq = Tout*10;
    for (int u = lane; u < nq; u += 128) {
        int t = u/10, o = (u%10)*4;
        float4 a4 = *(const float4*)&gc[(size_t)bn*nout + t*C_+o];
        for (int c = 0; c < C_; ++c) {
            float s = ps[tile][t*C_+c];
            float4 w = *(const float4*)&wl[c*C_+o];
            a4.x += s*w.x; a4.y += s*w.y; a4.z += s*w.z; a4.w += s*w.w;
        }
        *(float4*)&gc[(size_t)bn*nout + t*C_+o] = a4;
    }
}

// ---------------- adp dense hop via MFMA bf16 ----------------
// out[b][m][j] = sum_n adpTb[m][n]*inT[b][j][n]; optional fp32 out + transposed bf16 out
__global__ __launch_bounds__(256) void kern_gemm_mfma(const __hip_bfloat16* __restrict__ adpTb,
    const __hip_bfloat16* __restrict__ inT, float* __restrict__ outF,
    __hip_bfloat16* __restrict__ outT, int LD, int JP)
{
    int tid = threadIdx.x;
    int wave = tid >> 6, lane = tid & 63;
    int rn = lane & 15, q = lane >> 4;
    int b = blockIdx.z;
    int m0 = blockIdx.x*64;
    int j0 = blockIdx.y*64;
    const short* Ap = (const short*)adpTb + (size_t)(m0 + wave*16 + rn)*KP_ + q*8;
    const short* Bp = (const short*)inT + ((size_t)b*JP + j0 + rn)*KP_ + q*8;
    f32x4 acc[4] = {};
    for (int k = 0; k < KP_; k += 32) {
        bf16x8 a = *(const bf16x8*)(Ap + k);
        #pragma unroll
        for (int s = 0; s < 4; ++s) {
            bf16x8 bb = *(const bf16x8*)(Bp + (size_t)s*16*KP_ + k);
            acc[s] = __builtin_amdgcn_mfma_f32_16x16x32_bf16(a, bb, acc[s], 0, 0, 0);
        }
    }
    int mb = m0 + wave*16 + q*4;     // D row base
    #pragma unroll
    for (int s = 0; s < 4; ++s) {
        int j = j0 + s*16 + rn;      // D col
        if (j >= LD) continue;
        #pragma unroll
        for (int r = 0; r < 4; ++r) {
            int m = mb + r;
            if (m < N_) outF[((size_t)b*N_ + m)*LD + j] = acc[s][r];
        }
        if (outT) {
            ushort4 v;
            v.x = f2bf(acc[s][0]); v.y = f2bf(acc[s][1]);
            v.z = f2bf(acc[s][2]); v.w = f2bf(acc[s][3]);
            *(ushort4*)((unsigned short*)outT + ((size_t)b*JP + j)*KP_ + mb) = v;
        }
    }
}

// ---------------- gconv accumulate one 40-chunk (2 bn tiles / block) ----------------
__global__ __launch_bounds__(256) void kern_gacc(const float* __restrict__ part, const float* __restrict__ gwp,
    float* __restrict__ gc, int Tout)
{
    int tile = threadIdx.x >> 7;
    int lane = threadIdx.x & 127;
    int bn = blockIdx.x*2 + tile;
    int nout = Tout*C_;
    __shared__ alignas(16) float ps[2][11*C_];
    __shared__ alignas(16) float wl[C_*C_];
    int tid = threadIdx.x;
    {
        const float4* pp = (const float4*)(part + (size_t)bn*nout);
        float4* pd = (float4*)ps[tile];
        for (int i = lane; i < nout/4; i += 128) pd[i] = pp[i];
    }
    for (int i = tid; i < C_*C_; i += 256) wl[i] = gwp[i];
    __syncthreads();
    int nq = Tout*10;
    for (int u = lane; u < nq; u += 128) {
        int t = u/10, o = (u%10)*4;
        float4 a4 = *(const float4*)&gc[(size_t)bn*nout + t*C_+o];
        for (int c = 0; c < C_; ++c) {
            float s = ps[tile][t*C_+c];
            float4 w = *(const float4*)&wl[c*C_+o];
            a4.x += s*w.x; a4.y += s*w.y; a4.z += s*w.z; a4.w += s*w.w;
        }
        *(float4*)&gc[(size_t)bn*nout + t*C_+o] = a4;
    }
}

// ---------------- BN stats per channel ----------------
__global__ __launch_bounds__(320) void kern_bnstats(const float* __restrict__ src, size_t total, float* __restrict__ acc)
{
    int tid = threadIdx.x;
    float s = 0.f, ss = 0.f;
    for (size_t i = (size_t)blockIdx.x*320 + tid; i < total; i += (size_t)gridDim.x*320) {
        float v = src[i]; s += v; ss += v*v;
    }
    __shared__ float ls[320], lss[320];
    ls[tid] = s; lss[tid] = ss; __syncthreads();
    if (tid < C_) {
        float t1 = 0.f, t2 = 0.f;
        for (int r = 0; r < 8; ++r) { t1 += ls[r*C_+tid]; t2 += lss[r*C_+tid]; }
        atomicAdd(&acc[tid], t1); atomicAdd(&acc[C_+tid], t2);
    }
}

__global__ __launch_bounds__(320) void kern_bn1(float* __restrict__ gc, const float* __restrict__ resid,
    int Tin, int Tout, const float* __restrict__ acc1,
    const float* __restrict__ g1, const float* __restrict__ b1, float* __restrict__ acc2)
{
    int tid = threadIdx.x; int c = tid % C_;
    float cnt = (float)(B_*N_*Tout);
    float mean = acc1[c]/cnt;
    float var  = acc1[C_+c]/cnt - mean*mean;
    float inv  = rsqrtf(var + EPS_);
    float gg = g1[c], bb = b1[c];
    int dlt = Tin - Tout;
    float s = 0.f, ss = 0.f;
    size_t total = (size_t)B_*N_*Tout*C_;
    for (size_t i = (size_t)blockIdx.x*320 + tid; i < total; i += (size_t)gridDim.x*320) {
        size_t pos = i / C_; int t = (int)(pos % Tout); size_t bn = pos / Tout;
        float y = gg*(gc[i]-mean)*inv + bb;
        y += resid[(bn*Tin + (t+dlt))*C_ + c];
        gc[i] = y;
        s += y; ss += y*y;
    }
    __shared__ float ls[320], lss[320];
    ls[tid] = s; lss[tid] = ss; __syncthreads();
    if (tid < C_) {
        float t1 = 0.f, t2 = 0.f;
        for (int r = 0; r < 8; ++r) { t1 += ls[r*C_+tid]; t2 += lss[r*C_+tid]; }
        atomicAdd(&acc2[tid], t1); atomicAdd(&acc2[C_+tid], t2);
    }
}

__global__ __launch_bounds__(256) void kern_bn2(const float* __restrict__ gc, float* __restrict__ xout, int Tout,
    const float* __restrict__ acc2, const float* __restrict__ g2, const float* __restrict__ b2)
{
    size_t total = (size_t)B_*N_*Tout*C_;
    size_t i = (size_t)blockIdx.x*256 + threadIdx.x;
    if (i >= total) return;
    int c = (int)(i % C_);
    float cnt = (float)(B_*N_*Tout);
    float mean = acc2[c]/cnt;
    float var  = acc2[C_+c]/cnt - mean*mean;
    float inv  = rsqrtf(var + EPS_);
    xout[i] = g2[c]*(gc[i]-mean)*inv + b2[c];
}

// ---------------- skip conv on last 7 steps -> bf16 skip(B,N,7,320) ----------------
__global__ __launch_bounds__(256) void kern_skip(const float* __restrict__ x, int Tout,
    const float* __restrict__ sw, const float* __restrict__ sbias, __hip_bfloat16* __restrict__ skp, int first)
{
    int bn = blockIdx.x; int half = blockIdx.y;
    int off = Tout - 7;
    __shared__ alignas(16) float xs[7*C_];
    __shared__ alignas(16) float wl[C_*164];
    int tid = threadIdx.x;
    {
        const float4* xp = (const float4*)(x + ((size_t)bn*Tout + off)*C_);
        float4* xd = (float4*)xs;
        for (int i = tid; i < (7*C_)/4; i += 256) xd[i] = xp[i];
    }
    for (int i = tid; i < 160*C_; i += 256) {
        int oo = i / C_, c = i % C_;
        wl[c*164 + oo] = sw[(size_t)(half*160 + oo)*C_ + c];
    }
    __syncthreads();
    for (int u = tid; u < 7*40; u += 256) {
        int t = u / 40, o = (u % 40)*4;
        float4 a4 = {0.f,0.f,0.f,0.f};
        for (int c = 0; c < C_; ++c) {
            float s = xs[t*C_+c];
            float4 w = *(const float4*)&wl[c*164 + o];
            a4.x += s*w.x; a4.y += s*w.y; a4.z += s*w.z; a4.w += s*w.w;
        }
        int og = half*160 + o;
        float4 b4 = *(const float4*)&sbias[og];
        a4.x += b4.x; a4.y += b4.y; a4.z += b4.z; a4.w += b4.w;
        size_t di = ((size_t)bn*7 + t)*320 + og;
        if (first) {
            skp[di+0] = __float2bfloat16(a4.x);
            skp[di+1] = __float2bfloat16(a4.y);
            skp[di+2] = __float2bfloat16(a4.z);
            skp[di+3] = __float2bfloat16(a4.w);
        } else {
            skp[di+0] = __float2bfloat16(__bfloat162float(skp[di+0]) + a4.x);
            skp[di+1] = __float2bfloat16(__bfloat162float(skp[di+1]) + a4.y);
            skp[di+2] = __float2bfloat16(__bfloat162float(skp[di+2]) + a4.z);
            skp[di+3] = __float2bfloat16(__bfloat162float(skp[di+3]) + a4.w);
        }
    }
}

__global__ __launch_bounds__(256) void kern_cvtw(const float* __restrict__ w, __hip_bfloat16* __restrict__ wb, int n)
{
    int i = blockIdx.x*256 + threadIdx.x;
    if (i < n) wb[i] = __float2bfloat16(w[i]);
}

// ---------------- fused end stage: lrelu(skp) @ e1w (+bias,lrelu) @ e2w^T + e2b -> out ----------------
// 1 block per 64-row m-tile; A staged in LDS once; e2 epilogue via f16 MFMA per c-subtile pair.
constexpr int AS_ = 328;   // LDS row stride (shorts) for A tile
__global__ __launch_bounds__(256) void kern_end2(const __hip_bfloat16* __restrict__ skp,
    const __hip_bfloat16* __restrict__ e1wb, const float* __restrict__ e1b,
    const float* __restrict__ e2w, const float* __restrict__ e2b, float* __restrict__ out)
{
    __shared__ short As[64*AS_];          // ~42 KB
    __shared__ f16x8 w2f[20*64];          // 20 KB, pre-swizzled B frags for 16x16x32 f16
    __shared__ _Float16 yw[4][16][36];    // per-wave y tile (2 c-subtiles)
    int tid = threadIdx.x;
    int wave = tid >> 6, lane = tid & 63;
    int rn = lane & 15, q = lane >> 4;
    int m0 = blockIdx.x*64;
    // stage A = lrelu(skp) into LDS
    for (int i = tid; i < 64*40; i += 256) {
        bf16x8 v = ((const bf16x8*)skp)[(size_t)m0*40 + i];
        bf16x8 r;
        #pragma unroll
        for (int e = 0; e < 8; ++e) {
            unsigned short us = (unsigned short)v[e];
            __hip_bfloat16 h = *(__hip_bfloat16*)&us;
            float f = __bfloat162float(h);
            r[e] = (short)f2bf(lrelu(f));
        }
        int row = i / 40, col = (i % 40)*8;
        *(bf16x8*)&As[row*AS_ + col] = r;
    }
    // stage w2 frags: lane l of pair csp holds w2[o=l&15][c = csp*32 + (l>>4)*8 + i]
    for (int i = tid; i < 20*64; i += 256) {
        int csp = i >> 6, l = i & 63;
        int o = l & 15, qq = l >> 4;
        f16x8 v;
        #pragma unroll
        for (int e = 0; e < 8; ++e) {
            int c = csp*32 + qq*8 + e;
            v[e] = (o < 12) ? (_Float16)e2w[o*640 + c] : (_Float16)0.f;
        }
        w2f[i] = v;
    }
    __syncthreads();
    // preload A frags for this wave's 16 rows
    bf16x8 areg[10];
    const short* Arow = As + (wave*16 + rn)*AS_ + q*8;
    #pragma unroll
    for (int kk = 0; kk < 10; ++kk) areg[kk] = *(const bf16x8*)(Arow + kk*32);
    f32x4 acc2 = {};
    const short* e1p = (const short*)e1wb;
    for (int cs = 0; cs < 40; ++cs) {
        f32x4 acc = {};
        const short* Bp = e1p + (size_t)(cs*16 + rn)*320 + q*8;
        #pragma unroll
        for (int kk = 0; kk < 10; ++kk) {
            bf16x8 bb = *(const bf16x8*)(Bp + kk*32);
            acc = __builtin_amdgcn_mfma_f32_16x16x32_bf16(areg[kk], bb, acc, 0, 0, 0);
        }
        float bias = e1b[cs*16 + rn];
        int half = (cs & 1)*16;
        #pragma unroll
        for (int r = 0; r < 4; ++r)
            yw[wave][q*4+r][half + rn] = (_Float16)lrelu(acc[r] + bias);
        __builtin_amdgcn_wave_barrier();
        if (cs & 1) {
            f16x8 a2 = *(const f16x8*)&yw[wave][rn][q*8];
            f16x8 b2 = w2f[(cs>>1)*64 + lane];
            acc2 = __builtin_amdgcn_mfma_f32_16x16x32_f16(a2, b2, acc2, 0, 0, 0);
            __builtin_amdgcn_wave_barrier();
        }
    }
    // D: col = rn = o, row = q*4+r = m-local
    if (rn < 12) {
        float bo = e2b[rn];
        #pragma unroll
        for (int r = 0; r < 4; ++r) {
            int gm = m0 + wave*16 + q*4 + r;
            int t = gm % 7; int bn = gm / 7; int n = bn % N_; int b = bn / N_;
            out[(((size_t)b*12 + rn)*N_ + n)*7 + t] = acc2[r] + bo;
        }
    }
}

extern "C" void kernel_launch(void* const* d_in, const int* in_sizes, int n_in,
                              void* d_out, int out_size, void* d_ws, size_t ws_size,
                              hipStream_t stream)
{
    (void)in_sizes; (void)n_in; (void)out_size;
    const float* input   = (const float*)d_in[0];
    const float* A_fwd   = (const float*)d_in[1];
    const float* A_bwd   = (const float*)d_in[2];
    const int*   indices = (const int*)  d_in[3];
    const float* G0      = (const float*)d_in[4];
    const float* G1      = (const float*)d_in[5];
    const float* nv1     = (const float*)d_in[6];
    const float* nv2     = (const float*)d_in[7];
    const float* wef     = (const float*)d_in[8];
    const float* web     = (const float*)d_in[9];
    const float* vsf     = (const float*)d_in[10];
    const float* vdf     = (const float*)d_in[11];
    const float* vsb     = (const float*)d_in[12];
    const float* vdb     = (const float*)d_in[13];
    const float* start_w = (const float*)d_in[14];
    const float* start_b = (const float*)d_in[15];
    const float* filt_w  = (const float*)d_in[16];
    const float* filt_b  = (const float*)d_in[17];
    const float* gate_w  = (const float*)d_in[18];
    const float* gate_b  = (const float*)d_in[19];
    const float* gcw     = (const float*)d_in[20];
    const float* gcb     = (const float*)d_in[21];
    const float* bng_g   = (const float*)d_in[22];
    const float* bng_b   = (const float*)d_in[23];
    const float* bn_g    = (const float*)d_in[24];
    const float* bn_b    = (const float*)d_in[25];
    const float* skw     = (const float*)d_in[26];
    const float* skb     = (const float*)d_in[27];
    const float* e1w     = (const float*)d_in[28];
    const float* e1b     = (const float*)d_in[29];
    const float* e2w     = (const float*)d_in[30];
    const float* e2b     = (const float*)d_in[31];
    float* out = (float*)d_out;

    // ---- workspace layout (4B units, 16B-aligned allocations) ----
    float* W = (float*)d_ws;
    size_t off = 0;
    auto FA = [&](size_t n){ off = (off + 3) & ~(size_t)3; float* p = W + off; off += n; return p; };
    float* insum  = FA(2);
    float* tf     = FA((size_t)B_*EH_);
    float* tb     = FA((size_t)B_*EH_);
    float* bnacc1 = FA(80);
    float* bnacc2 = FA(80);
    float* usf = FA((size_t)B_*N_); float* udf = FA((size_t)B_*N_);
    float* usb = FA((size_t)B_*N_); float* udb = FA((size_t)B_*N_);
    float* scf = FA((size_t)B_*E_); float* scb = FA((size_t)B_*E_);
    float* efv = FA((size_t)B_*E_); float* ebv = FA((size_t)B_*E_);
    __hip_bfloat16* adpTb = (__hip_bfloat16*)FA((size_t)KP_*KP_/2);
    float* a0v = FA(E_); float* a1v = FA(E_);
    int* map  = (int*)FA((size_t)N_*N_);
    int* cnt0 = (int*)FA(512); int* cnt1 = (int*)FA(512);
    int* ptr0 = (int*)FA(512); int* ptr1 = (int*)FA(512);
    int* cur0 = (int*)FA(512); int* cur1 = (int*)FA(512);
    int* selfe = (int*)FA(512);
    int* e0id = (int*)FA(E_); int* e0nb = (int*)FA(E_);
    int* e1id = (int*)FA(E_); int* e1nb = (int*)FA(E_);
    float* xA  = FA((size_t)B_*N_*T0_*C_);
    float* xg  = FA((size_t)B_*N_*11*C_);
    float* pa  = FA((size_t)B_*N_*11*C_);
    float* gc  = FA((size_t)B_*N_*11*C_);
    __hip_bfloat16* skp = (__hip_bfloat16*)FA((size_t)B_*N_*7*320/2);
    __hip_bfloat16* xgT = (__hip_bfloat16*)FA((size_t)B_*448*KP_/2);
    __hip_bfloat16* paT = (__hip_bfloat16*)FA((size_t)B_*448*KP_/2);
    // e1wb overlays xg (dead after block loop, rewritten every call)
    __hip_bfloat16* e1wb = (__hip_bfloat16*)xg;

    if (ws_size < off*sizeof(float)) return;   // fail cleanly, not a fault

    // ---- setup ----
    kern_init<<<(N_*N_+255)/256, 256, 0, stream>>>(insum, map, cnt0, selfe, (int*)adpTb);
    kern_instats<<<256, 256, 0, stream>>>(input, insum);
    kern_x0<<<(B_*N_*T0_*C_+255)/256, 256, 0, stream>>>(input, insum, start_w, start_b, xA);
    kern_adp<<<N_, 512, 0, stream>>>(nv1, nv2, adpTb);
    kern_emax<<<(E_+255)/256, 256, 0, stream>>>(indices, map);
    kern_ecnt<<<(E_+255)/256, 256, 0, stream>>>(indices, map, cnt0, cnt1, selfe);
    kern_scan<<<1, 512, 0, stream>>>(cnt0, cnt1, ptr0, ptr1, cur0, cur1);
    kern_efill<<<(E_+255)/256, 256, 0, stream>>>(indices, map, A_fwd, A_bwd, cur0, cur1,
                                                 e0id, e0nb, a0v, e1id, e1nb, a1v);

    // ---- 3 blocks ----
    for (int blk = 0; blk < 3; ++blk) {
        int Tin = T0_ - 2*blk;
        int Tout = Tin - 2;
        int LD = Tout*C_;
        int JP = (LD + 63) & ~63;
        size_t total = (size_t)B_*N_*Tout*C_;
        kern_zeroacc<<<(2*B_*EH_+160+255)/256, 256, 0, stream>>>(tf, 2*B_*EH_+160);

        kern_umean<<<B_*N_, 64, 0, stream>>>(xA, Tin, vsf+blk*C_, vdf+blk*C_, vsb+blk*C_, vdb+blk*C_,
                                             usf, udf, usb, udb);
        kern_sc<<<(B_*E_+255)/256, 256, 0, stream>>>(indices, usf, udf, usb, udb, scf, scb);
        kern_t<<<dim3(B_, 8), 320, 0, stream>>>(scf, scb, G0, tf, tb);
        kern_ef<<<dim3(8, B_), 256, 0, stream>>>(tf, tb, wef, web, G1, efv, ebv);

        const float* gwb = gcw + (size_t)blk*7*C_*C_;
        kern_dconv_acc<<<B_*N_/2, 256, 0, stream>>>(xA, Tin,
            filt_w + (size_t)blk*2*C_*C_, filt_b + blk*C_,
            gate_w + (size_t)blk*2*C_*C_, gate_b + blk*C_,
            gwb + 0*C_*C_, gcb + blk*C_, xg, gc, xgT, JP);
        // s0 two hops
        kern_sparse_acc<<<B_*N_/2, 256, 0, stream>>>(xg, pa, Tout, ptr1, e0nb, e0id, a0v, efv,
                                                     A_fwd, selfe, gwb + 1*C_*C_, gc);
        kern_sparse_acc<<<B_*N_/2, 256, 0, stream>>>(pa, nullptr, Tout, ptr1, e0nb, e0id, a0v, efv,
                                                     A_fwd, selfe, gwb + 2*C_*C_, gc);
        // s1 two hops
        kern_sparse_acc<<<B_*N_/2, 256, 0, stream>>>(xg, pa, Tout, ptr0, e1nb, e1id, a1v, ebv,
                                                     A_bwd, selfe, gwb + 3*C_*C_, gc);
        kern_sparse_acc<<<B_*N_/2, 256, 0, stream>>>(pa, nullptr, Tout, ptr0, e1nb, e1id, a1v, ebv,
                                                     A_bwd, selfe, gwb + 4*C_*C_, gc);
        // adp two dense hops via MFMA
        dim3 gg(8, JP/64, B_);
        kern_gemm_mfma<<<gg, 256, 0, stream>>>(adpTb, xgT, pa, paT, LD, JP);
        kern_gacc<<<B_*N_/2, 256, 0, stream>>>(pa, gwb + 5*C_*C_, gc, Tout);
        kern_gemm_mfma<<<gg, 256, 0, stream>>>(adpTb, paT, xg, nullptr, LD, JP);
        kern_gacc<<<B_*N_/2, 256, 0, stream>>>(xg, gwb + 6*C_*C_, gc, Tout);

        kern_bnstats<<<512, 320, 0, stream>>>(gc, total, bnacc1);
        kern_bn1<<<512, 320, 0, stream>>>(gc, xA, Tin, Tout, bnacc1, bng_g + blk*C_, bng_b + blk*C_, bnacc2);
        kern_bn2<<<(int)((total+255)/256), 256, 0, stream>>>(gc, xA, Tout, bnacc2, bn_g + blk*C_, bn_b + blk*C_);

        kern_skip<<<dim3(B_*N_, 2), 256, 0, stream>>>(xA, Tout, skw + (size_t)blk*320*C_, skb + blk*320,
                                                      skp, blk == 0 ? 1 : 0);
    }

    // ---- end stage ----
    kern_cvtw<<<(640*320+255)/256, 256, 0, stream>>>(e1w, e1wb, 640*320);
    kern_end2<<<B_*N_*7/64, 256, 0, stream>>>(skp, e1wb, e1b, e2w, e2b, out);
}

// Round 5
// 2608.985 us; speedup vs baseline: 1.8414x; 1.0387x over previous
//
#include <hip/hip_runtime.h>
#include <hip/hip_bf16.h>

constexpr int B_  = 32;
constexpr int N_  = 500;
constexpr int T0_ = 13;
constexpr int E_  = 2000;
constexpr int EH_ = 300;
constexpr int C_  = 40;
constexpr float EPS_ = 1e-5f;
constexpr int KP_ = 512;     // padded node dim for MFMA adp gemm

typedef short bf16x8 __attribute__((ext_vector_type(8)));
typedef _Float16 f16x8 __attribute__((ext_vector_type(8)));
typedef float f32x4  __attribute__((ext_vector_type(4)));

__device__ __forceinline__ float sigm(float x){ return 1.f/(1.f+__expf(-x)); }
__device__ __forceinline__ float lrelu(float x){ return x > 0.f ? x : 0.01f*x; }
__device__ __forceinline__ unsigned short f2bf(float f){
    __hip_bfloat16 h = __float2bfloat16(f);
    return *(unsigned short*)&h;
}

// ---------------- init: zero/flag all small state ----------------
__global__ __launch_bounds__(256) void kern_init(float* __restrict__ insum, int* __restrict__ map,
                                                 int* __restrict__ cnts, int* __restrict__ selfe,
                                                 int* __restrict__ adpTbz)
{
    int i = blockIdx.x*256 + threadIdx.x;
    if (i < 2) insum[i] = 0.f;
    if (i < N_*N_) map[i] = -1;
    if (i < 1024) cnts[i] = 0;
    if (i < 512) selfe[i] = -1;
    if (i < KP_*KP_/2) adpTbz[i] = 0;
}

__global__ __launch_bounds__(256) void kern_zeroacc(float* __restrict__ p, int n)
{
    int i = blockIdx.x*256 + threadIdx.x;
    if (i < n) p[i] = 0.f;
}

// ---------------- input BN stats ----------------
__global__ __launch_bounds__(256) void kern_instats(const float* __restrict__ in, float* __restrict__ acc)
{
    float s = 0.f, ss = 0.f;
    int total = B_*N_*T0_;
    for (int i = blockIdx.x*256 + threadIdx.x; i < total; i += gridDim.x*256) {
        float v = in[i]; s += v; ss += v*v;
    }
    __shared__ float l1[256], l2[256];
    l1[threadIdx.x] = s; l2[threadIdx.x] = ss; __syncthreads();
    for (int o = 128; o > 0; o >>= 1) {
        if (threadIdx.x < o) { l1[threadIdx.x] += l1[threadIdx.x+o]; l2[threadIdx.x] += l2[threadIdx.x+o]; }
        __syncthreads();
    }
    if (threadIdx.x == 0) { atomicAdd(&acc[0], l1[0]); atomicAdd(&acc[1], l2[0]); }
}

// ---------------- normalize + start conv -> x (B,N,T,C) ----------------
__global__ __launch_bounds__(256) void kern_x0(const float* __restrict__ in, const float* __restrict__ insum,
    const float* __restrict__ sw, const float* __restrict__ sb, float* __restrict__ x)
{
    int idx = blockIdx.x*256 + threadIdx.x;
    int total = B_*N_*T0_*C_;
    if (idx >= total) return;
    float cnt = (float)(B_*N_*T0_);
    float mean = insum[0]/cnt;
    float var  = insum[1]/cnt - mean*mean;
    float inv  = rsqrtf(var + EPS_);
    int c = idx % C_;
    int pos = idx / C_;
    float xn = (in[pos] - mean)*inv;
    x[idx] = sw[c]*xn + sb[c];
}

// ---------------- adp = softmax(relu(nv1@nv2), axis=1), stored transposed bf16 padded ----------------
__global__ __launch_bounds__(512) void kern_adp(const float* __restrict__ nv1, const float* __restrict__ nv2,
                                                __hip_bfloat16* __restrict__ adpTb)
{
    int n = blockIdx.x;
    int m = threadIdx.x;
    float r = 0.f;
    if (m < N_) {
        #pragma unroll
        for (int k = 0; k < 10; ++k) r += nv1[n*10+k]*nv2[k*N_+m];
        r = r > 0.f ? r : 0.f;
    }
    __shared__ float red[512];
    red[threadIdx.x] = (m < N_) ? r : -1e30f; __syncthreads();
    for (int o = 256; o > 0; o >>= 1) {
        if (threadIdx.x < o) red[threadIdx.x] = fmaxf(red[threadIdx.x], red[threadIdx.x+o]);
        __syncthreads();
    }
    float mx = red[0]; __syncthreads();
    float ev = (m < N_) ? __expf(r - mx) : 0.f;
    red[threadIdx.x] = ev; __syncthreads();
    for (int o = 256; o > 0; o >>= 1) {
        if (threadIdx.x < o) red[threadIdx.x] += red[threadIdx.x+o];
        __syncthreads();
    }
    float sum = red[0];
    if (m < N_) adpTb[(size_t)m*KP_ + n] = __float2bfloat16(ev/sum);
}

// ---------------- edge preprocessing ----------------
__global__ void kern_emax(const int* __restrict__ idx, int* __restrict__ map)
{
    int e = blockIdx.x*256 + threadIdx.x;
    if (e < E_) atomicMax(&map[idx[e]*N_ + idx[E_+e]], e);
}
__global__ void kern_ecnt(const int* __restrict__ idx, const int* __restrict__ map,
                          int* __restrict__ cnt0, int* __restrict__ cnt1, int* __restrict__ selfe)
{
    int e = blockIdx.x*256 + threadIdx.x;
    if (e >= E_) return;
    int i0 = idx[e], i1 = idx[E_+e];
    if (map[i0*N_+i1] != e) return;
    atomicAdd(&cnt1[i1], 1);
    atomicAdd(&cnt0[i0], 1);
    if (i0 == i1) selfe[i0] = e;
}
__global__ __launch_bounds__(512) void kern_scan(const int* __restrict__ cnt0, const int* __restrict__ cnt1,
    int* __restrict__ ptr0, int* __restrict__ ptr1, int* __restrict__ cur0, int* __restrict__ cur1)
{
    __shared__ int s0[512], s1[512];
    int tid = threadIdx.x;
    s0[tid] = (tid < N_) ? cnt0[tid] : 0;
    s1[tid] = (tid < N_) ? cnt1[tid] : 0;
    __syncthreads();
    for (int o = 1; o < 512; o <<= 1) {
        int v0 = (tid >= o) ? s0[tid-o] : 0;
        int v1 = (tid >= o) ? s1[tid-o] : 0;
        __syncthreads();
        s0[tid] += v0; s1[tid] += v1;
        __syncthreads();
    }
    if (tid == 0) { ptr0[0] = 0; ptr1[0] = 0; }
    if (tid < N_) {
        ptr0[tid+1] = s0[tid]; ptr1[tid+1] = s1[tid];
        cur0[tid] = (tid == 0) ? 0 : s0[tid-1];
        cur1[tid] = (tid == 0) ? 0 : s1[tid-1];
    }
}
__global__ void kern_efill(const int* __restrict__ idx, const int* __restrict__ map,
    const float* __restrict__ Af, const float* __restrict__ Ab,
    int* __restrict__ cur0, int* __restrict__ cur1,
    int* __restrict__ e0id, int* __restrict__ e0nb, float* __restrict__ a0v,
    int* __restrict__ e1id, int* __restrict__ e1nb, float* __restrict__ a1v)
{
    int e = blockIdx.x*256 + threadIdx.x;
    if (e >= E_) return;
    int i0 = idx[e], i1 = idx[E_+e];
    if (map[i0*N_+i1] != e) return;
    int s1 = atomicAdd(&cur1[i1], 1);
    e0id[s1] = e; e0nb[s1] = i0; a0v[s1] = Af[i0*N_+i1];
    int s0 = atomicAdd(&cur0[i0], 1);
    e1id[s0] = e; e1nb[s0] = i1; a1v[s0] = Ab[i1*N_+i0];
}

// ---------------- per-(b,n) mean over t, dotted with 4 C-vectors ----------------
__global__ __launch_bounds__(64) void kern_umean(const float* __restrict__ x, int Tin,
    const float* __restrict__ vsf, const float* __restrict__ vdf,
    const float* __restrict__ vsb, const float* __restrict__ vdb,
    float* __restrict__ usf, float* __restrict__ udf, float* __restrict__ usb, float* __restrict__ udb)
{
    int bn = blockIdx.x;
    const float* xp = x + (size_t)bn*Tin*C_;
    int tid = threadIdx.x;
    float a0=0.f,a1=0.f,a2=0.f,a3=0.f;
    for (int i = tid; i < Tin*C_; i += 64) {
        float v = xp[i]; int c = i % C_;
        a0 += v*vsf[c]; a1 += v*vdf[c]; a2 += v*vsb[c]; a3 += v*vdb[c];
    }
    for (int o = 32; o > 0; o >>= 1) {
        a0 += __shfl_down(a0,o); a1 += __shfl_down(a1,o);
        a2 += __shfl_down(a2,o); a3 += __shfl_down(a3,o);
    }
    if (tid == 0) {
        float inv = 1.f/(float)Tin;
        usf[bn]=a0*inv; udf[bn]=a1*inv; usb[bn]=a2*inv; udb[bn]=a3*inv;
    }
}

__global__ void kern_sc(const int* __restrict__ idx,
    const float* __restrict__ usf, const float* __restrict__ udf,
    const float* __restrict__ usb, const float* __restrict__ udb,
    float* __restrict__ scf, float* __restrict__ scb)
{
    int i = blockIdx.x*256 + threadIdx.x;
    if (i >= B_*E_) return;
    int b = i / E_, e = i % E_;
    int i0 = idx[e], i1 = idx[E_+e];
    scf[i] = usf[b*N_+i0] + udf[b*N_+i1];
    scb[i] = usb[b*N_+i0] + udb[b*N_+i1];
}

__global__ __launch_bounds__(320) void kern_t(const float* __restrict__ scf, const float* __restrict__ scb,
    const float* __restrict__ G0, float* __restrict__ tf, float* __restrict__ tb)
{
    int b = blockIdx.x, chunk = blockIdx.y;
    int e0 = chunk*250;
    __shared__ float sf[250], sb2[250];
    int tid = threadIdx.x;
    for (int i = tid; i < 250; i += 320) { sf[i] = scf[b*E_+e0+i]; sb2[i] = scb[b*E_+e0+i]; }
    __syncthreads();
    if (tid < EH_) {
        float af = 0.f, ab = 0.f;
        for (int i = 0; i < 250; ++i) {
            float g = G0[(size_t)(e0+i)*EH_ + tid];
            af += sf[i]*g; ab += sb2[i]*g;
        }
        atomicAdd(&tf[b*EH_+tid], af);
        atomicAdd(&tb[b*EH_+tid], ab);
    }
}

__global__ __launch_bounds__(256) void kern_ef(const float* __restrict__ tf, const float* __restrict__ tb,
    const float* __restrict__ wf, const float* __restrict__ wb, const float* __restrict__ G1,
    float* __restrict__ ef, float* __restrict__ eb)
{
    int b = blockIdx.y;
    int e = blockIdx.x*256 + threadIdx.x;
    __shared__ float f[EH_], g[EH_];
    for (int i = threadIdx.x; i < EH_; i += 256) {
        f[i] = tf[b*EH_+i]*wf[i];
        g[i] = tb[b*EH_+i]*wb[i];
    }
    __syncthreads();
    if (e < E_) {
        float af = 0.f, ab = 0.f;
        for (int h = 0; h < EH_; ++h) {
            float v = G1[(size_t)h*E_ + e];
            af += f[h]*v; ab += g[h]*v;
        }
        ef[b*E_+e] = sigm(af);
        eb[b*E_+e] = sigm(ab);
    }
}

// ---------------- dilated conv + gate, fused with gconv chunk0; also writes transposed bf16 xgT ----------------
__global__ __launch_bounds__(256) void kern_dconv_acc(const float* __restrict__ x, int Tin,
    const float* __restrict__ fw, const float* __restrict__ fb4,
    const float* __restrict__ gw, const float* __restrict__ gb4,
    const float* __restrict__ wl0, const float* __restrict__ gbias,
    float* __restrict__ xg, float* __restrict__ gc,
    __hip_bfloat16* __restrict__ xgT, int JP)
{
    int Tout = Tin - 2;
    int nout = Tout*C_;
    int tile = threadIdx.x >> 7;
    int lane = threadIdx.x & 127;
    int bn = blockIdx.x*2 + tile;
    int b = bn / N_, n = bn % N_;
    __shared__ alignas(16) float xs[2][T0_*C_];
    __shared__ alignas(16) float wf[2*C_*C_];
    __shared__ alignas(16) float wg[2*C_*C_];
    __shared__ alignas(16) float wl[C_*C_];
    __shared__ alignas(16) float ps[2][11*C_];
    int tid = threadIdx.x;
    {
        const float4* xp = (const float4*)(x + (size_t)bn*Tin*C_);
        float4* xd = (float4*)xs[tile];
        for (int i = lane; i < (Tin*C_)/4; i += 128) xd[i] = xp[i];
    }
    for (int i = tid; i < 2*C_*C_; i += 256) {
        int k = i / (C_*C_); int r = i % (C_*C_); int c = r / C_; int o = r % C_;
        wf[i] = fw[(o*C_+c)*2 + k];
        wg[i] = gw[(o*C_+c)*2 + k];
    }
    for (int i = tid; i < C_*C_; i += 256) wl[i] = wl0[i];
    __syncthreads();
    int nq = Tout*10;
    for (int u = lane; u < nq; u += 128) {
        int t = u/10, o = (u%10)*4;
        float4 f4 = *(const float4*)&fb4[o];
        float4 g4 = *(const float4*)&gb4[o];
        for (int c = 0; c < C_; ++c) {
            float x0v = xs[tile][t*C_+c], x2v = xs[tile][(t+2)*C_+c];
            float4 wf0 = *(const float4*)&wf[c*C_+o];
            float4 wf1 = *(const float4*)&wf[C_*C_ + c*C_+o];
            float4 wg0 = *(const float4*)&wg[c*C_+o];
            float4 wg1 = *(const float4*)&wg[C_*C_ + c*C_+o];
            f4.x += wf0.x*x0v + wf1.x*x2v;  f4.y += wf0.y*x0v + wf1.y*x2v;
            f4.z += wf0.z*x0v + wf1.z*x2v;  f4.w += wf0.w*x0v + wf1.w*x2v;
            g4.x += wg0.x*x0v + wg1.x*x2v;  g4.y += wg0.y*x0v + wg1.y*x2v;
            g4.z += wg0.z*x0v + wg1.z*x2v;  g4.w += wg0.w*x0v + wg1.w*x2v;
        }
        float4 r4;
        r4.x = tanhf(f4.x)*sigm(g4.x);
        r4.y = tanhf(f4.y)*sigm(g4.y);
        r4.z = tanhf(f4.z)*sigm(g4.z);
        r4.w = tanhf(f4.w)*sigm(g4.w);
        *(float4*)&ps[tile][t*C_+o] = r4;
        *(float4*)&xg[(size_t)bn*nout + t*C_+o] = r4;
        int j = t*C_+o;
        size_t tb = ((size_t)b*JP + j)*KP_ + n;
        xgT[tb]          = __float2bfloat16(r4.x);
        xgT[tb + KP_]    = __float2bfloat16(r4.y);
        xgT[tb + 2*KP_]  = __float2bfloat16(r4.z);
        xgT[tb + 3*KP_]  = __float2bfloat16(r4.w);
    }
    __syncthreads();
    for (int u = lane; u < nq; u += 128) {
        int t = u/10, o = (u%10)*4;
        float4 a4 = *(const float4*)&gbias[o];
        for (int c = 0; c < C_; ++c) {
            float s = ps[tile][t*C_+c];
            float4 w = *(const float4*)&wl[c*C_+o];
            a4.x += s*w.x; a4.y += s*w.y; a4.z += s*w.z; a4.w += s*w.w;
        }
        *(float4*)&gc[(size_t)bn*nout + t*C_+o] = a4;
    }
}

// ---- fused sparse graph op + gconv accumulate (2 bn tiles / block) ----
__global__ __launch_bounds__(256) void kern_sparse_acc(const float* __restrict__ in,
    float* __restrict__ outTile, int Tout,
    const int* __restrict__ ptr, const int* __restrict__ nbr, const int* __restrict__ eid,
    const float* __restrict__ aval, const float* __restrict__ coef,
    const float* __restrict__ Amat, const int* __restrict__ selfe,
    const float* __restrict__ gwp, float* __restrict__ gc)
{
    int tile = threadIdx.x >> 7;
    int lane = threadIdx.x & 127;
    int bn = blockIdx.x*2 + tile;
    int b = bn / N_, m = bn % N_;
    __shared__ float wv[2][64];
    __shared__ int   nb[2][64];
    __shared__ alignas(16) float ps[2][11*C_];
    __shared__ alignas(16) float wl[C_*C_];
    int tid = threadIdx.x;
    int p0 = ptr[m], p1 = ptr[m+1];
    int deg = p1 - p0; if (deg > 64) deg = 64;
    if (lane < deg) {
        wv[tile][lane] = coef[b*E_ + eid[p0+lane]] * aval[p0+lane];
        nb[tile][lane] = nbr[p0+lane];
    }
    for (int i = tid; i < C_*C_; i += 256) wl[i] = gwp[i];
    __syncthreads();
    float dval = (selfe[m] >= 0) ? 0.f : Amat[(size_t)m*N_ + m];
    const float* inb = in + (size_t)b*N_*Tout*C_;
    int nout = Tout*C_;
    for (int oi = lane; oi < nout; oi += 128) {
        float acc = dval * inb[(size_t)m*nout + oi];
        for (int j = 0; j < deg; ++j) acc += wv[tile][j]*inb[(size_t)nb[tile][j]*nout + oi];
        ps[tile][oi] = acc;
        if (outTile) outTile[(size_t)bn*nout + oi] = acc;
    }
    __syncthreads();
    int nq = Tout*10;
    for (int u = lane; u < nq; u += 128) {
        int t = u/10, o = (u%10)*4;
        float4 a4 = *(const float4*)&gc[(size_t)bn*nout + t*C_+o];
        for (int c = 0; c < C_; ++c) {
            float s = ps[tile][t*C_+c];
            float4 w = *(const float4*)&wl[c*C_+o];
            a4.x += s*w.x; a4.y += s*w.y; a4.z += s*w.z; a4.w += s*w.w;
        }
        *(float4*)&gc[(size_t)bn*nout + t*C_+o] = a4;
    }
}

// ---------------- adp dense hop via MFMA bf16 (A frags preloaded to registers) ----------------
__global__ __launch_bounds__(256) void kern_gemm_mfma(const __hip_bfloat16* __restrict__ adpTb,
    const __hip_bfloat16* __restrict__ inT, float* __restrict__ outF,
    __hip_bfloat16* __restrict__ outT, int LD, int JP)
{
    int tid = threadIdx.x;
    int wave = tid >> 6, lane = tid & 63;
    int rn = lane & 15, q = lane >> 4;
    int b = blockIdx.z;
    int m0 = blockIdx.x*64;
    int j0 = blockIdx.y*64;
    const short* Ap = (const short*)adpTb + (size_t)(m0 + wave*16 + rn)*KP_ + q*8;
    bf16x8 areg[16];
    #pragma unroll
    for (int kk = 0; kk < 16; ++kk) areg[kk] = *(const bf16x8*)(Ap + kk*32);
    const short* Bp = (const short*)inT + ((size_t)b*JP + j0 + rn)*KP_ + q*8;
    f32x4 acc[4] = {};
    #pragma unroll
    for (int kk = 0; kk < 16; ++kk) {
        #pragma unroll
        for (int s = 0; s < 4; ++s) {
            bf16x8 bb = *(const bf16x8*)(Bp + (size_t)s*16*KP_ + kk*32);
            acc[s] = __builtin_amdgcn_mfma_f32_16x16x32_bf16(areg[kk], bb, acc[s], 0, 0, 0);
        }
    }
    int mb = m0 + wave*16 + q*4;     // D row base
    #pragma unroll
    for (int s = 0; s < 4; ++s) {
        int j = j0 + s*16 + rn;      // D col
        if (j >= LD) continue;
        #pragma unroll
        for (int r = 0; r < 4; ++r) {
            int m = mb + r;
            if (m < N_) outF[((size_t)b*N_ + m)*LD + j] = acc[s][r];
        }
        if (outT) {
            ushort4 v;
            v.x = f2bf(acc[s][0]); v.y = f2bf(acc[s][1]);
            v.z = f2bf(acc[s][2]); v.w = f2bf(acc[s][3]);
            *(ushort4*)((unsigned short*)outT + ((size_t)b*JP + j)*KP_ + mb) = v;
        }
    }
}

// ---------------- gconv accumulate one 40-chunk (2 bn tiles / block) ----------------
__global__ __launch_bounds__(256) void kern_gacc(const float* __restrict__ part, const float* __restrict__ gwp,
    float* __restrict__ gc, int Tout)
{
    int tile = threadIdx.x >> 7;
    int lane = threadIdx.x & 127;
    int bn = blockIdx.x*2 + tile;
    int nout = Tout*C_;
    __shared__ alignas(16) float ps[2][11*C_];
    __shared__ alignas(16) float wl[C_*C_];
    int tid = threadIdx.x;
    {
        const float4* pp = (const float4*)(part + (size_t)bn*nout);
        float4* pd = (float4*)ps[tile];
        for (int i = lane; i < nout/4; i += 128) pd[i] = pp[i];
    }
    for (int i = tid; i < C_*C_; i += 256) wl[i] = gwp[i];
    __syncthreads();
    int nq = Tout*10;
    for (int u = lane; u < nq; u += 128) {
        int t = u/10, o = (u%10)*4;
        float4 a4 = *(const float4*)&gc[(size_t)bn*nout + t*C_+o];
        for (int c = 0; c < C_; ++c) {
            float s = ps[tile][t*C_+c];
            float4 w = *(const float4*)&wl[c*C_+o];
            a4.x += s*w.x; a4.y += s*w.y; a4.z += s*w.z; a4.w += s*w.w;
        }
        *(float4*)&gc[(size_t)bn*nout + t*C_+o] = a4;
    }
}

// ---------------- BN stats per channel ----------------
__global__ __launch_bounds__(320) void kern_bnstats(const float* __restrict__ src, size_t total, float* __restrict__ acc)
{
    int tid = threadIdx.x;
    float s = 0.f, ss = 0.f;
    for (size_t i = (size_t)blockIdx.x*320 + tid; i < total; i += (size_t)gridDim.x*320) {
        float v = src[i]; s += v; ss += v*v;
    }
    __shared__ float ls[320], lss[320];
    ls[tid] = s; lss[tid] = ss; __syncthreads();
    if (tid < C_) {
        float t1 = 0.f, t2 = 0.f;
        for (int r = 0; r < 8; ++r) { t1 += ls[r*C_+tid]; t2 += lss[r*C_+tid]; }
        atomicAdd(&acc[tid], t1); atomicAdd(&acc[C_+tid], t2);
    }
}

__global__ __launch_bounds__(320) void kern_bn1(float* __restrict__ gc, const float* __restrict__ resid,
    int Tin, int Tout, const float* __restrict__ acc1,
    const float* __restrict__ g1, const float* __restrict__ b1, float* __restrict__ acc2)
{
    int tid = threadIdx.x; int c = tid % C_;
    float cnt = (float)(B_*N_*Tout);
    float mean = acc1[c]/cnt;
    float var  = acc1[C_+c]/cnt - mean*mean;
    float inv  = rsqrtf(var + EPS_);
    float gg = g1[c], bb = b1[c];
    int dlt = Tin - Tout;
    float s = 0.f, ss = 0.f;
    size_t total = (size_t)B_*N_*Tout*C_;
    for (size_t i = (size_t)blockIdx.x*320 + tid; i < total; i += (size_t)gridDim.x*320) {
        size_t pos = i / C_; int t = (int)(pos % Tout); size_t bn = pos / Tout;
        float y = gg*(gc[i]-mean)*inv + bb;
        y += resid[(bn*Tin + (t+dlt))*C_ + c];
        gc[i] = y;
        s += y; ss += y*y;
    }
    __shared__ float ls[320], lss[320];
    ls[tid] = s; lss[tid] = ss; __syncthreads();
    if (tid < C_) {
        float t1 = 0.f, t2 = 0.f;
        for (int r = 0; r < 8; ++r) { t1 += ls[r*C_+tid]; t2 += lss[r*C_+tid]; }
        atomicAdd(&acc2[tid], t1); atomicAdd(&acc2[C_+tid], t2);
    }
}

__global__ __launch_bounds__(256) void kern_bn2(const float* __restrict__ gc, float* __restrict__ xout, int Tout,
    const float* __restrict__ acc2, const float* __restrict__ g2, const float* __restrict__ b2)
{
    size_t total = (size_t)B_*N_*Tout*C_;
    size_t i = (size_t)blockIdx.x*256 + threadIdx.x;
    if (i >= total) return;
    int c = (int)(i % C_);
    float cnt = (float)(B_*N_*Tout);
    float mean = acc2[c]/cnt;
    float var  = acc2[C_+c]/cnt - mean*mean;
    float inv  = rsqrtf(var + EPS_);
    xout[i] = g2[c]*(gc[i]-mean)*inv + b2[c];
}

// ---------------- skip conv on last 7 steps -> bf16 skip(B,N,7,320); 4 bn per block ----------------
__global__ __launch_bounds__(256) void kern_skip(const float* __restrict__ x, int Tout,
    const float* __restrict__ sw, const float* __restrict__ sbias, __hip_bfloat16* __restrict__ skp, int first)
{
    int bn0 = blockIdx.x*4; int half = blockIdx.y;
    int off = Tout - 7;
    __shared__ alignas(16) float xs[4][7*C_];
    __shared__ alignas(16) float wl[C_*164];
    int tid = threadIdx.x;
    for (int i = tid; i < 4*(7*C_/4); i += 256) {
        int bl = i / 70, r = i % 70;
        ((float4*)xs[bl])[r] = ((const float4*)(x + ((size_t)(bn0+bl)*Tout + off)*C_))[r];
    }
    for (int i = tid; i < 160*C_; i += 256) {
        int oo = i / C_, c = i % C_;
        wl[c*164 + oo] = sw[(size_t)(half*160 + oo)*C_ + c];
    }
    __syncthreads();
    for (int u = tid; u < 4*7*40; u += 256) {
        int bl = u / 280; int v = u % 280;
        int t = v / 40, o = (v % 40)*4;
        float4 a4 = {0.f,0.f,0.f,0.f};
        for (int c = 0; c < C_; ++c) {
            float s = xs[bl][t*C_+c];
            float4 w = *(const float4*)&wl[c*164 + o];
            a4.x += s*w.x; a4.y += s*w.y; a4.z += s*w.z; a4.w += s*w.w;
        }
        int og = half*160 + o;
        float4 b4 = *(const float4*)&sbias[og];
        a4.x += b4.x; a4.y += b4.y; a4.z += b4.z; a4.w += b4.w;
        size_t di = ((size_t)(bn0+bl)*7 + t)*320 + og;
        if (first) {
            skp[di+0] = __float2bfloat16(a4.x);
            skp[di+1] = __float2bfloat16(a4.y);
            skp[di+2] = __float2bfloat16(a4.z);
            skp[di+3] = __float2bfloat16(a4.w);
        } else {
            skp[di+0] = __float2bfloat16(__bfloat162float(skp[di+0]) + a4.x);
            skp[di+1] = __float2bfloat16(__bfloat162float(skp[di+1]) + a4.y);
            skp[di+2] = __float2bfloat16(__bfloat162float(skp[di+2]) + a4.z);
            skp[di+3] = __float2bfloat16(__bfloat162float(skp[di+3]) + a4.w);
        }
    }
}

__global__ __launch_bounds__(256) void kern_cvtw(const float* __restrict__ w, __hip_bfloat16* __restrict__ wb, int n)
{
    int i = blockIdx.x*256 + threadIdx.x;
    if (i < n) wb[i] = __float2bfloat16(w[i]);
}

// ---------------- fused end stage: lrelu(skp) @ e1w (+bias,lrelu) @ e2w^T + e2b -> out ----------------
// A rows loaded direct global->reg (no LDS stage); 4 independent MFMA chains per 2-cs pair.
__global__ __launch_bounds__(256) void kern_end2(const __hip_bfloat16* __restrict__ skp,
    const __hip_bfloat16* __restrict__ e1wb, const float* __restrict__ e1b,
    const float* __restrict__ e2w, const float* __restrict__ e2b, float* __restrict__ out)
{
    __shared__ f16x8 w2f[20*64];          // 20 KB, pre-swizzled B frags for 16x16x32 f16
    __shared__ _Float16 yw[4][16][40];    // 5 KB, row stride 40 (80B -> 16B aligned)
    __shared__ float eb_s[640];
    int tid = threadIdx.x;
    int wave = tid >> 6, lane = tid & 63;
    int rn = lane & 15, q = lane >> 4;
    int m0 = blockIdx.x*64;
    for (int i = tid; i < 20*64; i += 256) {
        int csp = i >> 6, l = i & 63;
        int o = l & 15, qq = l >> 4;
        f16x8 v;
        #pragma unroll
        for (int e = 0; e < 8; ++e) {
            int c = csp*32 + qq*8 + e;
            v[e] = (o < 12) ? (_Float16)e2w[o*640 + c] : (_Float16)0.f;
        }
        w2f[i] = v;
    }
    for (int i = tid; i < 640; i += 256) eb_s[i] = e1b[i];
    // direct-global A rows + lrelu -> registers
    const short* Arow = (const short*)skp + (size_t)(m0 + wave*16 + rn)*320 + q*8;
    bf16x8 areg[10];
    #pragma unroll
    for (int kk = 0; kk < 10; ++kk) {
        bf16x8 v = *(const bf16x8*)(Arow + kk*32);
        bf16x8 r;
        #pragma unroll
        for (int e = 0; e < 8; ++e) {
            unsigned short us = (unsigned short)v[e];
            __hip_bfloat16 h = *(__hip_bfloat16*)&us;
            r[e] = (short)f2bf(lrelu(__bfloat162float(h)));
        }
        areg[kk] = r;
    }
    __syncthreads();
    f32x4 acc2 = {};
    const short* e1p = (const short*)e1wb;
    for (int csp = 0; csp < 20; ++csp) {
        const short* Bp0 = e1p + (size_t)(csp*32 + rn)*320 + q*8;
        const short* Bp1 = Bp0 + 16*320;
        f32x4 c00 = {}, c01 = {}, c10 = {}, c11 = {};
        #pragma unroll
        for (int kk = 0; kk < 10; kk += 2) {
            bf16x8 b00 = *(const bf16x8*)(Bp0 + kk*32);
            bf16x8 b01 = *(const bf16x8*)(Bp0 + (kk+1)*32);
            bf16x8 b10 = *(const bf16x8*)(Bp1 + kk*32);
            bf16x8 b11 = *(const bf16x8*)(Bp1 + (kk+1)*32);
            c00 = __builtin_amdgcn_mfma_f32_16x16x32_bf16(areg[kk],   b00, c00, 0, 0, 0);
            c10 = __builtin_amdgcn_mfma_f32_16x16x32_bf16(areg[kk],   b10, c10, 0, 0, 0);
            c01 = __builtin_amdgcn_mfma_f32_16x16x32_bf16(areg[kk+1], b01, c01, 0, 0, 0);
            c11 = __builtin_amdgcn_mfma_f32_16x16x32_bf16(areg[kk+1], b11, c11, 0, 0, 0);
        }
        float bias0 = eb_s[csp*32 + rn];
        float bias1 = eb_s[csp*32 + 16 + rn];
        #pragma unroll
        for (int r = 0; r < 4; ++r) {
            yw[wave][q*4+r][rn]      = (_Float16)lrelu(c00[r] + c01[r] + bias0);
            yw[wave][q*4+r][16 + rn] = (_Float16)lrelu(c10[r] + c11[r] + bias1);
        }
        __builtin_amdgcn_wave_barrier();
        f16x8 a2 = *(const f16x8*)&yw[wave][rn][q*8];
        acc2 = __builtin_amdgcn_mfma_f32_16x16x32_f16(a2, w2f[csp*64 + lane], acc2, 0, 0, 0);
        __builtin_amdgcn_wave_barrier();
    }
    // D: col = rn = o, row = q*4+r = m-local
    if (rn < 12) {
        float bo = e2b[rn];
        #pragma unroll
        for (int r = 0; r < 4; ++r) {
            int gm = m0 + wave*16 + q*4 + r;
            int t = gm % 7; int bn = gm / 7; int n = bn % N_; int b = bn / N_;
            out[(((size_t)b*12 + rn)*N_ + n)*7 + t] = acc2[r] + bo;
        }
    }
}

extern "C" void kernel_launch(void* const* d_in, const int* in_sizes, int n_in,
                              void* d_out, int out_size, void* d_ws, size_t ws_size,
                              hipStream_t stream)
{
    (void)in_sizes; (void)n_in; (void)out_size;
    const float* input   = (const float*)d_in[0];
    const float* A_fwd   = (const float*)d_in[1];
    const float* A_bwd   = (const float*)d_in[2];
    const int*   indices = (const int*)  d_in[3];
    const float* G0      = (const float*)d_in[4];
    const float* G1      = (const float*)d_in[5];
    const float* nv1     = (const float*)d_in[6];
    const float* nv2     = (const float*)d_in[7];
    const float* wef     = (const float*)d_in[8];
    const float* web     = (const float*)d_in[9];
    const float* vsf     = (const float*)d_in[10];
    const float* vdf     = (const float*)d_in[11];
    const float* vsb     = (const float*)d_in[12];
    const float* vdb     = (const float*)d_in[13];
    const float* start_w = (const float*)d_in[14];
    const float* start_b = (const float*)d_in[15];
    const float* filt_w  = (const float*)d_in[16];
    const float* filt_b  = (const float*)d_in[17];
    const float* gate_w  = (const float*)d_in[18];
    const float* gate_b  = (const float*)d_in[19];
    const float* gcw     = (const float*)d_in[20];
    const float* gcb     = (const float*)d_in[21];
    const float* bng_g   = (const float*)d_in[22];
    const float* bng_b   = (const float*)d_in[23];
    const float* bn_g    = (const float*)d_in[24];
    const float* bn_b    = (const float*)d_in[25];
    const float* skw     = (const float*)d_in[26];
    const float* skb     = (const float*)d_in[27];
    const float* e1w     = (const float*)d_in[28];
    const float* e1b     = (const float*)d_in[29];
    const float* e2w     = (const float*)d_in[30];
    const float* e2b     = (const float*)d_in[31];
    float* out = (float*)d_out;

    // ---- workspace layout (4B units, 16B-aligned allocations) ----
    float* W = (float*)d_ws;
    size_t off = 0;
    auto FA = [&](size_t n){ off = (off + 3) & ~(size_t)3; float* p = W + off; off += n; return p; };
    float* insum  = FA(2);
    float* tf     = FA((size_t)B_*EH_);
    float* tb     = FA((size_t)B_*EH_);
    float* bnacc1 = FA(80);
    float* bnacc2 = FA(80);
    float* usf = FA((size_t)B_*N_); float* udf = FA((size_t)B_*N_);
    float* usb = FA((size_t)B_*N_); float* udb = FA((size_t)B_*N_);
    float* scf = FA((size_t)B_*E_); float* scb = FA((size_t)B_*E_);
    float* efv = FA((size_t)B_*E_); float* ebv = FA((size_t)B_*E_);
    __hip_bfloat16* adpTb = (__hip_bfloat16*)FA((size_t)KP_*KP_/2);
    float* a0v = FA(E_); float* a1v = FA(E_);
    int* map  = (int*)FA((size_t)N_*N_);
    int* cnt0 = (int*)FA(512); int* cnt1 = (int*)FA(512);
    int* ptr0 = (int*)FA(512); int* ptr1 = (int*)FA(512);
    int* cur0 = (int*)FA(512); int* cur1 = (int*)FA(512);
    int* selfe = (int*)FA(512);
    int* e0id = (int*)FA(E_); int* e0nb = (int*)FA(E_);
    int* e1id = (int*)FA(E_); int* e1nb = (int*)FA(E_);
    float* xA  = FA((size_t)B_*N_*T0_*C_);
    float* xg  = FA((size_t)B_*N_*11*C_);
    float* pa  = FA((size_t)B_*N_*11*C_);
    float* gc  = FA((size_t)B_*N_*11*C_);
    __hip_bfloat16* skp = (__hip_bfloat16*)FA((size_t)B_*N_*7*320/2);
    __hip_bfloat16* xgT = (__hip_bfloat16*)FA((size_t)B_*448*KP_/2);
    __hip_bfloat16* paT = (__hip_bfloat16*)FA((size_t)B_*448*KP_/2);
    // e1wb overlays xg (dead after block loop, rewritten every call)
    __hip_bfloat16* e1wb = (__hip_bfloat16*)xg;

    if (ws_size < off*sizeof(float)) return;   // fail cleanly, not a fault

    // ---- setup ----
    kern_init<<<(N_*N_+255)/256, 256, 0, stream>>>(insum, map, cnt0, selfe, (int*)adpTb);
    kern_instats<<<256, 256, 0, stream>>>(input, insum);
    kern_x0<<<(B_*N_*T0_*C_+255)/256, 256, 0, stream>>>(input, insum, start_w, start_b, xA);
    kern_adp<<<N_, 512, 0, stream>>>(nv1, nv2, adpTb);
    kern_emax<<<(E_+255)/256, 256, 0, stream>>>(indices, map);
    kern_ecnt<<<(E_+255)/256, 256, 0, stream>>>(indices, map, cnt0, cnt1, selfe);
    kern_scan<<<1, 512, 0, stream>>>(cnt0, cnt1, ptr0, ptr1, cur0, cur1);
    kern_efill<<<(E_+255)/256, 256, 0, stream>>>(indices, map, A_fwd, A_bwd, cur0, cur1,
                                                 e0id, e0nb, a0v, e1id, e1nb, a1v);

    // ---- 3 blocks ----
    for (int blk = 0; blk < 3; ++blk) {
        int Tin = T0_ - 2*blk;
        int Tout = Tin - 2;
        int LD = Tout*C_;
        int JP = (LD + 63) & ~63;
        size_t total = (size_t)B_*N_*Tout*C_;
        kern_zeroacc<<<(2*B_*EH_+160+255)/256, 256, 0, stream>>>(tf, 2*B_*EH_+160);

        kern_umean<<<B_*N_, 64, 0, stream>>>(xA, Tin, vsf+blk*C_, vdf+blk*C_, vsb+blk*C_, vdb+blk*C_,
                                             usf, udf, usb, udb);
        kern_sc<<<(B_*E_+255)/256, 256, 0, stream>>>(indices, usf, udf, usb, udb, scf, scb);
        kern_t<<<dim3(B_, 8), 320, 0, stream>>>(scf, scb, G0, tf, tb);
        kern_ef<<<dim3(8, B_), 256, 0, stream>>>(tf, tb, wef, web, G1, efv, ebv);

        const float* gwb = gcw + (size_t)blk*7*C_*C_;
        kern_dconv_acc<<<B_*N_/2, 256, 0, stream>>>(xA, Tin,
            filt_w + (size_t)blk*2*C_*C_, filt_b + blk*C_,
            gate_w + (size_t)blk*2*C_*C_, gate_b + blk*C_,
            gwb + 0*C_*C_, gcb + blk*C_, xg, gc, xgT, JP);
        // s0 two hops
        kern_sparse_acc<<<B_*N_/2, 256, 0, stream>>>(xg, pa, Tout, ptr1, e0nb, e0id, a0v, efv,
                                                     A_fwd, selfe, gwb + 1*C_*C_, gc);
        kern_sparse_acc<<<B_*N_/2, 256, 0, stream>>>(pa, nullptr, Tout, ptr1, e0nb, e0id, a0v, efv,
                                                     A_fwd, selfe, gwb + 2*C_*C_, gc);
        // s1 two hops
        kern_sparse_acc<<<B_*N_/2, 256, 0, stream>>>(xg, pa, Tout, ptr0, e1nb, e1id, a1v, ebv,
                                                     A_bwd, selfe, gwb + 3*C_*C_, gc);
        kern_sparse_acc<<<B_*N_/2, 256, 0, stream>>>(pa, nullptr, Tout, ptr0, e1nb, e1id, a1v, ebv,
                                                     A_bwd, selfe, gwb + 4*C_*C_, gc);
        // adp two dense hops via MFMA
        dim3 gg(8, JP/64, B_);
        kern_gemm_mfma<<<gg, 256, 0, stream>>>(adpTb, xgT, pa, paT, LD, JP);
        kern_gacc<<<B_*N_/2, 256, 0, stream>>>(pa, gwb + 5*C_*C_, gc, Tout);
        kern_gemm_mfma<<<gg, 256, 0, stream>>>(adpTb, paT, xg, nullptr, LD, JP);
        kern_gacc<<<B_*N_/2, 256, 0, stream>>>(xg, gwb + 6*C_*C_, gc, Tout);

        kern_bnstats<<<512, 320, 0, stream>>>(gc, total, bnacc1);
        kern_bn1<<<512, 320, 0, stream>>>(gc, xA, Tin, Tout, bnacc1, bng_g + blk*C_, bng_b + blk*C_, bnacc2);
        kern_bn2<<<(int)((total+255)/256), 256, 0, stream>>>(gc, xA, Tout, bnacc2, bn_g + blk*C_, bn_b + blk*C_);

        kern_skip<<<dim3(B_*N_/4, 2), 256, 0, stream>>>(xA, Tout, skw + (size_t)blk*320*C_, skb + blk*320,
                                                        skp, blk == 0 ? 1 : 0);
    }

    // ---- end stage ----
    kern_cvtw<<<(640*320+255)/256, 256, 0, stream>>>(e1w, e1wb, 640*320);
    kern_end2<<<B_*N_*7/64, 256, 0, stream>>>(skp, e1wb, e1b, e2w, e2b, out);
}

// Round 6
// 2604.103 us; speedup vs baseline: 1.8448x; 1.0019x over previous
//
#include <hip/hip_runtime.h>
#include <hip/hip_bf16.h>

constexpr int B_  = 32;
constexpr int N_  = 500;
constexpr int T0_ = 13;
constexpr int E_  = 2000;
constexpr int EH_ = 300;
constexpr int C_  = 40;
constexpr float EPS_ = 1e-5f;
constexpr int KP_ = 512;     // padded node dim for MFMA adp gemm

typedef short bf16x8 __attribute__((ext_vector_type(8)));
typedef _Float16 f16x8 __attribute__((ext_vector_type(8)));
typedef float f32x4  __attribute__((ext_vector_type(4)));

__device__ __forceinline__ float sigm(float x){ return 1.f/(1.f+__expf(-x)); }
__device__ __forceinline__ float lrelu(float x){ return x > 0.f ? x : 0.01f*x; }
__device__ __forceinline__ unsigned short f2bf(float f){
    __hip_bfloat16 h = __float2bfloat16(f);
    return *(unsigned short*)&h;
}
__device__ __forceinline__ float bf2f(unsigned short us){
    __hip_bfloat16 h = *(__hip_bfloat16*)&us;
    return __bfloat162float(h);
}

// ---------------- init: zero/flag all small state ----------------
__global__ __launch_bounds__(256) void kern_init(float* __restrict__ insum, int* __restrict__ map,
                                                 int* __restrict__ cnts, int* __restrict__ selfe,
                                                 int* __restrict__ adpTbz)
{
    int i = blockIdx.x*256 + threadIdx.x;
    if (i < 2) insum[i] = 0.f;
    if (i < N_*N_) map[i] = -1;
    if (i < 1024) cnts[i] = 0;
    if (i < 512) selfe[i] = -1;
    if (i < KP_*KP_/2) adpTbz[i] = 0;
}

__global__ __launch_bounds__(256) void kern_zeroacc(float* __restrict__ p, int n)
{
    int i = blockIdx.x*256 + threadIdx.x;
    if (i < n) p[i] = 0.f;
}

// ---------------- input BN stats ----------------
__global__ __launch_bounds__(256) void kern_instats(const float* __restrict__ in, float* __restrict__ acc)
{
    float s = 0.f, ss = 0.f;
    int total = B_*N_*T0_;
    for (int i = blockIdx.x*256 + threadIdx.x; i < total; i += gridDim.x*256) {
        float v = in[i]; s += v; ss += v*v;
    }
    __shared__ float l1[256], l2[256];
    l1[threadIdx.x] = s; l2[threadIdx.x] = ss; __syncthreads();
    for (int o = 128; o > 0; o >>= 1) {
        if (threadIdx.x < o) { l1[threadIdx.x] += l1[threadIdx.x+o]; l2[threadIdx.x] += l2[threadIdx.x+o]; }
        __syncthreads();
    }
    if (threadIdx.x == 0) { atomicAdd(&acc[0], l1[0]); atomicAdd(&acc[1], l2[0]); }
}

// ---------------- normalize + start conv -> x (B,N,T,C) ----------------
__global__ __launch_bounds__(256) void kern_x0(const float* __restrict__ in, const float* __restrict__ insum,
    const float* __restrict__ sw, const float* __restrict__ sb, float* __restrict__ x)
{
    int idx = blockIdx.x*256 + threadIdx.x;
    int total = B_*N_*T0_*C_;
    if (idx >= total) return;
    float cnt = (float)(B_*N_*T0_);
    float mean = insum[0]/cnt;
    float var  = insum[1]/cnt - mean*mean;
    float inv  = rsqrtf(var + EPS_);
    int c = idx % C_;
    int pos = idx / C_;
    float xn = (in[pos] - mean)*inv;
    x[idx] = sw[c]*xn + sb[c];
}

// ---------------- adp = softmax(relu(nv1@nv2), axis=1), stored transposed bf16 padded ----------------
__global__ __launch_bounds__(512) void kern_adp(const float* __restrict__ nv1, const float* __restrict__ nv2,
                                                __hip_bfloat16* __restrict__ adpTb)
{
    int n = blockIdx.x;
    int m = threadIdx.x;
    float r = 0.f;
    if (m < N_) {
        #pragma unroll
        for (int k = 0; k < 10; ++k) r += nv1[n*10+k]*nv2[k*N_+m];
        r = r > 0.f ? r : 0.f;
    }
    __shared__ float red[512];
    red[threadIdx.x] = (m < N_) ? r : -1e30f; __syncthreads();
    for (int o = 256; o > 0; o >>= 1) {
        if (threadIdx.x < o) red[threadIdx.x] = fmaxf(red[threadIdx.x], red[threadIdx.x+o]);
        __syncthreads();
    }
    float mx = red[0]; __syncthreads();
    float ev = (m < N_) ? __expf(r - mx) : 0.f;
    red[threadIdx.x] = ev; __syncthreads();
    for (int o = 256; o > 0; o >>= 1) {
        if (threadIdx.x < o) red[threadIdx.x] += red[threadIdx.x+o];
        __syncthreads();
    }
    float sum = red[0];
    if (m < N_) adpTb[(size_t)m*KP_ + n] = __float2bfloat16(ev/sum);
}

// ---------------- edge preprocessing ----------------
__global__ void kern_emax(const int* __restrict__ idx, int* __restrict__ map)
{
    int e = blockIdx.x*256 + threadIdx.x;
    if (e < E_) atomicMax(&map[idx[e]*N_ + idx[E_+e]], e);
}
__global__ void kern_ecnt(const int* __restrict__ idx, const int* __restrict__ map,
                          int* __restrict__ cnt0, int* __restrict__ cnt1, int* __restrict__ selfe)
{
    int e = blockIdx.x*256 + threadIdx.x;
    if (e >= E_) return;
    int i0 = idx[e], i1 = idx[E_+e];
    if (map[i0*N_+i1] != e) return;
    atomicAdd(&cnt1[i1], 1);
    atomicAdd(&cnt0[i0], 1);
    if (i0 == i1) selfe[i0] = e;
}
__global__ __launch_bounds__(512) void kern_scan(const int* __restrict__ cnt0, const int* __restrict__ cnt1,
    int* __restrict__ ptr0, int* __restrict__ ptr1, int* __restrict__ cur0, int* __restrict__ cur1)
{
    __shared__ int s0[512], s1[512];
    int tid = threadIdx.x;
    s0[tid] = (tid < N_) ? cnt0[tid] : 0;
    s1[tid] = (tid < N_) ? cnt1[tid] : 0;
    __syncthreads();
    for (int o = 1; o < 512; o <<= 1) {
        int v0 = (tid >= o) ? s0[tid-o] : 0;
        int v1 = (tid >= o) ? s1[tid-o] : 0;
        __syncthreads();
        s0[tid] += v0; s1[tid] += v1;
        __syncthreads();
    }
    if (tid == 0) { ptr0[0] = 0; ptr1[0] = 0; }
    if (tid < N_) {
        ptr0[tid+1] = s0[tid]; ptr1[tid+1] = s1[tid];
        cur0[tid] = (tid == 0) ? 0 : s0[tid-1];
        cur1[tid] = (tid == 0) ? 0 : s1[tid-1];
    }
}
__global__ void kern_efill(const int* __restrict__ idx, const int* __restrict__ map,
    const float* __restrict__ Af, const float* __restrict__ Ab,
    int* __restrict__ cur0, int* __restrict__ cur1,
    int* __restrict__ e0id, int* __restrict__ e0nb, float* __restrict__ a0v,
    int* __restrict__ e1id, int* __restrict__ e1nb, float* __restrict__ a1v)
{
    int e = blockIdx.x*256 + threadIdx.x;
    if (e >= E_) return;
    int i0 = idx[e], i1 = idx[E_+e];
    if (map[i0*N_+i1] != e) return;
    int s1 = atomicAdd(&cur1[i1], 1);
    e0id[s1] = e; e0nb[s1] = i0; a0v[s1] = Af[i0*N_+i1];
    int s0 = atomicAdd(&cur0[i0], 1);
    e1id[s0] = e; e1nb[s0] = i1; a1v[s0] = Ab[i1*N_+i0];
}

// ---------------- per-(b,n) mean over t, dotted with 4 C-vectors ----------------
__global__ __launch_bounds__(64) void kern_umean(const float* __restrict__ x, int Tin,
    const float* __restrict__ vsf, const float* __restrict__ vdf,
    const float* __restrict__ vsb, const float* __restrict__ vdb,
    float* __restrict__ usf, float* __restrict__ udf, float* __restrict__ usb, float* __restrict__ udb)
{
    int bn = blockIdx.x;
    const float* xp = x + (size_t)bn*Tin*C_;
    int tid = threadIdx.x;
    float a0=0.f,a1=0.f,a2=0.f,a3=0.f;
    for (int i = tid; i < Tin*C_; i += 64) {
        float v = xp[i]; int c = i % C_;
        a0 += v*vsf[c]; a1 += v*vdf[c]; a2 += v*vsb[c]; a3 += v*vdb[c];
    }
    for (int o = 32; o > 0; o >>= 1) {
        a0 += __shfl_down(a0,o); a1 += __shfl_down(a1,o);
        a2 += __shfl_down(a2,o); a3 += __shfl_down(a3,o);
    }
    if (tid == 0) {
        float inv = 1.f/(float)Tin;
        usf[bn]=a0*inv; udf[bn]=a1*inv; usb[bn]=a2*inv; udb[bn]=a3*inv;
    }
}

__global__ void kern_sc(const int* __restrict__ idx,
    const float* __restrict__ usf, const float* __restrict__ udf,
    const float* __restrict__ usb, const float* __restrict__ udb,
    float* __restrict__ scf, float* __restrict__ scb)
{
    int i = blockIdx.x*256 + threadIdx.x;
    if (i >= B_*E_) return;
    int b = i / E_, e = i % E_;
    int i0 = idx[e], i1 = idx[E_+e];
    scf[i] = usf[b*N_+i0] + udf[b*N_+i1];
    scb[i] = usb[b*N_+i0] + udb[b*N_+i1];
}

__global__ __launch_bounds__(320) void kern_t(const float* __restrict__ scf, const float* __restrict__ scb,
    const float* __restrict__ G0, float* __restrict__ tf, float* __restrict__ tb)
{
    int b = blockIdx.x, chunk = blockIdx.y;
    int e0 = chunk*250;
    __shared__ float sf[250], sb2[250];
    int tid = threadIdx.x;
    for (int i = tid; i < 250; i += 320) { sf[i] = scf[b*E_+e0+i]; sb2[i] = scb[b*E_+e0+i]; }
    __syncthreads();
    if (tid < EH_) {
        float af = 0.f, ab = 0.f;
        for (int i = 0; i < 250; ++i) {
            float g = G0[(size_t)(e0+i)*EH_ + tid];
            af += sf[i]*g; ab += sb2[i]*g;
        }
        atomicAdd(&tf[b*EH_+tid], af);
        atomicAdd(&tb[b*EH_+tid], ab);
    }
}

__global__ __launch_bounds__(256) void kern_ef(const float* __restrict__ tf, const float* __restrict__ tb,
    const float* __restrict__ wf, const float* __restrict__ wb, const float* __restrict__ G1,
    float* __restrict__ ef, float* __restrict__ eb)
{
    int b = blockIdx.y;
    int e = blockIdx.x*256 + threadIdx.x;
    __shared__ float f[EH_], g[EH_];
    for (int i = threadIdx.x; i < EH_; i += 256) {
        f[i] = tf[b*EH_+i]*wf[i];
        g[i] = tb[b*EH_+i]*wb[i];
    }
    __syncthreads();
    if (e < E_) {
        float af = 0.f, ab = 0.f;
        for (int h = 0; h < EH_; ++h) {
            float v = G1[(size_t)h*E_ + e];
            af += f[h]*v; ab += g[h]*v;
        }
        ef[b*E_+e] = sigm(af);
        eb[b*E_+e] = sigm(ab);
    }
}

// ---------------- dilated conv + gate, fused with gconv chunk0; also writes transposed bf16 xgT ----------------
__global__ __launch_bounds__(256) void kern_dconv_acc(const float* __restrict__ x, int Tin,
    const float* __restrict__ fw, const float* __restrict__ fb4,
    const float* __restrict__ gw, const float* __restrict__ gb4,
    const float* __restrict__ wl0, const float* __restrict__ gbias,
    float* __restrict__ xg, float* __restrict__ gc,
    __hip_bfloat16* __restrict__ xgT, int JP)
{
    int Tout = Tin - 2;
    int nout = Tout*C_;
    int tile = threadIdx.x >> 7;
    int lane = threadIdx.x & 127;
    int bn = blockIdx.x*2 + tile;
    int b = bn / N_, n = bn % N_;
    __shared__ alignas(16) float xs[2][T0_*C_];
    __shared__ alignas(16) float wf[2*C_*C_];
    __shared__ alignas(16) float wg[2*C_*C_];
    __shared__ alignas(16) float wl[C_*C_];
    __shared__ alignas(16) float ps[2][11*C_];
    int tid = threadIdx.x;
    {
        const float4* xp = (const float4*)(x + (size_t)bn*Tin*C_);
        float4* xd = (float4*)xs[tile];
        for (int i = lane; i < (Tin*C_)/4; i += 128) xd[i] = xp[i];
    }
    for (int i = tid; i < 2*C_*C_; i += 256) {
        int k = i / (C_*C_); int r = i % (C_*C_); int c = r / C_; int o = r % C_;
        wf[i] = fw[(o*C_+c)*2 + k];
        wg[i] = gw[(o*C_+c)*2 + k];
    }
    for (int i = tid; i < C_*C_; i += 256) wl[i] = wl0[i];
    __syncthreads();
    int nq = Tout*10;
    for (int u = lane; u < nq; u += 128) {
        int t = u/10, o = (u%10)*4;
        float4 f4 = *(const float4*)&fb4[o];
        float4 g4 = *(const float4*)&gb4[o];
        for (int c = 0; c < C_; ++c) {
            float x0v = xs[tile][t*C_+c], x2v = xs[tile][(t+2)*C_+c];
            float4 wf0 = *(const float4*)&wf[c*C_+o];
            float4 wf1 = *(const float4*)&wf[C_*C_ + c*C_+o];
            float4 wg0 = *(const float4*)&wg[c*C_+o];
            float4 wg1 = *(const float4*)&wg[C_*C_ + c*C_+o];
            f4.x += wf0.x*x0v + wf1.x*x2v;  f4.y += wf0.y*x0v + wf1.y*x2v;
            f4.z += wf0.z*x0v + wf1.z*x2v;  f4.w += wf0.w*x0v + wf1.w*x2v;
            g4.x += wg0.x*x0v + wg1.x*x2v;  g4.y += wg0.y*x0v + wg1.y*x2v;
            g4.z += wg0.z*x0v + wg1.z*x2v;  g4.w += wg0.w*x0v + wg1.w*x2v;
        }
        float4 r4;
        r4.x = tanhf(f4.x)*sigm(g4.x);
        r4.y = tanhf(f4.y)*sigm(g4.y);
        r4.z = tanhf(f4.z)*sigm(g4.z);
        r4.w = tanhf(f4.w)*sigm(g4.w);
        *(float4*)&ps[tile][t*C_+o] = r4;
        *(float4*)&xg[(size_t)bn*nout + t*C_+o] = r4;
        int j = t*C_+o;
        size_t tb = ((size_t)b*JP + j)*KP_ + n;
        xgT[tb]          = __float2bfloat16(r4.x);
        xgT[tb + KP_]    = __float2bfloat16(r4.y);
        xgT[tb + 2*KP_]  = __float2bfloat16(r4.z);
        xgT[tb + 3*KP_]  = __float2bfloat16(r4.w);
    }
    __syncthreads();
    for (int u = lane; u < nq; u += 128) {
        int t = u/10, o = (u%10)*4;
        float4 a4 = *(const float4*)&gbias[o];
        for (int c = 0; c < C_; ++c) {
            float s = ps[tile][t*C_+c];
            float4 w = *(const float4*)&wl[c*C_+o];
            a4.x += s*w.x; a4.y += s*w.y; a4.z += s*w.z; a4.w += s*w.w;
        }
        *(float4*)&gc[(size_t)bn*nout + t*C_+o] = a4;
    }
}

// ---- fused sparse graph op + gconv accumulate (2 bn tiles / block) ----
__global__ __launch_bounds__(256) void kern_sparse_acc(const float* __restrict__ in,
    float* __restrict__ outTile, int Tout,
    const int* __restrict__ ptr, const int* __restrict__ nbr, const int* __restrict__ eid,
    const float* __restrict__ aval, const float* __restrict__ coef,
    const float* __restrict__ Amat, const int* __restrict__ selfe,
    const float* __restrict__ gwp, float* __restrict__ gc)
{
    int tile = threadIdx.x >> 7;
    int lane = threadIdx.x & 127;
    int bn = blockIdx.x*2 + tile;
    int b = bn / N_, m = bn % N_;
    __shared__ float wv[2][64];
    __shared__ int   nb[2][64];
    __shared__ alignas(16) float ps[2][11*C_];
    __shared__ alignas(16) float wl[C_*C_];
    int tid = threadIdx.x;
    int p0 = ptr[m], p1 = ptr[m+1];
    int deg = p1 - p0; if (deg > 64) deg = 64;
    if (lane < deg) {
        wv[tile][lane] = coef[b*E_ + eid[p0+lane]] * aval[p0+lane];
        nb[tile][lane] = nbr[p0+lane];
    }
    for (int i = tid; i < C_*C_; i += 256) wl[i] = gwp[i];
    __syncthreads();
    float dval = (selfe[m] >= 0) ? 0.f : Amat[(size_t)m*N_ + m];
    const float* inb = in + (size_t)b*N_*Tout*C_;
    int nout = Tout*C_;
    for (int oi = lane; oi < nout; oi += 128) {
        float acc = dval * inb[(size_t)m*nout + oi];
        for (int j = 0; j < deg; ++j) acc += wv[tile][j]*inb[(size_t)nb[tile][j]*nout + oi];
        ps[tile][oi] = acc;
        if (outTile) outTile[(size_t)bn*nout + oi] = acc;
    }
    __syncthreads();
    int nq = Tout*10;
    for (int u = lane; u < nq; u += 128) {
        int t = u/10, o = (u%10)*4;
        float4 a4 = *(const float4*)&gc[(size_t)bn*nout + t*C_+o];
        for (int c = 0; c < C_; ++c) {
            float s = ps[tile][t*C_+c];
            float4 w = *(const float4*)&wl[c*C_+o];
            a4.x += s*w.x; a4.y += s*w.y; a4.z += s*w.z; a4.w += s*w.w;
        }
        *(float4*)&gc[(size_t)bn*nout + t*C_+o] = a4;
    }
}

// ---------------- adp dense hop via MFMA bf16 (A frags preloaded to registers) ----------------
__global__ __launch_bounds__(256) void kern_gemm_mfma(const __hip_bfloat16* __restrict__ adpTb,
    const __hip_bfloat16* __restrict__ inT, float* __restrict__ outF,
    __hip_bfloat16* __restrict__ outT, int LD, int JP)
{
    int tid = threadIdx.x;
    int wave = tid >> 6, lane = tid & 63;
    int rn = lane & 15, q = lane >> 4;
    int b = blockIdx.z;
    int m0 = blockIdx.x*64;
    int j0 = blockIdx.y*64;
    const short* Ap = (const short*)adpTb + (size_t)(m0 + wave*16 + rn)*KP_ + q*8;
    bf16x8 areg[16];
    #pragma unroll
    for (int kk = 0; kk < 16; ++kk) areg[kk] = *(const bf16x8*)(Ap + kk*32);
    const short* Bp = (const short*)inT + ((size_t)b*JP + j0 + rn)*KP_ + q*8;
    f32x4 acc[4] = {};
    #pragma unroll
    for (int kk = 0; kk < 16; ++kk) {
        #pragma unroll
        for (int s = 0; s < 4; ++s) {
            bf16x8 bb = *(const bf16x8*)(Bp + (size_t)s*16*KP_ + kk*32);
            acc[s] = __builtin_amdgcn_mfma_f32_16x16x32_bf16(areg[kk], bb, acc[s], 0, 0, 0);
        }
    }
    int mb = m0 + wave*16 + q*4;     // D row base
    #pragma unroll
    for (int s = 0; s < 4; ++s) {
        int j = j0 + s*16 + rn;      // D col
        if (j >= LD) continue;
        #pragma unroll
        for (int r = 0; r < 4; ++r) {
            int m = mb + r;
            if (m < N_) outF[((size_t)b*N_ + m)*LD + j] = acc[s][r];
        }
        if (outT) {
            ushort4 v;
            v.x = f2bf(acc[s][0]); v.y = f2bf(acc[s][1]);
            v.z = f2bf(acc[s][2]); v.w = f2bf(acc[s][3]);
            *(ushort4*)((unsigned short*)outT + ((size_t)b*JP + j)*KP_ + mb) = v;
        }
    }
}

// ---------------- gconv accumulate one 40-chunk (2 bn tiles / block) ----------------
__global__ __launch_bounds__(256) void kern_gacc(const float* __restrict__ part, const float* __restrict__ gwp,
    float* __restrict__ gc, int Tout)
{
    int tile = threadIdx.x >> 7;
    int lane = threadIdx.x & 127;
    int bn = blockIdx.x*2 + tile;
    int nout = Tout*C_;
    __shared__ alignas(16) float ps[2][11*C_];
    __shared__ alignas(16) float wl[C_*C_];
    int tid = threadIdx.x;
    {
        const float4* pp = (const float4*)(part + (size_t)bn*nout);
        float4* pd = (float4*)ps[tile];
        for (int i = lane; i < nout/4; i += 128) pd[i] = pp[i];
    }
    for (int i = tid; i < C_*C_; i += 256) wl[i] = gwp[i];
    __syncthreads();
    int nq = Tout*10;
    for (int u = lane; u < nq; u += 128) {
        int t = u/10, o = (u%10)*4;
        float4 a4 = *(const float4*)&gc[(size_t)bn*nout + t*C_+o];
        for (int c = 0; c < C_; ++c) {
            float s = ps[tile][t*C_+c];
            float4 w = *(const float4*)&wl[c*C_+o];
            a4.x += s*w.x; a4.y += s*w.y; a4.z += s*w.z; a4.w += s*w.w;
        }
        *(float4*)&gc[(size_t)bn*nout + t*C_+o] = a4;
    }
}

// ---------------- BN stats per channel ----------------
__global__ __launch_bounds__(320) void kern_bnstats(const float* __restrict__ src, size_t total, float* __restrict__ acc)
{
    int tid = threadIdx.x;
    float s = 0.f, ss = 0.f;
    for (size_t i = (size_t)blockIdx.x*320 + tid; i < total; i += (size_t)gridDim.x*320) {
        float v = src[i]; s += v; ss += v*v;
    }
    __shared__ float ls[320], lss[320];
    ls[tid] = s; lss[tid] = ss; __syncthreads();
    if (tid < C_) {
        float t1 = 0.f, t2 = 0.f;
        for (int r = 0; r < 8; ++r) { t1 += ls[r*C_+tid]; t2 += lss[r*C_+tid]; }
        atomicAdd(&acc[tid], t1); atomicAdd(&acc[C_+tid], t2);
    }
}

__global__ __launch_bounds__(320) void kern_bn1(float* __restrict__ gc, const float* __restrict__ resid,
    int Tin, int Tout, const float* __restrict__ acc1,
    const float* __restrict__ g1, const float* __restrict__ b1, float* __restrict__ acc2)
{
    int tid = threadIdx.x; int c = tid % C_;
    float cnt = (float)(B_*N_*Tout);
    float mean = acc1[c]/cnt;
    float var  = acc1[C_+c]/cnt - mean*mean;
    float inv  = rsqrtf(var + EPS_);
    float gg = g1[c], bb = b1[c];
    int dlt = Tin - Tout;
    float s = 0.f, ss = 0.f;
    size_t total = (size_t)B_*N_*Tout*C_;
    for (size_t i = (size_t)blockIdx.x*320 + tid; i < total; i += (size_t)gridDim.x*320) {
        size_t pos = i / C_; int t = (int)(pos % Tout); size_t bn = pos / Tout;
        float y = gg*(gc[i]-mean)*inv + bb;
        y += resid[(bn*Tin + (t+dlt))*C_ + c];
        gc[i] = y;
        s += y; ss += y*y;
    }
    __shared__ float ls[320], lss[320];
    ls[tid] = s; lss[tid] = ss; __syncthreads();
    if (tid < C_) {
        float t1 = 0.f, t2 = 0.f;
        for (int r = 0; r < 8; ++r) { t1 += ls[r*C_+tid]; t2 += lss[r*C_+tid]; }
        atomicAdd(&acc2[tid], t1); atomicAdd(&acc2[C_+tid], t2);
    }
}

__global__ __launch_bounds__(256) void kern_bn2(const float* __restrict__ gc, float* __restrict__ xout, int Tout,
    const float* __restrict__ acc2, const float* __restrict__ g2, const float* __restrict__ b2)
{
    size_t total = (size_t)B_*N_*Tout*C_;
    size_t i = (size_t)blockIdx.x*256 + threadIdx.x;
    if (i >= total) return;
    int c = (int)(i % C_);
    float cnt = (float)(B_*N_*Tout);
    float mean = acc2[c]/cnt;
    float var  = acc2[C_+c]/cnt - mean*mean;
    float inv  = rsqrtf(var + EPS_);
    xout[i] = g2[c]*(gc[i]-mean)*inv + b2[c];
}

// ---------------- skip conv on last 7 steps -> bf16 skip(B,N,7,320); 4 bn per block ----------------
__global__ __launch_bounds__(256) void kern_skip(const float* __restrict__ x, int Tout,
    const float* __restrict__ sw, const float* __restrict__ sbias, __hip_bfloat16* __restrict__ skp, int first)
{
    int bn0 = blockIdx.x*4; int half = blockIdx.y;
    int off = Tout - 7;
    __shared__ alignas(16) float xs[4][7*C_];
    __shared__ alignas(16) float wl[C_*164];
    int tid = threadIdx.x;
    for (int i = tid; i < 4*(7*C_/4); i += 256) {
        int bl = i / 70, r = i % 70;
        ((float4*)xs[bl])[r] = ((const float4*)(x + ((size_t)(bn0+bl)*Tout + off)*C_))[r];
    }
    for (int i = tid; i < 160*C_; i += 256) {
        int oo = i / C_, c = i % C_;
        wl[c*164 + oo] = sw[(size_t)(half*160 + oo)*C_ + c];
    }
    __syncthreads();
    for (int u = tid; u < 4*7*40; u += 256) {
        int bl = u / 280; int v = u % 280;
        int t = v / 40, o = (v % 40)*4;
        float4 a4 = {0.f,0.f,0.f,0.f};
        for (int c = 0; c < C_; ++c) {
            float s = xs[bl][t*C_+c];
            float4 w = *(const float4*)&wl[c*164 + o];
            a4.x += s*w.x; a4.y += s*w.y; a4.z += s*w.z; a4.w += s*w.w;
        }
        int og = half*160 + o;
        float4 b4 = *(const float4*)&sbias[og];
        a4.x += b4.x; a4.y += b4.y; a4.z += b4.z; a4.w += b4.w;
        size_t di = ((size_t)(bn0+bl)*7 + t)*320 + og;
        if (first) {
            skp[di+0] = __float2bfloat16(a4.x);
            skp[di+1] = __float2bfloat16(a4.y);
            skp[di+2] = __float2bfloat16(a4.z);
            skp[di+3] = __float2bfloat16(a4.w);
        } else {
            skp[di+0] = __float2bfloat16(__bfloat162float(skp[di+0]) + a4.x);
            skp[di+1] = __float2bfloat16(__bfloat162float(skp[di+1]) + a4.y);
            skp[di+2] = __float2bfloat16(__bfloat162float(skp[di+2]) + a4.z);
            skp[di+3] = __float2bfloat16(__bfloat162float(skp[di+3]) + a4.w);
        }
    }
}

__global__ __launch_bounds__(256) void kern_cvtw(const float* __restrict__ w, __hip_bfloat16* __restrict__ wb, int n)
{
    int i = blockIdx.x*256 + threadIdx.x;
    if (i < n) wb[i] = __float2bfloat16(w[i]);
}

// ---------------- fused end stage: lrelu(skp) @ e1w (+bias,lrelu) @ e2w^T + e2b -> out ----------------
// Barrier-free csp loop: MFMA for end1, per-lane VALU FMA for end2, shfl_xor final reduction.
constexpr int ASD_ = 324;   // LDS A row stride in shorts (320 + 4 pad -> conflict-free b128)
__global__ __launch_bounds__(256) void kern_end2(const __hip_bfloat16* __restrict__ skp,
    const __hip_bfloat16* __restrict__ e1wb, const float* __restrict__ e1b,
    const float* __restrict__ e2w, const float* __restrict__ e2b, float* __restrict__ out)
{
    __shared__ short As[64*ASD_];         // 41472 B, coalesced-staged A tile
    __shared__ _Float16 w2h[640][12];     // 15360 B
    int tid = threadIdx.x;
    int wave = tid >> 6, lane = tid & 63;
    int rn = lane & 15, q = lane >> 4;
    int m0 = blockIdx.x*64;
    // stage A (raw bf16) with perfectly coalesced 16B loads
    {
        const bf16x8* gA = (const bf16x8*)((const short*)skp + (size_t)m0*320);
        for (int i = tid; i < 2560; i += 256) {
            bf16x8 v = gA[i];
            int row = i / 40, col = (i % 40)*8;
            *(bf16x8*)&As[row*ASD_ + col] = v;
        }
    }
    // stage w2 (f16)
    for (int i = tid; i < 640*12; i += 256) {
        int c = i / 12, o = i % 12;
        w2h[c][o] = (_Float16)e2w[o*640 + c];
    }
    __syncthreads();
    // A frags -> registers, lrelu applied
    bf16x8 areg[10];
    {
        const short* Arow = As + (wave*16 + rn)*ASD_ + q*8;
        #pragma unroll
        for (int kk = 0; kk < 10; ++kk) {
            bf16x8 v = *(const bf16x8*)(Arow + kk*32);
            bf16x8 r;
            #pragma unroll
            for (int e = 0; e < 8; ++e)
                r[e] = (short)f2bf(lrelu(bf2f((unsigned short)v[e])));
            areg[kk] = r;
        }
    }
    float acc_out[4][12] = {};
    const short* e1p = (const short*)e1wb;
    for (int csp = 0; csp < 20; ++csp) {
        const short* Bp0 = e1p + (size_t)(csp*32 + rn)*320 + q*8;
        const short* Bp1 = Bp0 + 16*320;
        f32x4 c00 = {}, c01 = {}, c10 = {}, c11 = {};
        #pragma unroll
        for (int kk = 0; kk < 10; kk += 2) {
            bf16x8 b00 = *(const bf16x8*)(Bp0 + kk*32);
            bf16x8 b01 = *(const bf16x8*)(Bp0 + (kk+1)*32);
            bf16x8 b10 = *(const bf16x8*)(Bp1 + kk*32);
            bf16x8 b11 = *(const bf16x8*)(Bp1 + (kk+1)*32);
            c00 = __builtin_amdgcn_mfma_f32_16x16x32_bf16(areg[kk],   b00, c00, 0, 0, 0);
            c10 = __builtin_amdgcn_mfma_f32_16x16x32_bf16(areg[kk],   b10, c10, 0, 0, 0);
            c01 = __builtin_amdgcn_mfma_f32_16x16x32_bf16(areg[kk+1], b01, c01, 0, 0, 0);
            c11 = __builtin_amdgcn_mfma_f32_16x16x32_bf16(areg[kk+1], b11, c11, 0, 0, 0);
        }
        int ca = csp*32 + rn, cb = ca + 16;
        float bias0 = e1b[ca], bias1 = e1b[cb];
        float wa[12], wb[12];
        #pragma unroll
        for (int o = 0; o < 12; ++o) { wa[o] = (float)w2h[ca][o]; wb[o] = (float)w2h[cb][o]; }
        #pragma unroll
        for (int r = 0; r < 4; ++r) {
            float y0 = lrelu(c00[r] + c01[r] + bias0);
            float y1 = lrelu(c10[r] + c11[r] + bias1);
            #pragma unroll
            for (int o = 0; o < 12; ++o)
                acc_out[r][o] += y0*wa[o] + y1*wb[o];
        }
    }
    // reduce over the 16 rn-lanes (masks keep q-group intact)
    #pragma unroll
    for (int r = 0; r < 4; ++r)
        #pragma unroll
        for (int o = 0; o < 12; ++o) {
            float v = acc_out[r][o];
            v += __shfl_xor(v, 1);
            v += __shfl_xor(v, 2);
            v += __shfl_xor(v, 4);
            v += __shfl_xor(v, 8);
            acc_out[r][o] = v;
        }
    if (rn < 12) {
        float bo = e2b[rn];
        #pragma unroll
        for (int r = 0; r < 4; ++r) {
            int gm = m0 + wave*16 + q*4 + r;
            int t = gm % 7; int bn = gm / 7; int n = bn % N_; int b = bn / N_;
            out[(((size_t)b*12 + rn)*N_ + n)*7 + t] = acc_out[r][rn] + bo;
        }
    }
}

extern "C" void kernel_launch(void* const* d_in, const int* in_sizes, int n_in,
                              void* d_out, int out_size, void* d_ws, size_t ws_size,
                              hipStream_t stream)
{
    (void)in_sizes; (void)n_in; (void)out_size;
    const float* input   = (const float*)d_in[0];
    const float* A_fwd   = (const float*)d_in[1];
    const float* A_bwd   = (const float*)d_in[2];
    const int*   indices = (const int*)  d_in[3];
    const float* G0      = (const float*)d_in[4];
    const float* G1      = (const float*)d_in[5];
    const float* nv1     = (const float*)d_in[6];
    const float* nv2     = (const float*)d_in[7];
    const float* wef     = (const float*)d_in[8];
    const float* web     = (const float*)d_in[9];
    const float* vsf     = (const float*)d_in[10];
    const float* vdf     = (const float*)d_in[11];
    const float* vsb     = (const float*)d_in[12];
    const float* vdb     = (const float*)d_in[13];
    const float* start_w = (const float*)d_in[14];
    const float* start_b = (const float*)d_in[15];
    const float* filt_w  = (const float*)d_in[16];
    const float* filt_b  = (const float*)d_in[17];
    const float* gate_w  = (const float*)d_in[18];
    const float* gate_b  = (const float*)d_in[19];
    const float* gcw     = (const float*)d_in[20];
    const float* gcb     = (const float*)d_in[21];
    const float* bng_g   = (const float*)d_in[22];
    const float* bng_b   = (const float*)d_in[23];
    const float* bn_g    = (const float*)d_in[24];
    const float* bn_b    = (const float*)d_in[25];
    const float* skw     = (const float*)d_in[26];
    const float* skb     = (const float*)d_in[27];
    const float* e1w     = (const float*)d_in[28];
    const float* e1b     = (const float*)d_in[29];
    const float* e2w     = (const float*)d_in[30];
    const float* e2b     = (const float*)d_in[31];
    float* out = (float*)d_out;

    // ---- workspace layout (4B units, 16B-aligned allocations) ----
    float* W = (float*)d_ws;
    size_t off = 0;
    auto FA = [&](size_t n){ off = (off + 3) & ~(size_t)3; float* p = W + off; off += n; return p; };
    float* insum  = FA(2);
    float* tf     = FA((size_t)B_*EH_);
    float* tb     = FA((size_t)B_*EH_);
    float* bnacc1 = FA(80);
    float* bnacc2 = FA(80);
    float* usf = FA((size_t)B_*N_); float* udf = FA((size_t)B_*N_);
    float* usb = FA((size_t)B_*N_); float* udb = FA((size_t)B_*N_);
    float* scf = FA((size_t)B_*E_); float* scb = FA((size_t)B_*E_);
    float* efv = FA((size_t)B_*E_); float* ebv = FA((size_t)B_*E_);
    __hip_bfloat16* adpTb = (__hip_bfloat16*)FA((size_t)KP_*KP_/2);
    float* a0v = FA(E_); float* a1v = FA(E_);
    int* map  = (int*)FA((size_t)N_*N_);
    int* cnt0 = (int*)FA(512); int* cnt1 = (int*)FA(512);
    int* ptr0 = (int*)FA(512); int* ptr1 = (int*)FA(512);
    int* cur0 = (int*)FA(512); int* cur1 = (int*)FA(512);
    int* selfe = (int*)FA(512);
    int* e0id = (int*)FA(E_); int* e0nb = (int*)FA(E_);
    int* e1id = (int*)FA(E_); int* e1nb = (int*)FA(E_);
    float* xA  = FA((size_t)B_*N_*T0_*C_);
    float* xg  = FA((size_t)B_*N_*11*C_);
    float* pa  = FA((size_t)B_*N_*11*C_);
    float* gc  = FA((size_t)B_*N_*11*C_);
    __hip_bfloat16* skp = (__hip_bfloat16*)FA((size_t)B_*N_*7*320/2);
    __hip_bfloat16* xgT = (__hip_bfloat16*)FA((size_t)B_*448*KP_/2);
    __hip_bfloat16* paT = (__hip_bfloat16*)FA((size_t)B_*448*KP_/2);
    // e1wb overlays xg (dead after block loop, rewritten every call)
    __hip_bfloat16* e1wb = (__hip_bfloat16*)xg;

    if (ws_size < off*sizeof(float)) return;   // fail cleanly, not a fault

    // ---- setup ----
    kern_init<<<(N_*N_+255)/256, 256, 0, stream>>>(insum, map, cnt0, selfe, (int*)adpTb);
    kern_instats<<<256, 256, 0, stream>>>(input, insum);
    kern_x0<<<(B_*N_*T0_*C_+255)/256, 256, 0, stream>>>(input, insum, start_w, start_b, xA);
    kern_adp<<<N_, 512, 0, stream>>>(nv1, nv2, adpTb);
    kern_emax<<<(E_+255)/256, 256, 0, stream>>>(indices, map);
    kern_ecnt<<<(E_+255)/256, 256, 0, stream>>>(indices, map, cnt0, cnt1, selfe);
    kern_scan<<<1, 512, 0, stream>>>(cnt0, cnt1, ptr0, ptr1, cur0, cur1);
    kern_efill<<<(E_+255)/256, 256, 0, stream>>>(indices, map, A_fwd, A_bwd, cur0, cur1,
                                                 e0id, e0nb, a0v, e1id, e1nb, a1v);

    // ---- 3 blocks ----
    for (int blk = 0; blk < 3; ++blk) {
        int Tin = T0_ - 2*blk;
        int Tout = Tin - 2;
        int LD = Tout*C_;
        int JP = (LD + 63) & ~63;
        size_t total = (size_t)B_*N_*Tout*C_;
        kern_zeroacc<<<(2*B_*EH_+160+255)/256, 256, 0, stream>>>(tf, 2*B_*EH_+160);

        kern_umean<<<B_*N_, 64, 0, stream>>>(xA, Tin, vsf+blk*C_, vdf+blk*C_, vsb+blk*C_, vdb+blk*C_,
                                             usf, udf, usb, udb);
        kern_sc<<<(B_*E_+255)/256, 256, 0, stream>>>(indices, usf, udf, usb, udb, scf, scb);
        kern_t<<<dim3(B_, 8), 320, 0, stream>>>(scf, scb, G0, tf, tb);
        kern_ef<<<dim3(8, B_), 256, 0, stream>>>(tf, tb, wef, web, G1, efv, ebv);

        const float* gwb = gcw + (size_t)blk*7*C_*C_;
        kern_dconv_acc<<<B_*N_/2, 256, 0, stream>>>(xA, Tin,
            filt_w + (size_t)blk*2*C_*C_, filt_b + blk*C_,
            gate_w + (size_t)blk*2*C_*C_, gate_b + blk*C_,
            gwb + 0*C_*C_, gcb + blk*C_, xg, gc, xgT, JP);
        // s0 two hops
        kern_sparse_acc<<<B_*N_/2, 256, 0, stream>>>(xg, pa, Tout, ptr1, e0nb, e0id, a0v, efv,
                                                     A_fwd, selfe, gwb + 1*C_*C_, gc);
        kern_sparse_acc<<<B_*N_/2, 256, 0, stream>>>(pa, nullptr, Tout, ptr1, e0nb, e0id, a0v, efv,
                                                     A_fwd, selfe, gwb + 2*C_*C_, gc);
        // s1 two hops
        kern_sparse_acc<<<B_*N_/2, 256, 0, stream>>>(xg, pa, Tout, ptr0, e1nb, e1id, a1v, ebv,
                                                     A_bwd, selfe, gwb + 3*C_*C_, gc);
        kern_sparse_acc<<<B_*N_/2, 256, 0, stream>>>(pa, nullptr, Tout, ptr0, e1nb, e1id, a1v, ebv,
                                                     A_bwd, selfe, gwb + 4*C_*C_, gc);
        // adp two dense hops via MFMA
        dim3 gg(8, JP/64, B_);
        kern_gemm_mfma<<<gg, 256, 0, stream>>>(adpTb, xgT, pa, paT, LD, JP);
        kern_gacc<<<B_*N_/2, 256, 0, stream>>>(pa, gwb + 5*C_*C_, gc, Tout);
        kern_gemm_mfma<<<gg, 256, 0, stream>>>(adpTb, paT, xg, nullptr, LD, JP);
        kern_gacc<<<B_*N_/2, 256, 0, stream>>>(xg, gwb + 6*C_*C_, gc, Tout);

        kern_bnstats<<<512, 320, 0, stream>>>(gc, total, bnacc1);
        kern_bn1<<<512, 320, 0, stream>>>(gc, xA, Tin, Tout, bnacc1, bng_g + blk*C_, bng_b + blk*C_, bnacc2);
        kern_bn2<<<(int)((total+255)/256), 256, 0, stream>>>(gc, xA, Tout, bnacc2, bn_g + blk*C_, bn_b + blk*C_);

        kern_skip<<<dim3(B_*N_/4, 2), 256, 0, stream>>>(xA, Tout, skw + (size_t)blk*320*C_, skb + blk*320,
                                                        skp, blk == 0 ? 1 : 0);
    }

    // ---- end stage ----
    kern_cvtw<<<(640*320+255)/256, 256, 0, stream>>>(e1w, e1wb, 640*320);
    kern_end2<<<B_*N_*7/64, 256, 0, stream>>>(skp, e1wb, e1b, e2w, e2b, out);
}

// Round 7
// 2522.925 us; speedup vs baseline: 1.9042x; 1.0322x over previous
//
#include <hip/hip_runtime.h>
#include <hip/hip_bf16.h>

constexpr int B_  = 32;
constexpr int N_  = 500;
constexpr int T0_ = 13;
constexpr int E_  = 2000;
constexpr int EH_ = 300;
constexpr int C_  = 40;
constexpr float EPS_ = 1e-5f;
constexpr int KP_ = 512;     // padded node dim for MFMA adp gemm

typedef short bf16x8 __attribute__((ext_vector_type(8)));
typedef _Float16 f16x8 __attribute__((ext_vector_type(8)));
typedef _Float16 f16x4 __attribute__((ext_vector_type(4)));
typedef float f32x4  __attribute__((ext_vector_type(4)));

__device__ __forceinline__ float sigm(float x){ return 1.f/(1.f+__expf(-x)); }
__device__ __forceinline__ float lrelu(float x){ return x > 0.f ? x : 0.01f*x; }
__device__ __forceinline__ unsigned short f2bf(float f){
    __hip_bfloat16 h = __float2bfloat16(f);
    return *(unsigned short*)&h;
}
__device__ __forceinline__ float bf2f(unsigned short us){
    __hip_bfloat16 h = *(__hip_bfloat16*)&us;
    return __bfloat162float(h);
}

// ---------------- init: zero/flag all small state ----------------
__global__ __launch_bounds__(256) void kern_init(float* __restrict__ insum, int* __restrict__ map,
                                                 int* __restrict__ cnts, int* __restrict__ selfe,
                                                 int* __restrict__ adpTbz)
{
    int i = blockIdx.x*256 + threadIdx.x;
    if (i < 2) insum[i] = 0.f;
    if (i < N_*N_) map[i] = -1;
    if (i < 1024) cnts[i] = 0;
    if (i < 512) selfe[i] = -1;
    if (i < KP_*KP_/2) adpTbz[i] = 0;
}

__global__ __launch_bounds__(256) void kern_zeroacc(float* __restrict__ p, int n)
{
    int i = blockIdx.x*256 + threadIdx.x;
    if (i < n) p[i] = 0.f;
}

// ---------------- input BN stats ----------------
__global__ __launch_bounds__(256) void kern_instats(const float* __restrict__ in, float* __restrict__ acc)
{
    float s = 0.f, ss = 0.f;
    int total = B_*N_*T0_;
    for (int i = blockIdx.x*256 + threadIdx.x; i < total; i += gridDim.x*256) {
        float v = in[i]; s += v; ss += v*v;
    }
    __shared__ float l1[256], l2[256];
    l1[threadIdx.x] = s; l2[threadIdx.x] = ss; __syncthreads();
    for (int o = 128; o > 0; o >>= 1) {
        if (threadIdx.x < o) { l1[threadIdx.x] += l1[threadIdx.x+o]; l2[threadIdx.x] += l2[threadIdx.x+o]; }
        __syncthreads();
    }
    if (threadIdx.x == 0) { atomicAdd(&acc[0], l1[0]); atomicAdd(&acc[1], l2[0]); }
}

// ---------------- normalize + start conv -> x (B,N,T,C) ----------------
__global__ __launch_bounds__(256) void kern_x0(const float* __restrict__ in, const float* __restrict__ insum,
    const float* __restrict__ sw, const float* __restrict__ sb, float* __restrict__ x)
{
    int idx = blockIdx.x*256 + threadIdx.x;
    int total = B_*N_*T0_*C_;
    if (idx >= total) return;
    float cnt = (float)(B_*N_*T0_);
    float mean = insum[0]/cnt;
    float var  = insum[1]/cnt - mean*mean;
    float inv  = rsqrtf(var + EPS_);
    int c = idx % C_;
    int pos = idx / C_;
    float xn = (in[pos] - mean)*inv;
    x[idx] = sw[c]*xn + sb[c];
}

// ---------------- adp = softmax(relu(nv1@nv2), axis=1), stored transposed bf16 padded ----------------
__global__ __launch_bounds__(512) void kern_adp(const float* __restrict__ nv1, const float* __restrict__ nv2,
                                                __hip_bfloat16* __restrict__ adpTb)
{
    int n = blockIdx.x;
    int m = threadIdx.x;
    float r = 0.f;
    if (m < N_) {
        #pragma unroll
        for (int k = 0; k < 10; ++k) r += nv1[n*10+k]*nv2[k*N_+m];
        r = r > 0.f ? r : 0.f;
    }
    __shared__ float red[512];
    red[threadIdx.x] = (m < N_) ? r : -1e30f; __syncthreads();
    for (int o = 256; o > 0; o >>= 1) {
        if (threadIdx.x < o) red[threadIdx.x] = fmaxf(red[threadIdx.x], red[threadIdx.x+o]);
        __syncthreads();
    }
    float mx = red[0]; __syncthreads();
    float ev = (m < N_) ? __expf(r - mx) : 0.f;
    red[threadIdx.x] = ev; __syncthreads();
    for (int o = 256; o > 0; o >>= 1) {
        if (threadIdx.x < o) red[threadIdx.x] += red[threadIdx.x+o];
        __syncthreads();
    }
    float sum = red[0];
    if (m < N_) adpTb[(size_t)m*KP_ + n] = __float2bfloat16(ev/sum);
}

// ---------------- edge preprocessing ----------------
__global__ void kern_emax(const int* __restrict__ idx, int* __restrict__ map)
{
    int e = blockIdx.x*256 + threadIdx.x;
    if (e < E_) atomicMax(&map[idx[e]*N_ + idx[E_+e]], e);
}
__global__ void kern_ecnt(const int* __restrict__ idx, const int* __restrict__ map,
                          int* __restrict__ cnt0, int* __restrict__ cnt1, int* __restrict__ selfe)
{
    int e = blockIdx.x*256 + threadIdx.x;
    if (e >= E_) return;
    int i0 = idx[e], i1 = idx[E_+e];
    if (map[i0*N_+i1] != e) return;
    atomicAdd(&cnt1[i1], 1);
    atomicAdd(&cnt0[i0], 1);
    if (i0 == i1) selfe[i0] = e;
}
__global__ __launch_bounds__(512) void kern_scan(const int* __restrict__ cnt0, const int* __restrict__ cnt1,
    int* __restrict__ ptr0, int* __restrict__ ptr1, int* __restrict__ cur0, int* __restrict__ cur1)
{
    __shared__ int s0[512], s1[512];
    int tid = threadIdx.x;
    s0[tid] = (tid < N_) ? cnt0[tid] : 0;
    s1[tid] = (tid < N_) ? cnt1[tid] : 0;
    __syncthreads();
    for (int o = 1; o < 512; o <<= 1) {
        int v0 = (tid >= o) ? s0[tid-o] : 0;
        int v1 = (tid >= o) ? s1[tid-o] : 0;
        __syncthreads();
        s0[tid] += v0; s1[tid] += v1;
        __syncthreads();
    }
    if (tid == 0) { ptr0[0] = 0; ptr1[0] = 0; }
    if (tid < N_) {
        ptr0[tid+1] = s0[tid]; ptr1[tid+1] = s1[tid];
        cur0[tid] = (tid == 0) ? 0 : s0[tid-1];
        cur1[tid] = (tid == 0) ? 0 : s1[tid-1];
    }
}
__global__ void kern_efill(const int* __restrict__ idx, const int* __restrict__ map,
    const float* __restrict__ Af, const float* __restrict__ Ab,
    int* __restrict__ cur0, int* __restrict__ cur1,
    int* __restrict__ e0id, int* __restrict__ e0nb, float* __restrict__ a0v,
    int* __restrict__ e1id, int* __restrict__ e1nb, float* __restrict__ a1v)
{
    int e = blockIdx.x*256 + threadIdx.x;
    if (e >= E_) return;
    int i0 = idx[e], i1 = idx[E_+e];
    if (map[i0*N_+i1] != e) return;
    int s1 = atomicAdd(&cur1[i1], 1);
    e0id[s1] = e; e0nb[s1] = i0; a0v[s1] = Af[i0*N_+i1];
    int s0 = atomicAdd(&cur0[i0], 1);
    e1id[s0] = e; e1nb[s0] = i1; a1v[s0] = Ab[i1*N_+i0];
}

// ---------------- per-(b,n) mean over t, dotted with 4 C-vectors ----------------
__global__ __launch_bounds__(64) void kern_umean(const float* __restrict__ x, int Tin,
    const float* __restrict__ vsf, const float* __restrict__ vdf,
    const float* __restrict__ vsb, const float* __restrict__ vdb,
    float* __restrict__ usf, float* __restrict__ udf, float* __restrict__ usb, float* __restrict__ udb)
{
    int bn = blockIdx.x;
    const float* xp = x + (size_t)bn*Tin*C_;
    int tid = threadIdx.x;
    float a0=0.f,a1=0.f,a2=0.f,a3=0.f;
    for (int i = tid; i < Tin*C_; i += 64) {
        float v = xp[i]; int c = i % C_;
        a0 += v*vsf[c]; a1 += v*vdf[c]; a2 += v*vsb[c]; a3 += v*vdb[c];
    }
    for (int o = 32; o > 0; o >>= 1) {
        a0 += __shfl_down(a0,o); a1 += __shfl_down(a1,o);
        a2 += __shfl_down(a2,o); a3 += __shfl_down(a3,o);
    }
    if (tid == 0) {
        float inv = 1.f/(float)Tin;
        usf[bn]=a0*inv; udf[bn]=a1*inv; usb[bn]=a2*inv; udb[bn]=a3*inv;
    }
}

// ---------------- fused sc-gather + tf accumulate ----------------
__global__ __launch_bounds__(320) void kern_t(const int* __restrict__ idx,
    const float* __restrict__ usf, const float* __restrict__ udf,
    const float* __restrict__ usb, const float* __restrict__ udb,
    const float* __restrict__ G0, float* __restrict__ tf, float* __restrict__ tb,
    float* __restrict__ scf, float* __restrict__ scb)
{
    int b = blockIdx.x, chunk = blockIdx.y;
    int e0 = chunk*250;
    __shared__ float sf[250], sb2[250];
    int tid = threadIdx.x;
    for (int i = tid; i < 250; i += 320) {
        int e = e0 + i;
        int i0 = idx[e], i1 = idx[E_+e];
        float vf = usf[b*N_+i0] + udf[b*N_+i1];
        float vb = usb[b*N_+i0] + udb[b*N_+i1];
        sf[i] = vf; sb2[i] = vb;
        scf[b*E_+e] = vf; scb[b*E_+e] = vb;   // kept for debug-free reuse (cheap)
    }
    __syncthreads();
    if (tid < EH_) {
        float af = 0.f, ab = 0.f;
        for (int i = 0; i < 250; ++i) {
            float g = G0[(size_t)(e0+i)*EH_ + tid];
            af += sf[i]*g; ab += sb2[i]*g;
        }
        atomicAdd(&tf[b*EH_+tid], af);
        atomicAdd(&tb[b*EH_+tid], ab);
    }
}

__global__ __launch_bounds__(256) void kern_ef(const float* __restrict__ tf, const float* __restrict__ tb,
    const float* __restrict__ wf, const float* __restrict__ wb, const float* __restrict__ G1,
    float* __restrict__ ef, float* __restrict__ eb)
{
    int b = blockIdx.y;
    int e = blockIdx.x*256 + threadIdx.x;
    __shared__ float f[EH_], g[EH_];
    for (int i = threadIdx.x; i < EH_; i += 256) {
        f[i] = tf[b*EH_+i]*wf[i];
        g[i] = tb[b*EH_+i]*wb[i];
    }
    __syncthreads();
    if (e < E_) {
        float af = 0.f, ab = 0.f;
        for (int h = 0; h < EH_; ++h) {
            float v = G1[(size_t)h*E_ + e];
            af += f[h]*v; ab += g[h]*v;
        }
        ef[b*E_+e] = sigm(af);
        eb[b*E_+e] = sigm(ab);
    }
}

// ---------------- dilated conv + gate, fused with gconv chunk0; also writes transposed bf16 xgT ----------------
__global__ __launch_bounds__(256) void kern_dconv_acc(const float* __restrict__ x, int Tin,
    const float* __restrict__ fw, const float* __restrict__ fb4,
    const float* __restrict__ gw, const float* __restrict__ gb4,
    const float* __restrict__ wl0, const float* __restrict__ gbias,
    float* __restrict__ xg, float* __restrict__ gc,
    __hip_bfloat16* __restrict__ xgT, int JP)
{
    int Tout = Tin - 2;
    int nout = Tout*C_;
    int tile = threadIdx.x >> 7;
    int lane = threadIdx.x & 127;
    int bn = blockIdx.x*2 + tile;
    int b = bn / N_, n = bn % N_;
    __shared__ alignas(16) float xs[2][T0_*C_];
    __shared__ alignas(16) float wf[2*C_*C_];
    __shared__ alignas(16) float wg[2*C_*C_];
    __shared__ alignas(16) float wl[C_*C_];
    __shared__ alignas(16) float ps[2][11*C_];
    int tid = threadIdx.x;
    {
        const float4* xp = (const float4*)(x + (size_t)bn*Tin*C_);
        float4* xd = (float4*)xs[tile];
        for (int i = lane; i < (Tin*C_)/4; i += 128) xd[i] = xp[i];
    }
    for (int i = tid; i < 2*C_*C_; i += 256) {
        int k = i / (C_*C_); int r = i % (C_*C_); int c = r / C_; int o = r % C_;
        wf[i] = fw[(o*C_+c)*2 + k];
        wg[i] = gw[(o*C_+c)*2 + k];
    }
    for (int i = tid; i < C_*C_; i += 256) wl[i] = wl0[i];
    __syncthreads();
    int nq = Tout*10;
    for (int u = lane; u < nq; u += 128) {
        int t = u/10, o = (u%10)*4;
        float4 f4 = *(const float4*)&fb4[o];
        float4 g4 = *(const float4*)&gb4[o];
        for (int c = 0; c < C_; ++c) {
            float x0v = xs[tile][t*C_+c], x2v = xs[tile][(t+2)*C_+c];
            float4 wf0 = *(const float4*)&wf[c*C_+o];
            float4 wf1 = *(const float4*)&wf[C_*C_ + c*C_+o];
            float4 wg0 = *(const float4*)&wg[c*C_+o];
            float4 wg1 = *(const float4*)&wg[C_*C_ + c*C_+o];
            f4.x += wf0.x*x0v + wf1.x*x2v;  f4.y += wf0.y*x0v + wf1.y*x2v;
            f4.z += wf0.z*x0v + wf1.z*x2v;  f4.w += wf0.w*x0v + wf1.w*x2v;
            g4.x += wg0.x*x0v + wg1.x*x2v;  g4.y += wg0.y*x0v + wg1.y*x2v;
            g4.z += wg0.z*x0v + wg1.z*x2v;  g4.w += wg0.w*x0v + wg1.w*x2v;
        }
        float4 r4;
        r4.x = tanhf(f4.x)*sigm(g4.x);
        r4.y = tanhf(f4.y)*sigm(g4.y);
        r4.z = tanhf(f4.z)*sigm(g4.z);
        r4.w = tanhf(f4.w)*sigm(g4.w);
        *(float4*)&ps[tile][t*C_+o] = r4;
        *(float4*)&xg[(size_t)bn*nout + t*C_+o] = r4;
        int j = t*C_+o;
        size_t tb = ((size_t)b*JP + j)*KP_ + n;
        xgT[tb]          = __float2bfloat16(r4.x);
        xgT[tb + KP_]    = __float2bfloat16(r4.y);
        xgT[tb + 2*KP_]  = __float2bfloat16(r4.z);
        xgT[tb + 3*KP_]  = __float2bfloat16(r4.w);
    }
    __syncthreads();
    for (int u = lane; u < nq; u += 128) {
        int t = u/10, o = (u%10)*4;
        float4 a4 = *(const float4*)&gbias[o];
        for (int c = 0; c < C_; ++c) {
            float s = ps[tile][t*C_+c];
            float4 w = *(const float4*)&wl[c*C_+o];
            a4.x += s*w.x; a4.y += s*w.y; a4.z += s*w.z; a4.w += s*w.w;
        }
        *(float4*)&gc[(size_t)bn*nout + t*C_+o] = a4;
    }
}

// ---- fused sparse graph op + gconv accumulate (2 bn tiles / block) ----
__global__ __launch_bounds__(256) void kern_sparse_acc(const float* __restrict__ in,
    float* __restrict__ outTile, int Tout,
    const int* __restrict__ ptr, const int* __restrict__ nbr, const int* __restrict__ eid,
    const float* __restrict__ aval, const float* __restrict__ coef,
    const float* __restrict__ Amat, const int* __restrict__ selfe,
    const float* __restrict__ gwp, float* __restrict__ gc)
{
    int tile = threadIdx.x >> 7;
    int lane = threadIdx.x & 127;
    int bn = blockIdx.x*2 + tile;
    int b = bn / N_, m = bn % N_;
    __shared__ float wv[2][64];
    __shared__ int   nb[2][64];
    __shared__ alignas(16) float ps[2][11*C_];
    __shared__ alignas(16) float wl[C_*C_];
    int tid = threadIdx.x;
    int p0 = ptr[m], p1 = ptr[m+1];
    int deg = p1 - p0; if (deg > 64) deg = 64;
    if (lane < deg) {
        wv[tile][lane] = coef[b*E_ + eid[p0+lane]] * aval[p0+lane];
        nb[tile][lane] = nbr[p0+lane];
    }
    for (int i = tid; i < C_*C_; i += 256) wl[i] = gwp[i];
    __syncthreads();
    float dval = (selfe[m] >= 0) ? 0.f : Amat[(size_t)m*N_ + m];
    const float* inb = in + (size_t)b*N_*Tout*C_;
    int nout = Tout*C_;
    for (int oi = lane; oi < nout; oi += 128) {
        float acc = dval * inb[(size_t)m*nout + oi];
        for (int j = 0; j < deg; ++j) acc += wv[tile][j]*inb[(size_t)nb[tile][j]*nout + oi];
        ps[tile][oi] = acc;
        if (outTile) outTile[(size_t)bn*nout + oi] = acc;
    }
    __syncthreads();
    int nq = Tout*10;
    for (int u = lane; u < nq; u += 128) {
        int t = u/10, o = (u%10)*4;
        float4 a4 = *(const float4*)&gc[(size_t)bn*nout + t*C_+o];
        for (int c = 0; c < C_; ++c) {
            float s = ps[tile][t*C_+c];
            float4 w = *(const float4*)&wl[c*C_+o];
            a4.x += s*w.x; a4.y += s*w.y; a4.z += s*w.z; a4.w += s*w.w;
        }
        *(float4*)&gc[(size_t)bn*nout + t*C_+o] = a4;
    }
}

// ---------------- adp dense hop via MFMA bf16 (A frags preloaded to registers) ----------------
__global__ __launch_bounds__(256) void kern_gemm_mfma(const __hip_bfloat16* __restrict__ adpTb,
    const __hip_bfloat16* __restrict__ inT, float* __restrict__ outF,
    __hip_bfloat16* __restrict__ outT, int LD, int JP)
{
    int tid = threadIdx.x;
    int wave = tid >> 6, lane = tid & 63;
    int rn = lane & 15, q = lane >> 4;
    int b = blockIdx.z;
    int m0 = blockIdx.x*64;
    int j0 = blockIdx.y*64;
    const short* Ap = (const short*)adpTb + (size_t)(m0 + wave*16 + rn)*KP_ + q*8;
    bf16x8 areg[16];
    #pragma unroll
    for (int kk = 0; kk < 16; ++kk) areg[kk] = *(const bf16x8*)(Ap + kk*32);
    const short* Bp = (const short*)inT + ((size_t)b*JP + j0 + rn)*KP_ + q*8;
    f32x4 acc[4] = {};
    #pragma unroll
    for (int kk = 0; kk < 16; ++kk) {
        #pragma unroll
        for (int s = 0; s < 4; ++s) {
            bf16x8 bb = *(const bf16x8*)(Bp + (size_t)s*16*KP_ + kk*32);
            acc[s] = __builtin_amdgcn_mfma_f32_16x16x32_bf16(areg[kk], bb, acc[s], 0, 0, 0);
        }
    }
    int mb = m0 + wave*16 + q*4;     // D row base
    #pragma unroll
    for (int s = 0; s < 4; ++s) {
        int j = j0 + s*16 + rn;      // D col
        if (j >= LD) continue;
        #pragma unroll
        for (int r = 0; r < 4; ++r) {
            int m = mb + r;
            if (m < N_) outF[((size_t)b*N_ + m)*LD + j] = acc[s][r];
        }
        if (outT) {
            ushort4 v;
            v.x = f2bf(acc[s][0]); v.y = f2bf(acc[s][1]);
            v.z = f2bf(acc[s][2]); v.w = f2bf(acc[s][3]);
            *(ushort4*)((unsigned short*)outT + ((size_t)b*JP + j)*KP_ + mb) = v;
        }
    }
}

// ---------------- gconv accumulate one 40-chunk (2 bn tiles / block) ----------------
__global__ __launch_bounds__(256) void kern_gacc(const float* __restrict__ part, const float* __restrict__ gwp,
    float* __restrict__ gc, int Tout)
{
    int tile = threadIdx.x >> 7;
    int lane = threadIdx.x & 127;
    int bn = blockIdx.x*2 + tile;
    int nout = Tout*C_;
    __shared__ alignas(16) float ps[2][11*C_];
    __shared__ alignas(16) float wl[C_*C_];
    int tid = threadIdx.x;
    {
        const float4* pp = (const float4*)(part + (size_t)bn*nout);
        float4* pd = (float4*)ps[tile];
        for (int i = lane; i < nout/4; i += 128) pd[i] = pp[i];
    }
    for (int i = tid; i < C_*C_; i += 256) wl[i] = gwp[i];
    __syncthreads();
    int nq = Tout*10;
    for (int u = lane; u < nq; u += 128) {
        int t = u/10, o = (u%10)*4;
        float4 a4 = *(const float4*)&gc[(size_t)bn*nout + t*C_+o];
        for (int c = 0; c < C_; ++c) {
            float s = ps[tile][t*C_+c];
            float4 w = *(const float4*)&wl[c*C_+o];
            a4.x += s*w.x; a4.y += s*w.y; a4.z += s*w.z; a4.w += s*w.w;
        }
        *(float4*)&gc[(size_t)bn*nout + t*C_+o] = a4;
    }
}

// ---------------- BN stats per channel ----------------
__global__ __launch_bounds__(320) void kern_bnstats(const float* __restrict__ src, size_t total, float* __restrict__ acc)
{
    int tid = threadIdx.x;
    float s = 0.f, ss = 0.f;
    for (size_t i = (size_t)blockIdx.x*320 + tid; i < total; i += (size_t)gridDim.x*320) {
        float v = src[i]; s += v; ss += v*v;
    }
    __shared__ float ls[320], lss[320];
    ls[tid] = s; lss[tid] = ss; __syncthreads();
    if (tid < C_) {
        float t1 = 0.f, t2 = 0.f;
        for (int r = 0; r < 8; ++r) { t1 += ls[r*C_+tid]; t2 += lss[r*C_+tid]; }
        atomicAdd(&acc[tid], t1); atomicAdd(&acc[C_+tid], t2);
    }
}

__global__ __launch_bounds__(320) void kern_bn1(float* __restrict__ gc, const float* __restrict__ resid,
    int Tin, int Tout, const float* __restrict__ acc1,
    const float* __restrict__ g1, const float* __restrict__ b1, float* __restrict__ acc2)
{
    int tid = threadIdx.x; int c = tid % C_;
    float cnt = (float)(B_*N_*Tout);
    float mean = acc1[c]/cnt;
    float var  = acc1[C_+c]/cnt - mean*mean;
    float inv  = rsqrtf(var + EPS_);
    float gg = g1[c], bb = b1[c];
    int dlt = Tin - Tout;
    float s = 0.f, ss = 0.f;
    size_t total = (size_t)B_*N_*Tout*C_;
    for (size_t i = (size_t)blockIdx.x*320 + tid; i < total; i += (size_t)gridDim.x*320) {
        size_t pos = i / C_; int t = (int)(pos % Tout); size_t bn = pos / Tout;
        float y = gg*(gc[i]-mean)*inv + bb;
        y += resid[(bn*Tin + (t+dlt))*C_ + c];
        gc[i] = y;
        s += y; ss += y*y;
    }
    __shared__ float ls[320], lss[320];
    ls[tid] = s; lss[tid] = ss; __syncthreads();
    if (tid < C_) {
        float t1 = 0.f, t2 = 0.f;
        for (int r = 0; r < 8; ++r) { t1 += ls[r*C_+tid]; t2 += lss[r*C_+tid]; }
        atomicAdd(&acc2[tid], t1); atomicAdd(&acc2[C_+tid], t2);
    }
}

__global__ __launch_bounds__(256) void kern_bn2(const float* __restrict__ gc, float* __restrict__ xout, int Tout,
    const float* __restrict__ acc2, const float* __restrict__ g2, const float* __restrict__ b2)
{
    size_t total = (size_t)B_*N_*Tout*C_;
    size_t i = (size_t)blockIdx.x*256 + threadIdx.x;
    if (i >= total) return;
    int c = (int)(i % C_);
    float cnt = (float)(B_*N_*Tout);
    float mean = acc2[c]/cnt;
    float var  = acc2[C_+c]/cnt - mean*mean;
    float inv  = rsqrtf(var + EPS_);
    xout[i] = g2[c]*(gc[i]-mean)*inv + b2[c];
}

// ---------------- skip conv on last 7 steps -> bf16 skip(B,N,7,320); 4 bn per block ----------------
// If acc2 != nullptr, input is pre-bn2 gc and bn2 affine is applied in-stage.
__global__ __launch_bounds__(256) void kern_skip(const float* __restrict__ x, int Tout,
    const float* __restrict__ sw, const float* __restrict__ sbias, __hip_bfloat16* __restrict__ skp, int first,
    const float* __restrict__ acc2, const float* __restrict__ g2, const float* __restrict__ b2)
{
    int bn0 = blockIdx.x*4; int half = blockIdx.y;
    int off = Tout - 7;
    __shared__ alignas(16) float xs[4][7*C_];
    __shared__ alignas(16) float wl[C_*164];
    __shared__ float scl[C_], bia[C_];
    int tid = threadIdx.x;
    if (acc2) {
        if (tid < C_) {
            float cnt = (float)(B_*N_*Tout);
            float mean = acc2[tid]/cnt;
            float var  = acc2[C_+tid]/cnt - mean*mean;
            float inv  = rsqrtf(var + EPS_);
            scl[tid] = g2[tid]*inv;
            bia[tid] = b2[tid] - g2[tid]*mean*inv;
        }
        __syncthreads();
    }
    for (int i = tid; i < 4*(7*C_/4); i += 256) {
        int bl = i / 70, r = i % 70;
        float4 v = ((const float4*)(x + ((size_t)(bn0+bl)*Tout + off)*C_))[r];
        if (acc2) {
            int c0 = (r*4) % C_;
            v.x = scl[c0]*v.x + bia[c0];
            v.y = scl[c0+1]*v.y + bia[c0+1];
            v.z = scl[c0+2]*v.z + bia[c0+2];
            v.w = scl[c0+3]*v.w + bia[c0+3];
        }
        ((float4*)xs[bl])[r] = v;
    }
    for (int i = tid; i < 160*C_; i += 256) {
        int oo = i / C_, c = i % C_;
        wl[c*164 + oo] = sw[(size_t)(half*160 + oo)*C_ + c];
    }
    __syncthreads();
    for (int u = tid; u < 4*7*40; u += 256) {
        int bl = u / 280; int v = u % 280;
        int t = v / 40, o = (v % 40)*4;
        float4 a4 = {0.f,0.f,0.f,0.f};
        for (int c = 0; c < C_; ++c) {
            float s = xs[bl][t*C_+c];
            float4 w = *(const float4*)&wl[c*164 + o];
            a4.x += s*w.x; a4.y += s*w.y; a4.z += s*w.z; a4.w += s*w.w;
        }
        int og = half*160 + o;
        float4 b4 = *(const float4*)&sbias[og];
        a4.x += b4.x; a4.y += b4.y; a4.z += b4.z; a4.w += b4.w;
        size_t di = ((size_t)(bn0+bl)*7 + t)*320 + og;
        if (first) {
            skp[di+0] = __float2bfloat16(a4.x);
            skp[di+1] = __float2bfloat16(a4.y);
            skp[di+2] = __float2bfloat16(a4.z);
            skp[di+3] = __float2bfloat16(a4.w);
        } else {
            skp[di+0] = __float2bfloat16(__bfloat162float(skp[di+0]) + a4.x);
            skp[di+1] = __float2bfloat16(__bfloat162float(skp[di+1]) + a4.y);
            skp[di+2] = __float2bfloat16(__bfloat162float(skp[di+2]) + a4.z);
            skp[di+3] = __float2bfloat16(__bfloat162float(skp[di+3]) + a4.w);
        }
    }
}

__global__ __launch_bounds__(256) void kern_cvtw(const float* __restrict__ w, __hip_bfloat16* __restrict__ wb, int n)
{
    int i = blockIdx.x*256 + threadIdx.x;
    if (i < n) wb[i] = __float2bfloat16(w[i]);
}

// ---------------- fused end stage: lrelu(skp) @ e1w (+bias,lrelu) @ e2w^T + e2b -> out ----------------
// Barrier-free csp loop (unroll-limited to avoid spills); per-lane VALU e2 epilogue; shfl_xor reduce.
constexpr int ASD_ = 324;   // LDS A row stride in shorts
__global__ __launch_bounds__(256, 2) void kern_end2(const __hip_bfloat16* __restrict__ skp,
    const __hip_bfloat16* __restrict__ e1wb, const float* __restrict__ e1b,
    const float* __restrict__ e2w, const float* __restrict__ e2b, float* __restrict__ out)
{
    __shared__ short As[64*ASD_];         // 41472 B, coalesced-staged A tile
    __shared__ _Float16 w2h[640][12];     // 15360 B, row = c (24 B, 8B-aligned)
    int tid = threadIdx.x;
    int wave = tid >> 6, lane = tid & 63;
    int rn = lane & 15, q = lane >> 4;
    int m0 = blockIdx.x*64;
    // stage A (lrelu applied) with coalesced 16B loads
    {
        const bf16x8* gA = (const bf16x8*)((const short*)skp + (size_t)m0*320);
        for (int i = tid; i < 2560; i += 256) {
            bf16x8 v = gA[i];
            bf16x8 r;
            #pragma unroll
            for (int e = 0; e < 8; ++e)
                r[e] = (short)f2bf(lrelu(bf2f((unsigned short)v[e])));
            int row = i / 40, col = (i % 40)*8;
            *(bf16x8*)&As[row*ASD_ + col] = r;
        }
    }
    for (int i = tid; i < 640*12; i += 256) {
        int c = i / 12, o = i % 12;
        w2h[c][o] = (_Float16)e2w[o*640 + c];
    }
    __syncthreads();
    bf16x8 areg[10];
    {
        const short* Arow = As + (wave*16 + rn)*ASD_ + q*8;
        #pragma unroll
        for (int kk = 0; kk < 10; ++kk) areg[kk] = *(const bf16x8*)(Arow + kk*32);
    }
    float acc_out[4][12] = {};
    const short* e1p = (const short*)e1wb;
    #pragma unroll 1
    for (int csp = 0; csp < 20; ++csp) {
        const short* Bp0 = e1p + (size_t)(csp*32 + rn)*320 + q*8;
        const short* Bp1 = Bp0 + 16*320;
        f32x4 c00 = {}, c01 = {}, c10 = {}, c11 = {};
        #pragma unroll
        for (int kk = 0; kk < 10; kk += 2) {
            bf16x8 b00 = *(const bf16x8*)(Bp0 + kk*32);
            bf16x8 b01 = *(const bf16x8*)(Bp0 + (kk+1)*32);
            bf16x8 b10 = *(const bf16x8*)(Bp1 + kk*32);
            bf16x8 b11 = *(const bf16x8*)(Bp1 + (kk+1)*32);
            c00 = __builtin_amdgcn_mfma_f32_16x16x32_bf16(areg[kk],   b00, c00, 0, 0, 0);
            c10 = __builtin_amdgcn_mfma_f32_16x16x32_bf16(areg[kk],   b10, c10, 0, 0, 0);
            c01 = __builtin_amdgcn_mfma_f32_16x16x32_bf16(areg[kk+1], b01, c01, 0, 0, 0);
            c11 = __builtin_amdgcn_mfma_f32_16x16x32_bf16(areg[kk+1], b11, c11, 0, 0, 0);
        }
        int ca = csp*32 + rn, cb = ca + 16;
        float bias0 = e1b[ca], bias1 = e1b[cb];
        f16x4 wa0 = *(const f16x4*)&w2h[ca][0];
        f16x4 wa1 = *(const f16x4*)&w2h[ca][4];
        f16x4 wa2 = *(const f16x4*)&w2h[ca][8];
        f16x4 wb0 = *(const f16x4*)&w2h[cb][0];
        f16x4 wb1 = *(const f16x4*)&w2h[cb][4];
        f16x4 wb2 = *(const f16x4*)&w2h[cb][8];
        float wa[12], wb[12];
        #pragma unroll
        for (int o = 0; o < 4; ++o) {
            wa[o] = (float)wa0[o]; wa[4+o] = (float)wa1[o]; wa[8+o] = (float)wa2[o];
            wb[o] = (float)wb0[o]; wb[4+o] = (float)wb1[o]; wb[8+o] = (float)wb2[o];
        }
        #pragma unroll
        for (int r = 0; r < 4; ++r) {
            float y0 = lrelu(c00[r] + c01[r] + bias0);
            float y1 = lrelu(c10[r] + c11[r] + bias1);
            #pragma unroll
            for (int o = 0; o < 12; ++o)
                acc_out[r][o] += y0*wa[o] + y1*wb[o];
        }
    }
    #pragma unroll
    for (int r = 0; r < 4; ++r)
        #pragma unroll
        for (int o = 0; o < 12; ++o) {
            float v = acc_out[r][o];
            v += __shfl_xor(v, 1);
            v += __shfl_xor(v, 2);
            v += __shfl_xor(v, 4);
            v += __shfl_xor(v, 8);
            acc_out[r][o] = v;
        }
    if (rn < 12) {
        float bo = e2b[rn];
        #pragma unroll
        for (int r = 0; r < 4; ++r) {
            int gm = m0 + wave*16 + q*4 + r;
            int t = gm % 7; int bn = gm / 7; int n = bn % N_; int b = bn / N_;
            out[(((size_t)b*12 + rn)*N_ + n)*7 + t] = acc_out[r][rn] + bo;
        }
    }
}

extern "C" void kernel_launch(void* const* d_in, const int* in_sizes, int n_in,
                              void* d_out, int out_size, void* d_ws, size_t ws_size,
                              hipStream_t stream)
{
    (void)in_sizes; (void)n_in; (void)out_size;
    const float* input   = (const float*)d_in[0];
    const float* A_fwd   = (const float*)d_in[1];
    const float* A_bwd   = (const float*)d_in[2];
    const int*   indices = (const int*)  d_in[3];
    const float* G0      = (const float*)d_in[4];
    const float* G1      = (const float*)d_in[5];
    const float* nv1     = (const float*)d_in[6];
    const float* nv2     = (const float*)d_in[7];
    const float* wef     = (const float*)d_in[8];
    const float* web     = (const float*)d_in[9];
    const float* vsf     = (const float*)d_in[10];
    const float* vdf     = (const float*)d_in[11];
    const float* vsb     = (const float*)d_in[12];
    const float* vdb     = (const float*)d_in[13];
    const float* start_w = (const float*)d_in[14];
    const float* start_b = (const float*)d_in[15];
    const float* filt_w  = (const float*)d_in[16];
    const float* filt_b  = (const float*)d_in[17];
    const float* gate_w  = (const float*)d_in[18];
    const float* gate_b  = (const float*)d_in[19];
    const float* gcw     = (const float*)d_in[20];
    const float* gcb     = (const float*)d_in[21];
    const float* bng_g   = (const float*)d_in[22];
    const float* bng_b   = (const float*)d_in[23];
    const float* bn_g    = (const float*)d_in[24];
    const float* bn_b    = (const float*)d_in[25];
    const float* skw     = (const float*)d_in[26];
    const float* skb     = (const float*)d_in[27];
    const float* e1w     = (const float*)d_in[28];
    const float* e1b     = (const float*)d_in[29];
    const float* e2w     = (const float*)d_in[30];
    const float* e2b     = (const float*)d_in[31];
    float* out = (float*)d_out;

    // ---- workspace layout (4B units, 16B-aligned allocations) ----
    float* W = (float*)d_ws;
    size_t off = 0;
    auto FA = [&](size_t n){ off = (off + 3) & ~(size_t)3; float* p = W + off; off += n; return p; };
    float* insum  = FA(2);
    float* tf     = FA((size_t)B_*EH_);
    float* tb     = FA((size_t)B_*EH_);
    float* bnacc1 = FA(80);
    float* bnacc2 = FA(80);
    float* usf = FA((size_t)B_*N_); float* udf = FA((size_t)B_*N_);
    float* usb = FA((size_t)B_*N_); float* udb = FA((size_t)B_*N_);
    float* scf = FA((size_t)B_*E_); float* scb = FA((size_t)B_*E_);
    float* efv = FA((size_t)B_*E_); float* ebv = FA((size_t)B_*E_);
    __hip_bfloat16* adpTb = (__hip_bfloat16*)FA((size_t)KP_*KP_/2);
    float* a0v = FA(E_); float* a1v = FA(E_);
    int* map  = (int*)FA((size_t)N_*N_);
    int* cnt0 = (int*)FA(512); int* cnt1 = (int*)FA(512);
    int* ptr0 = (int*)FA(512); int* ptr1 = (int*)FA(512);
    int* cur0 = (int*)FA(512); int* cur1 = (int*)FA(512);
    int* selfe = (int*)FA(512);
    int* e0id = (int*)FA(E_); int* e0nb = (int*)FA(E_);
    int* e1id = (int*)FA(E_); int* e1nb = (int*)FA(E_);
    float* xA  = FA((size_t)B_*N_*T0_*C_);
    float* xg  = FA((size_t)B_*N_*11*C_);
    float* pa  = FA((size_t)B_*N_*11*C_);
    float* gc  = FA((size_t)B_*N_*11*C_);
    __hip_bfloat16* skp = (__hip_bfloat16*)FA((size_t)B_*N_*7*320/2);
    __hip_bfloat16* xgT = (__hip_bfloat16*)FA((size_t)B_*448*KP_/2);
    __hip_bfloat16* paT = (__hip_bfloat16*)FA((size_t)B_*448*KP_/2);
    // e1wb overlays xg (dead after block loop, rewritten every call)
    __hip_bfloat16* e1wb = (__hip_bfloat16*)xg;

    if (ws_size < off*sizeof(float)) return;   // fail cleanly, not a fault

    // ---- setup ----
    kern_init<<<(N_*N_+255)/256, 256, 0, stream>>>(insum, map, cnt0, selfe, (int*)adpTb);
    kern_instats<<<256, 256, 0, stream>>>(input, insum);
    kern_x0<<<(B_*N_*T0_*C_+255)/256, 256, 0, stream>>>(input, insum, start_w, start_b, xA);
    kern_adp<<<N_, 512, 0, stream>>>(nv1, nv2, adpTb);
    kern_emax<<<(E_+255)/256, 256, 0, stream>>>(indices, map);
    kern_ecnt<<<(E_+255)/256, 256, 0, stream>>>(indices, map, cnt0, cnt1, selfe);
    kern_scan<<<1, 512, 0, stream>>>(cnt0, cnt1, ptr0, ptr1, cur0, cur1);
    kern_efill<<<(E_+255)/256, 256, 0, stream>>>(indices, map, A_fwd, A_bwd, cur0, cur1,
                                                 e0id, e0nb, a0v, e1id, e1nb, a1v);

    // ---- 3 blocks ----
    for (int blk = 0; blk < 3; ++blk) {
        int Tin = T0_ - 2*blk;
        int Tout = Tin - 2;
        int LD = Tout*C_;
        int JP = (LD + 63) & ~63;
        size_t total = (size_t)B_*N_*Tout*C_;
        kern_zeroacc<<<(2*B_*EH_+160+255)/256, 256, 0, stream>>>(tf, 2*B_*EH_+160);

        kern_umean<<<B_*N_, 64, 0, stream>>>(xA, Tin, vsf+blk*C_, vdf+blk*C_, vsb+blk*C_, vdb+blk*C_,
                                             usf, udf, usb, udb);
        kern_t<<<dim3(B_, 8), 320, 0, stream>>>(indices, usf, udf, usb, udb, G0, tf, tb, scf, scb);
        kern_ef<<<dim3(8, B_), 256, 0, stream>>>(tf, tb, wef, web, G1, efv, ebv);

        const float* gwb = gcw + (size_t)blk*7*C_*C_;
        kern_dconv_acc<<<B_*N_/2, 256, 0, stream>>>(xA, Tin,
            filt_w + (size_t)blk*2*C_*C_, filt_b + blk*C_,
            gate_w + (size_t)blk*2*C_*C_, gate_b + blk*C_,
            gwb + 0*C_*C_, gcb + blk*C_, xg, gc, xgT, JP);
        // s0 two hops
        kern_sparse_acc<<<B_*N_/2, 256, 0, stream>>>(xg, pa, Tout, ptr1, e0nb, e0id, a0v, efv,
                                                     A_fwd, selfe, gwb + 1*C_*C_, gc);
        kern_sparse_acc<<<B_*N_/2, 256, 0, stream>>>(pa, nullptr, Tout, ptr1, e0nb, e0id, a0v, efv,
                                                     A_fwd, selfe, gwb + 2*C_*C_, gc);
        // s1 two hops
        kern_sparse_acc<<<B_*N_/2, 256, 0, stream>>>(xg, pa, Tout, ptr0, e1nb, e1id, a1v, ebv,
                                                     A_bwd, selfe, gwb + 3*C_*C_, gc);
        kern_sparse_acc<<<B_*N_/2, 256, 0, stream>>>(pa, nullptr, Tout, ptr0, e1nb, e1id, a1v, ebv,
                                                     A_bwd, selfe, gwb + 4*C_*C_, gc);
        // adp two dense hops via MFMA
        dim3 gg(8, JP/64, B_);
        kern_gemm_mfma<<<gg, 256, 0, stream>>>(adpTb, xgT, pa, paT, LD, JP);
        kern_gacc<<<B_*N_/2, 256, 0, stream>>>(pa, gwb + 5*C_*C_, gc, Tout);
        kern_gemm_mfma<<<gg, 256, 0, stream>>>(adpTb, paT, xg, nullptr, LD, JP);
        kern_gacc<<<B_*N_/2, 256, 0, stream>>>(xg, gwb + 6*C_*C_, gc, Tout);

        kern_bnstats<<<512, 320, 0, stream>>>(gc, total, bnacc1);
        kern_bn1<<<512, 320, 0, stream>>>(gc, xA, Tin, Tout, bnacc1, bng_g + blk*C_, bng_b + blk*C_, bnacc2);
        if (blk < 2) {
            kern_bn2<<<(int)((total+255)/256), 256, 0, stream>>>(gc, xA, Tout, bnacc2, bn_g + blk*C_, bn_b + blk*C_);
            kern_skip<<<dim3(B_*N_/4, 2), 256, 0, stream>>>(xA, Tout, skw + (size_t)blk*320*C_, skb + blk*320,
                                                            skp, blk == 0 ? 1 : 0, nullptr, nullptr, nullptr);
        } else {
            // final block: xA never consumed again -> fuse bn2 into skip, drop bn2 pass
            kern_skip<<<dim3(B_*N_/4, 2), 256, 0, stream>>>(gc, Tout, skw + (size_t)blk*320*C_, skb + blk*320,
                                                            skp, 0, bnacc2, bn_g + blk*C_, bn_b + blk*C_);
        }
    }

    // ---- end stage ----
    kern_cvtw<<<(640*320+255)/256, 256, 0, stream>>>(e1w, e1wb, 640*320);
    kern_end2<<<B_*N_*7/64, 256, 0, stream>>>(skp, e1wb, e1b, e2w, e2b, out);
}